// Round 1
// baseline (2742.480 us; speedup 1.0000x reference)
//
#include <hip/hip_runtime.h>
#include <hip/hip_bf16.h>

// ============================================================================
// Round 1: correct fp32 baseline.
//   B=64, S1=S2=512, H=768, DW=200
//   branch(X, W, KV):  xw = [X|y] @ W ; A = xw @ KV^T ; A[masked2] = -1e-5 ;
//                      P = softmax(A) ; V = P @ KV ; V[masked1 rows] = -1e5 ;
//                      out = max over rows
//   K1 = xw GEMM, K2 = fused scores/softmax/PV/max (atomicMax on ordered uint),
//   K3 = wv 200->768 projection, K4 = final dot + sigmoid, K5 = mask outputs.
// ============================================================================

#define BB 64
#define SS 512
#define HH 768
#define DWW 200

__device__ __forceinline__ unsigned fkey(float f) {
    unsigned u = __float_as_uint(f);
    return (u & 0x80000000u) ? ~u : (u | 0x80000000u);
}
__device__ __forceinline__ float fdec(unsigned k) {
    unsigned u = (k & 0x80000000u) ? (k & 0x7fffffffu) : ~k;
    return __uint_as_float(u);
}

// ---------------------------------------------------------------------------
// K5: mask outputs (as float 0/1) -> d_out[64 .. 64+2*B*S)
__global__ __launch_bounds__(256) void k_masks(const int* __restrict__ m1,
                                               const int* __restrict__ m2,
                                               float* __restrict__ out) {
    int i = blockIdx.x * 256 + threadIdx.x;
    if (i < BB * SS) {
        out[BB + i]           = (float)(1 - m1[i]);
        out[BB + BB * SS + i] = (float)(1 - m2[i]);
    }
}

// ---------------------------------------------------------------------------
// init max-keys to key(-1e5): matches ref semantics (masked rows contribute -1e5)
__global__ __launch_bounds__(256) void k_init(unsigned* __restrict__ k1,
                                              unsigned* __restrict__ k2) {
    int i = blockIdx.x * 256 + threadIdx.x;
    unsigned v = fkey(-1e5f);
    if (i < BB * HH) k1[i] = v;
    if (i < BB * DWW) k2[i] = v;
}

// ---------------------------------------------------------------------------
// K1: XW[b,s,n] = sum_k A(b,s,k) * W[k,n];  A = [X | y] (K = Din+1)
// 64x64 tile, 256 threads, 4x4 per thread, fp32.
__global__ __launch_bounds__(256) void k_gemm1(const float* __restrict__ X,
                                               const float* __restrict__ y,
                                               const float* __restrict__ W,
                                               float* __restrict__ XW,
                                               int K, int N, int b0) {
    const int Din = K - 1;
    int bl = blockIdx.x >> 3, stile = blockIdx.x & 7;
    int bg = b0 + bl;
    int s0 = stile * 64;
    int n0 = blockIdx.y * 64;

    __shared__ float As[16][68];  // [k][s], stride 68 (16B-aligned rows, 2-way max)
    __shared__ float Bs[16][68];  // [k][n]

    int tid = threadIdx.x;
    int tx = tid & 15, ty = tid >> 4;
    float c[4][4] = {};

    const float* Xb = X + (size_t)bg * SS * Din;
    const float* yb = y + (size_t)bg * SS;

    int arow = tid >> 2;         // 0..63 (s within tile)
    int ak   = (tid & 3) * 4;    // 0,4,8,12
    int brow = tid >> 4;         // 0..15 (k)
    int bc   = (tid & 15) * 4;   // 0..60 (n)

    int ktiles = (K + 15) >> 4;
    for (int kt = 0; kt < ktiles; ++kt) {
        int k0 = kt << 4;
        // stage A (transpose to [k][s])
        {
            int gs = s0 + arow;
            int gk = k0 + ak;
            float4 v;
            if (gk + 3 < Din) {
                v = *reinterpret_cast<const float4*>(Xb + (size_t)gs * Din + gk);
            } else {
                float tmp[4];
#pragma unroll
                for (int i = 0; i < 4; ++i) {
                    int k = gk + i;
                    tmp[i] = (k < Din) ? Xb[(size_t)gs * Din + k]
                                       : ((k == Din) ? yb[gs] : 0.f);
                }
                v.x = tmp[0]; v.y = tmp[1]; v.z = tmp[2]; v.w = tmp[3];
            }
            As[ak + 0][arow] = v.x; As[ak + 1][arow] = v.y;
            As[ak + 2][arow] = v.z; As[ak + 3][arow] = v.w;
        }
        // stage B
        {
            int gk = k0 + brow;
            int gn = n0 + bc;
            float4 v = make_float4(0.f, 0.f, 0.f, 0.f);
            if (gk < K) {
                if (gn + 3 < N) {
                    v = *reinterpret_cast<const float4*>(W + (size_t)gk * N + gn);
                } else {
                    float* pv = &v.x;
#pragma unroll
                    for (int i = 0; i < 4; ++i) {
                        int n = gn + i;
                        pv[i] = (n < N) ? W[(size_t)gk * N + n] : 0.f;
                    }
                }
            }
            *reinterpret_cast<float4*>(&Bs[brow][bc]) = v;
        }
        __syncthreads();
#pragma unroll
        for (int kk = 0; kk < 16; ++kk) {
            float4 a = *reinterpret_cast<const float4*>(&As[kk][ty * 4]);
            float4 b = *reinterpret_cast<const float4*>(&Bs[kk][tx * 4]);
            const float av[4] = {a.x, a.y, a.z, a.w};
            const float bv[4] = {b.x, b.y, b.z, b.w};
#pragma unroll
            for (int i = 0; i < 4; ++i)
#pragma unroll
                for (int j = 0; j < 4; ++j) c[i][j] += av[i] * bv[j];
        }
        __syncthreads();
    }
#pragma unroll
    for (int i = 0; i < 4; ++i) {
        int gs = s0 + ty * 4 + i;
#pragma unroll
        for (int j = 0; j < 4; ++j) {
            int gn = n0 + tx * 4 + j;
            if (gn < N) XW[((size_t)bl * SS + gs) * N + gn] = c[i][j];
        }
    }
}

// ---------------------------------------------------------------------------
// K2: fused attention for one (batch, 64-row tile).
//  Phase A: scores[64][512] (LDS) = XWrows @ KV^T, masked cols -> -1e-5
//  Phase B: row softmax (unnormalized p + row sums, division deferred)
//  Phase C: V = P @ KV in 128-col passes; normalize; row-mask; max over rows;
//           atomicMax into keys[bg][d].
__global__ __launch_bounds__(256) void k_attn(const float* __restrict__ XW,
                                              const float* __restrict__ KV,
                                              const int* __restrict__ m1,
                                              const int* __restrict__ m2,
                                              unsigned* __restrict__ keys,
                                              int D, int b0) {
    int bl = blockIdx.x >> 3, stile = blockIdx.x & 7;
    int bg = b0 + bl;
    int s0 = stile * 64;

    __shared__ float sc[64][519];   // scores/P, stride 519 (odd -> low conflicts)
    __shared__ float As[16][68];    // [k][s] xw tile
    __shared__ float Bs[16][136];   // [k][t] (phase A) / [t][d] (phase C) / red
    __shared__ float rsum[64];

    int tid = threadIdx.x;
    int tx = tid & 15, ty = tid >> 4;

    const float* XWb = XW + ((size_t)bl * SS + s0) * D;
    const float* KVb = KV + (size_t)bg * SS * D;

    // ---- Phase A: scores ----
    int ktiles = (D + 15) >> 4;
    for (int t0 = 0; t0 < SS; t0 += 128) {
        float c[4][8] = {};
        for (int kt = 0; kt < ktiles; ++kt) {
            int k0 = kt << 4;
            // stage A: 64 s x 16 k  -> As[k][s]
            {
                int row = tid >> 2, ksub = (tid & 3) * 4;
                int gk = k0 + ksub;
                float4 v = make_float4(0.f, 0.f, 0.f, 0.f);
                if (gk + 3 < D) {
                    v = *reinterpret_cast<const float4*>(XWb + (size_t)row * D + gk);
                } else {
                    float* pv = &v.x;
#pragma unroll
                    for (int i = 0; i < 4; ++i) {
                        int k = gk + i;
                        pv[i] = (k < D) ? XWb[(size_t)row * D + k] : 0.f;
                    }
                }
                As[ksub + 0][row] = v.x; As[ksub + 1][row] = v.y;
                As[ksub + 2][row] = v.z; As[ksub + 3][row] = v.w;
            }
            // stage B: 128 t x 16 k -> Bs[k][t]
#pragma unroll
            for (int q = 0; q < 2; ++q) {
                int idx = tid + q * 256;       // 0..511
                int trow = idx >> 2;           // 0..127
                int ksub = (idx & 3) * 4;
                int gk = k0 + ksub;
                float4 v = make_float4(0.f, 0.f, 0.f, 0.f);
                if (gk + 3 < D) {
                    v = *reinterpret_cast<const float4*>(KVb + (size_t)(t0 + trow) * D + gk);
                } else {
                    float* pv = &v.x;
#pragma unroll
                    for (int i = 0; i < 4; ++i) {
                        int k = gk + i;
                        pv[i] = (k < D) ? KVb[(size_t)(t0 + trow) * D + k] : 0.f;
                    }
                }
                Bs[ksub + 0][trow] = v.x; Bs[ksub + 1][trow] = v.y;
                Bs[ksub + 2][trow] = v.z; Bs[ksub + 3][trow] = v.w;
            }
            __syncthreads();
#pragma unroll
            for (int kk = 0; kk < 16; ++kk) {
                float4 a4 = *reinterpret_cast<const float4*>(&As[kk][ty * 4]);
                float4 b0v = *reinterpret_cast<const float4*>(&Bs[kk][tx * 8]);
                float4 b1v = *reinterpret_cast<const float4*>(&Bs[kk][tx * 8 + 4]);
                const float av[4] = {a4.x, a4.y, a4.z, a4.w};
                const float bv[8] = {b0v.x, b0v.y, b0v.z, b0v.w,
                                     b1v.x, b1v.y, b1v.z, b1v.w};
#pragma unroll
                for (int i = 0; i < 4; ++i)
#pragma unroll
                    for (int j = 0; j < 8; ++j) c[i][j] += av[i] * bv[j];
            }
            __syncthreads();
        }
        // write scores with col mask (-1e-5 pre-softmax, faithful to ref)
#pragma unroll
        for (int i = 0; i < 4; ++i) {
            int sl = ty * 4 + i;
#pragma unroll
            for (int j = 0; j < 8; ++j) {
                int t = t0 + tx * 8 + j;
                float v = c[i][j];
                if (m2[bg * SS + t] == 0) v = -1e-5f;
                sc[sl][t] = v;
            }
        }
    }
    __syncthreads();

    // ---- Phase B: softmax (store unnormalized p, defer division) ----
    {
        int r = tid >> 2, part = tid & 3;
        float mx = -3e38f;
        for (int t = part; t < SS; t += 4) mx = fmaxf(mx, sc[r][t]);
        mx = fmaxf(mx, __shfl_xor(mx, 1));
        mx = fmaxf(mx, __shfl_xor(mx, 2));
        float sm = 0.f;
        for (int t = part; t < SS; t += 4) {
            float p = __expf(sc[r][t] - mx);
            sc[r][t] = p;
            sm += p;
        }
        sm += __shfl_xor(sm, 1);
        sm += __shfl_xor(sm, 2);
        if (part == 0) rsum[r] = sm;
    }
    __syncthreads();

    // ---- Phase C: PV + normalize + row-masked max -> atomicMax ----
    int ndp = (D + 127) >> 7;
    for (int dp = 0; dp < ndp; ++dp) {
        int d0 = dp << 7;
        float c[4][8] = {};
        for (int tt0 = 0; tt0 < SS; tt0 += 16) {
            // stage KV tile [16 t][128 d] -> Bs[t][d]
#pragma unroll
            for (int q = 0; q < 2; ++q) {
                int idx = tid + q * 256;     // 0..511
                int trow = idx >> 5;         // 0..15
                int dc = (idx & 31) * 4;     // 0..124
                int gd = d0 + dc;
                float4 v = make_float4(0.f, 0.f, 0.f, 0.f);
                if (gd + 3 < D) {
                    v = *reinterpret_cast<const float4*>(KVb + (size_t)(tt0 + trow) * D + gd);
                } else {
                    float* pv = &v.x;
#pragma unroll
                    for (int i = 0; i < 4; ++i) {
                        int d = gd + i;
                        pv[i] = (d < D) ? KVb[(size_t)(tt0 + trow) * D + d] : 0.f;
                    }
                }
                *reinterpret_cast<float4*>(&Bs[trow][dc]) = v;
            }
            __syncthreads();
#pragma unroll
            for (int kk = 0; kk < 16; ++kk) {
                float av[4];
#pragma unroll
                for (int i = 0; i < 4; ++i) av[i] = sc[ty * 4 + i][tt0 + kk];
                float4 b0v = *reinterpret_cast<const float4*>(&Bs[kk][tx * 8]);
                float4 b1v = *reinterpret_cast<const float4*>(&Bs[kk][tx * 8 + 4]);
                const float bv[8] = {b0v.x, b0v.y, b0v.z, b0v.w,
                                     b1v.x, b1v.y, b1v.z, b1v.w};
#pragma unroll
                for (int i = 0; i < 4; ++i)
#pragma unroll
                    for (int j = 0; j < 8; ++j) c[i][j] += av[i] * bv[j];
            }
            __syncthreads();
        }
        // normalize + row mask + partial max over this thread's 4 rows
        float m[8];
#pragma unroll
        for (int j = 0; j < 8; ++j) m[j] = -3e38f;
#pragma unroll
        for (int i = 0; i < 4; ++i) {
            int sl = ty * 4 + i;
            int sg = s0 + sl;
            if (m1[bg * SS + sg] != 0) {
                float rn = 1.0f / rsum[sl];
#pragma unroll
                for (int j = 0; j < 8; ++j) m[j] = fmaxf(m[j], c[i][j] * rn);
            }
        }
        // cross-thread max over 16 ty groups via LDS (reuse Bs as red[16][128])
        float (*red)[128] = reinterpret_cast<float (*)[128]>(&Bs[0][0]);
        __syncthreads();
#pragma unroll
        for (int j = 0; j < 8; ++j) red[ty][tx * 8 + j] = m[j];
        __syncthreads();
        if (tid < 128) {
            float mx = red[0][tid];
#pragma unroll
            for (int r = 1; r < 16; ++r) mx = fmaxf(mx, red[r][tid]);
            int gd = d0 + tid;
            if (gd < D) atomicMax(&keys[(size_t)bg * D + gd], fkey(mx));
        }
        __syncthreads();
    }
}

// ---------------------------------------------------------------------------
// K3: x12wv (decoded) @ lin_wv_w + lin_wv_b -> x12wvp[b][768]
__global__ __launch_bounds__(256) void k_wvproj(const unsigned* __restrict__ wvkeys,
                                                const float* __restrict__ Wp,
                                                const float* __restrict__ bp,
                                                float* __restrict__ outp) {
    int b = blockIdx.x;
    __shared__ float xv[DWW];
    int tid = threadIdx.x;
    if (tid < DWW) xv[tid] = fdec(wvkeys[b * DWW + tid]);
    __syncthreads();
    for (int h = tid; h < HH; h += 256) {
        float acc = bp[h];
        for (int d = 0; d < DWW; ++d) acc += xv[d] * Wp[d * HH + h];
        outp[b * HH + h] = acc;
    }
}

// ---------------------------------------------------------------------------
// K4: o[b] = sigmoid( [x1_h|x2_h|x12|x12wvp] . lin_w + lin_b )
__global__ __launch_bounds__(256) void k_final(const float* __restrict__ x1h,
                                               const float* __restrict__ x2h,
                                               const unsigned* __restrict__ keys,
                                               const float* __restrict__ wvp,
                                               const float* __restrict__ lw,
                                               const float* __restrict__ lb,
                                               float* __restrict__ out) {
    int b = blockIdx.x;
    int tid = threadIdx.x;
    float acc = 0.f;
    for (int i = tid; i < HH; i += 256) {
        acc += x1h[b * HH + i] * lw[i];
        acc += x2h[b * HH + i] * lw[HH + i];
        acc += fdec(keys[b * HH + i]) * lw[2 * HH + i];
        acc += wvp[b * HH + i] * lw[3 * HH + i];
    }
    __shared__ float red[4];
    int wid = tid >> 6, lane = tid & 63;
#pragma unroll
    for (int off = 32; off; off >>= 1) acc += __shfl_down(acc, off);
    if (lane == 0) red[wid] = acc;
    __syncthreads();
    if (tid == 0) {
        float z = red[0] + red[1] + red[2] + red[3] + lb[0];
        out[b] = 1.f / (1.f + __expf(-z));
    }
}

// ---------------------------------------------------------------------------
extern "C" void kernel_launch(void* const* d_in, const int* in_sizes, int n_in,
                              void* d_out, int out_size, void* d_ws, size_t ws_size,
                              hipStream_t stream) {
    const float* x1    = (const float*)d_in[0];
    const float* x1h   = (const float*)d_in[1];
    const int*   m1    = (const int*)d_in[2];
    const float* y     = (const float*)d_in[3];
    const float* x2    = (const float*)d_in[4];
    const float* x2h   = (const float*)d_in[5];
    const int*   m2    = (const int*)d_in[6];
    const float* tt    = (const float*)d_in[7];
    const float* tt2   = (const float*)d_in[8];
    const float* Wb    = (const float*)d_in[9];
    const float* Wwv   = (const float*)d_in[10];
    const float* lwvw  = (const float*)d_in[11];
    const float* lwvb  = (const float*)d_in[12];
    const float* lw    = (const float*)d_in[13];
    const float* lb    = (const float*)d_in[14];
    float* out = (float*)d_out;

    // workspace layout (all 4-byte elems; xw area 16B aligned)
    char* ws = (char*)d_ws;
    unsigned* x12key   = (unsigned*)ws;                       // 64*768
    unsigned* x12wvkey = (unsigned*)(ws + 196608);            // 64*200
    float*    x12wvp   = (float*)(ws + 247808);               // 64*768
    float*    xwbase   = (float*)(ws + 444416);

    const size_t per_batch_f = (size_t)SS * HH + (size_t)SS * DWW;  // floats/batch
    size_t avail_f = (ws_size > 444416) ? (ws_size - 444416) / 4 : 0;
    int nb = (int)(avail_f / per_batch_f);
    if (nb > BB) nb = BB;
    if (nb < 1) nb = 1;  // requires ws_size >= ~2.5 MB

    float* xw_bert = xwbase;
    float* xw_wv   = xwbase + (size_t)nb * SS * HH;

    k_init<<<(BB * HH + 255) / 256, 256, 0, stream>>>(x12key, x12wvkey);
    k_masks<<<(BB * SS + 255) / 256, 256, 0, stream>>>(m1, m2, out);

    for (int b0 = 0; b0 < BB; b0 += nb) {
        int cb = (BB - b0 < nb) ? (BB - b0) : nb;
        dim3 g1(cb * 8, 12);
        k_gemm1<<<g1, 256, 0, stream>>>(x1, y, Wb, xw_bert, HH + 1, HH, b0);
        dim3 g2(cb * 8, (DWW + 63) / 64);
        k_gemm1<<<g2, 256, 0, stream>>>(tt, y, Wwv, xw_wv, DWW + 1, DWW, b0);
        dim3 g3(cb * 8);
        k_attn<<<g3, 256, 0, stream>>>(xw_bert, x2, m1, m2, x12key, HH, b0);
        dim3 g4(cb * 8);
        k_attn<<<g4, 256, 0, stream>>>(xw_wv, tt2, m1, m2, x12wvkey, DWW, b0);
    }

    k_wvproj<<<BB, 256, 0, stream>>>(x12wvkey, lwvw, lwvb, x12wvp);
    k_final<<<BB, 256, 0, stream>>>(x1h, x2h, x12key, x12wvp, lw, lb, out);
}

// Round 2
// 941.480 us; speedup vs baseline: 2.9129x; 2.9129x over previous
//
#include <hip/hip_runtime.h>

// ============================================================================
// Round 2: MFMA split-bf16 rewrite.
//   All GEMMs on v_mfma_f32_16x16x32_bf16. Exact-enough scores via hi/lo
//   split (3 MFMA); PV plain bf16; two-pass softmax (pass0 = hi-only approx
//   max, safe because P = exp(S - m_hat) is normalized by the sum of the
//   stored values). Prep kernels pre-convert W (transposed+padded) and KV
//   (hi/lo row-major + bf16 transposed) so hot loops stage with 16B copies.
// ============================================================================

#define BB 64
#define SS 512
#define HH 768
#define DWW 200

typedef __attribute__((ext_vector_type(8))) short bf16x8;
typedef __attribute__((ext_vector_type(4))) float f32x4;
typedef unsigned short u16;
typedef unsigned int u32;

__device__ __forceinline__ u32 fkey(float f) {
    u32 u = __float_as_uint(f);
    return (u & 0x80000000u) ? ~u : (u | 0x80000000u);
}
__device__ __forceinline__ float fdec(u32 k) {
    u32 u = (k & 0x80000000u) ? (k & 0x7fffffffu) : ~k;
    return __uint_as_float(u);
}
__device__ __forceinline__ u16 bf16rn(float f) {
    u32 u = __float_as_uint(f);
    return (u16)((u + 0x7fffu + ((u >> 16) & 1u)) >> 16);
}
__device__ __forceinline__ float bf2f(u16 h) {
    return __uint_as_float(((u32)h) << 16);
}
__device__ __forceinline__ f32x4 mm(bf16x8 a, bf16x8 b, f32x4 c) {
    return __builtin_amdgcn_mfma_f32_16x16x32_bf16(a, b, c, 0, 0, 0);
}

// ---------------------------------------------------------------------------
__global__ __launch_bounds__(256) void k_masks(const int* __restrict__ m1,
                                               const int* __restrict__ m2,
                                               float* __restrict__ out) {
    int i = blockIdx.x * 256 + threadIdx.x;
    if (i < BB * SS) {
        out[BB + i]           = (float)(1 - m1[i]);
        out[BB + BB * SS + i] = (float)(1 - m2[i]);
    }
}

__global__ __launch_bounds__(256) void k_init(u32* __restrict__ k1,
                                              u32* __restrict__ k2) {
    int i = blockIdx.x * 256 + threadIdx.x;
    u32 v = fkey(-1e5f);
    if (i < BB * HH) k1[i] = v;
    if (i < BB * DWW) k2[i] = v;
}

// ---------------------------------------------------------------------------
// prep: W [K][N] fp32 -> transposed padded bf16 hi/lo [NPAD][KPAD]
__global__ __launch_bounds__(256) void k_prep_w(const float* __restrict__ W,
                                                u16* __restrict__ tH, u16* __restrict__ tL,
                                                int K, int N, int KPAD, int NPAD) {
    int idx = blockIdx.x * 256 + threadIdx.x;
    if (idx >= NPAD * KPAD) return;
    int n = idx / KPAD, k = idx - n * KPAD;
    float v = (k < K && n < N) ? W[(size_t)k * N + n] : 0.f;
    u16 h = bf16rn(v);
    tH[idx] = h;
    tL[idx] = bf16rn(v - bf2f(h));
}

// ---------------------------------------------------------------------------
// prep: KV [B][512][D] fp32 -> hi/lo [cb][512][DPAD] + transposed bf16 [cb][DTPAD][512]
template<int D, int DPAD, int DTPAD>
__global__ __launch_bounds__(256) void k_prep_kv(const float* __restrict__ src,
                                                 u16* __restrict__ hi, u16* __restrict__ lo,
                                                 u16* __restrict__ tr, int b0) {
    __shared__ float tile[64][65];
    int cbi = blockIdx.x >> 3;
    int t0 = (blockIdx.x & 7) * 64;
    int d0 = blockIdx.y * 64;
    int bg = b0 + cbi;
    int tid = threadIdx.x;
    const float* base = src + ((size_t)bg * SS + t0) * D;
    int trr = tid >> 4, dc = (tid & 15) * 4;
#pragma unroll
    for (int i = 0; i < 4; ++i) {
        int t = trr + i * 16;
        int gd = d0 + dc;
        float v[4];
        if (gd + 3 < D) {
            float4 p = *(const float4*)(base + (size_t)t * D + gd);
            v[0] = p.x; v[1] = p.y; v[2] = p.z; v[3] = p.w;
        } else {
#pragma unroll
            for (int j = 0; j < 4; ++j) v[j] = (gd + j < D) ? base[(size_t)t * D + gd + j] : 0.f;
        }
#pragma unroll
        for (int j = 0; j < 4; ++j) tile[t][dc + j] = v[j];
        if (gd < DPAD) {
            size_t o = ((size_t)cbi * SS + t0 + t) * DPAD + gd;
#pragma unroll
            for (int j = 0; j < 4; ++j) {
                u16 h = bf16rn(v[j]);
                hi[o + j] = h;
                lo[o + j] = bf16rn(v[j] - bf2f(h));
            }
        }
    }
    __syncthreads();
#pragma unroll
    for (int i = 0; i < 4; ++i) {
        int drl = trr + i * 16;
        int gdr = d0 + drl;
        if (gdr < DTPAD) {
            int tcq = (tid & 15) * 4;
            size_t o = ((size_t)cbi * DTPAD + gdr) * SS + t0 + tcq;
#pragma unroll
            for (int j = 0; j < 4; ++j) tr[o + j] = bf16rn(tile[tcq + j][drl]);
        }
    }
}

// ---------------------------------------------------------------------------
// K1: XW = [X|y] @ W -> bf16 hi/lo, tile 64x128, 4 waves 32x64 each.
template<int KSTEPS, int KPAD>
__global__ __launch_bounds__(256) void k_gemm1(const float* __restrict__ X,
                                               const float* __restrict__ yv,
                                               const u16* __restrict__ wtH,
                                               const u16* __restrict__ wtL,
                                               u16* __restrict__ xwH, u16* __restrict__ xwL,
                                               int Din, int SX, int b0) {
    __shared__ short AsH[64 * 40], AsL[64 * 40], BsH[128 * 40], BsL[128 * 40];
    int cbi = blockIdx.x >> 3, stile = blockIdx.x & 7;
    int bg = b0 + cbi;
    int s0 = stile * 64;
    int n0 = blockIdx.y * 128;
    int tid = threadIdx.x;
    int lane = tid & 63, wid = tid >> 6;
    int wr = wid >> 1, wc = wid & 1;
    int l15 = lane & 15, kg = (lane >> 4) * 8, gb = (lane >> 4) * 4;

    f32x4 zz = {0.f, 0.f, 0.f, 0.f};
    f32x4 acc[2][4];
#pragma unroll
    for (int i = 0; i < 2; ++i)
#pragma unroll
        for (int j = 0; j < 4; ++j) acc[i][j] = zz;

    const float* Xb = X + (size_t)bg * SS * Din;
    const float* yb = yv + (size_t)bg * SS;

    for (int ks = 0; ks < KSTEPS; ++ks) {
        int k0 = ks * 32;
        {   // stage A (fp32 -> hi/lo)
            int r = tid >> 2, kq = (tid & 3) * 8;
            float v[8];
            const float* srow = Xb + (size_t)(s0 + r) * Din;
            if (k0 + kq + 7 < Din) {
                float4 p0 = *(const float4*)(srow + k0 + kq);
                float4 p1 = *(const float4*)(srow + k0 + kq + 4);
                v[0] = p0.x; v[1] = p0.y; v[2] = p0.z; v[3] = p0.w;
                v[4] = p1.x; v[5] = p1.y; v[6] = p1.z; v[7] = p1.w;
            } else {
#pragma unroll
                for (int j = 0; j < 8; ++j) {
                    int gk = k0 + kq + j;
                    v[j] = (gk < Din) ? srow[gk] : ((gk == Din) ? yb[s0 + r] : 0.f);
                }
            }
            bf16x8 hv, lv;
#pragma unroll
            for (int j = 0; j < 8; ++j) {
                u16 h = bf16rn(v[j]);
                hv[j] = (short)h;
                lv[j] = (short)bf16rn(v[j] - bf2f(h));
            }
            *(bf16x8*)(AsH + r * 40 + kq) = hv;
            *(bf16x8*)(AsL + r * 40 + kq) = lv;
        }
#pragma unroll
        for (int q = 0; q < 2; ++q) {  // stage B from pre-transposed W
            int slot = tid + q * 256;
            int nr = slot >> 2, kk = (slot & 3) * 8;
            size_t g = (size_t)(n0 + nr) * KPAD + k0 + kk;
            *(bf16x8*)(BsH + nr * 40 + kk) = *(const bf16x8*)(wtH + g);
            *(bf16x8*)(BsL + nr * 40 + kk) = *(const bf16x8*)(wtL + g);
        }
        __syncthreads();
        bf16x8 aH[2], aL[2], bH[4], bL[4];
#pragma unroll
        for (int mf = 0; mf < 2; ++mf) {
            int row = wr * 32 + mf * 16 + l15;
            aH[mf] = *(bf16x8*)(AsH + row * 40 + kg);
            aL[mf] = *(bf16x8*)(AsL + row * 40 + kg);
        }
#pragma unroll
        for (int nf = 0; nf < 4; ++nf) {
            int col = wc * 64 + nf * 16 + l15;
            bH[nf] = *(bf16x8*)(BsH + col * 40 + kg);
            bL[nf] = *(bf16x8*)(BsL + col * 40 + kg);
        }
#pragma unroll
        for (int mf = 0; mf < 2; ++mf)
#pragma unroll
            for (int nf = 0; nf < 4; ++nf) {
                acc[mf][nf] = mm(aH[mf], bH[nf], acc[mf][nf]);
                acc[mf][nf] = mm(aH[mf], bL[nf], acc[mf][nf]);
                acc[mf][nf] = mm(aL[mf], bH[nf], acc[mf][nf]);
            }
        __syncthreads();
    }
#pragma unroll
    for (int mf = 0; mf < 2; ++mf)
#pragma unroll
        for (int nf = 0; nf < 4; ++nf)
#pragma unroll
            for (int r = 0; r < 4; ++r) {
                int row = s0 + wr * 32 + mf * 16 + gb + r;
                int col = n0 + wc * 64 + nf * 16 + l15;
                if (col < SX) {
                    float c = acc[mf][nf][r];
                    u16 h = bf16rn(c);
                    size_t o = ((size_t)cbi * SS + row) * SX + col;
                    xwH[o] = h;
                    xwL[o] = bf16rn(c - bf2f(h));
                }
            }
}

// ---------------------------------------------------------------------------
// K2: fused attention, 32-row tile, 256 thr, two-pass scores + PV.
template<int KSTEPS, int SX, int DTPAD, int DCHUNKS, int DV>
__global__ __launch_bounds__(256, 2) void k_attn(
    const u16* __restrict__ xwH, const u16* __restrict__ xwL,
    const u16* __restrict__ kvH, const u16* __restrict__ kvL,
    const u16* __restrict__ kvT,
    const int* __restrict__ m1, const int* __restrict__ m2,
    u32* __restrict__ keys, int b0, int nwg) {
    __shared__ char smem[69632];
    short* P   = (short*)smem;                    // [32][520]
    short* BsH = (short*)(smem + 33280);          // [128][40]
    short* BsL = BsH + 5120;
    short* AsH = BsL + 5120;                      // [32][40]
    short* AsL = AsH + 1280;
    short* KT  = (short*)(smem + 33280);          // [128][136] (aliases Bs/As)
    u32*   rmaxk = (u32*)(smem + 68096);          // [32]
    float* rsumw = (float*)(smem + 68224);        // [4][32]
    float* rsumf = (float*)(smem + 68736);        // [32]
    u32*   m1v   = (u32*)(smem + 68864);          // [32]
    unsigned char* m2v = (unsigned char*)(smem + 68992);  // [512]

    int bid = blockIdx.x;
    int lb = (bid & 7) * (nwg >> 3) + (bid >> 3);  // XCD-contiguous remap
    int cbi = lb >> 4;
    int s0 = (lb & 15) * 32;
    int bg = b0 + cbi;
    int tid = threadIdx.x;
    int lane = tid & 63, wid = tid >> 6;
    int l15 = lane & 15, kg = (lane >> 4) * 8, gb = (lane >> 4) * 4;

    if (tid < 32) { rmaxk[tid] = 0u; m1v[tid] = (u32)m1[bg * SS + s0 + tid]; }
    if (tid < 128) rsumw[tid] = 0.f;
    for (int i = tid; i < SS; i += 256) m2v[i] = (unsigned char)m2[bg * SS + i];
    __syncthreads();

    const size_t rowb = (size_t)cbi * SS;
    f32x4 zz = {0.f, 0.f, 0.f, 0.f};

    for (int pass = 0; pass < 2; ++pass) {
        for (int tp = 0; tp < 4; ++tp) {
            int t0 = tp * 128;
            f32x4 acc[2][2];
            acc[0][0] = zz; acc[0][1] = zz; acc[1][0] = zz; acc[1][1] = zz;
            for (int ks = 0; ks < KSTEPS; ++ks) {
                int k0 = ks * 32;
                if (pass == 0) {  // hi-only staging
                    if (tid < 128) {
                        int r = tid >> 2, kk = (tid & 3) * 8;
                        *(bf16x8*)(AsH + r * 40 + kk) =
                            *(const bf16x8*)(xwH + (rowb + s0 + r) * SX + k0 + kk);
                    }
#pragma unroll
                    for (int q = 0; q < 2; ++q) {
                        int slot = tid + q * 256;
                        int tr = slot >> 2, kk = (slot & 3) * 8;
                        *(bf16x8*)(BsH + tr * 40 + kk) =
                            *(const bf16x8*)(kvH + (rowb + t0 + tr) * SX + k0 + kk);
                    }
                } else {
                    {
                        int q = tid & 127;
                        int r = q >> 2, kk = (q & 3) * 8;
                        const u16* src = (tid < 128) ? xwH : xwL;
                        short* dst = (tid < 128) ? AsH : AsL;
                        *(bf16x8*)(dst + r * 40 + kk) =
                            *(const bf16x8*)(src + (rowb + s0 + r) * SX + k0 + kk);
                    }
#pragma unroll
                    for (int q = 0; q < 2; ++q) {
                        int slot = tid + q * 256;
                        int tr = slot >> 2, kk = (slot & 3) * 8;
                        size_t g = (rowb + t0 + tr) * SX + k0 + kk;
                        *(bf16x8*)(BsH + tr * 40 + kk) = *(const bf16x8*)(kvH + g);
                        *(bf16x8*)(BsL + tr * 40 + kk) = *(const bf16x8*)(kvL + g);
                    }
                }
                __syncthreads();
                bf16x8 aH[2], bH[2];
#pragma unroll
                for (int mf = 0; mf < 2; ++mf)
                    aH[mf] = *(bf16x8*)(AsH + (mf * 16 + l15) * 40 + kg);
#pragma unroll
                for (int nf = 0; nf < 2; ++nf)
                    bH[nf] = *(bf16x8*)(BsH + (wid * 32 + nf * 16 + l15) * 40 + kg);
                if (pass == 0) {
#pragma unroll
                    for (int mf = 0; mf < 2; ++mf)
#pragma unroll
                        for (int nf = 0; nf < 2; ++nf)
                            acc[mf][nf] = mm(aH[mf], bH[nf], acc[mf][nf]);
                } else {
                    bf16x8 aL[2], bL[2];
#pragma unroll
                    for (int mf = 0; mf < 2; ++mf)
                        aL[mf] = *(bf16x8*)(AsL + (mf * 16 + l15) * 40 + kg);
#pragma unroll
                    for (int nf = 0; nf < 2; ++nf)
                        bL[nf] = *(bf16x8*)(BsL + (wid * 32 + nf * 16 + l15) * 40 + kg);
#pragma unroll
                    for (int mf = 0; mf < 2; ++mf)
#pragma unroll
                        for (int nf = 0; nf < 2; ++nf) {
                            acc[mf][nf] = mm(aH[mf], bH[nf], acc[mf][nf]);
                            acc[mf][nf] = mm(aH[mf], bL[nf], acc[mf][nf]);
                            acc[mf][nf] = mm(aL[mf], bH[nf], acc[mf][nf]);
                        }
                }
                __syncthreads();
            }
            if (pass == 0) {
#pragma unroll
                for (int mf = 0; mf < 2; ++mf)
#pragma unroll
                    for (int r = 0; r < 4; ++r) {
                        float v = -3.0e38f;
#pragma unroll
                        for (int nf = 0; nf < 2; ++nf) {
                            int t = t0 + wid * 32 + nf * 16 + l15;
                            float c = acc[mf][nf][r];
                            if (!m2v[t]) c = -1e-5f;
                            v = fmaxf(v, c);
                        }
                        v = fmaxf(v, __shfl_xor(v, 1));
                        v = fmaxf(v, __shfl_xor(v, 2));
                        v = fmaxf(v, __shfl_xor(v, 4));
                        v = fmaxf(v, __shfl_xor(v, 8));
                        if (l15 == 0) atomicMax(&rmaxk[mf * 16 + gb + r], fkey(v));
                    }
            } else {
#pragma unroll
                for (int mf = 0; mf < 2; ++mf)
#pragma unroll
                    for (int r = 0; r < 4; ++r) {
                        int row = mf * 16 + gb + r;
                        float m = fdec(rmaxk[row]);
                        float s = 0.f;
#pragma unroll
                        for (int nf = 0; nf < 2; ++nf) {
                            int t = t0 + wid * 32 + nf * 16 + l15;
                            float c = acc[mf][nf][r];
                            if (!m2v[t]) c = -1e-5f;
                            u16 h = bf16rn(__expf(c - m));
                            P[row * 520 + t] = (short)h;
                            s += bf2f(h);
                        }
                        s += __shfl_xor(s, 1);
                        s += __shfl_xor(s, 2);
                        s += __shfl_xor(s, 4);
                        s += __shfl_xor(s, 8);
                        if (l15 == 0) rsumw[wid * 32 + row] += s;
                    }
            }
        }
        __syncthreads();
    }
    if (tid < 32)
        rsumf[tid] = 1.0f / (rsumw[tid] + rsumw[32 + tid] + rsumw[64 + tid] + rsumw[96 + tid]);
    __syncthreads();

    // ---- PV + normalize + masked row-max ----
    for (int dc = 0; dc < DCHUNKS; ++dc) {
        f32x4 acc[2][2];
        acc[0][0] = zz; acc[0][1] = zz; acc[1][0] = zz; acc[1][1] = zz;
        for (int tc = 0; tc < 4; ++tc) {
#pragma unroll
            for (int q = 0; q < 8; ++q) {
                int slot = q * 256 + tid;
                int row = slot >> 4, c8 = (slot & 15) * 8;
                *(bf16x8*)(KT + row * 136 + c8) =
                    *(const bf16x8*)(kvT + ((size_t)cbi * DTPAD + dc * 128 + row) * SS + tc * 128 + c8);
            }
            __syncthreads();
#pragma unroll
            for (int ks2 = 0; ks2 < 4; ++ks2) {
                int tl = tc * 128 + ks2 * 32;
                bf16x8 a[2], b[2];
#pragma unroll
                for (int mf = 0; mf < 2; ++mf)
                    a[mf] = *(bf16x8*)(P + (mf * 16 + l15) * 520 + tl + kg);
#pragma unroll
                for (int nf = 0; nf < 2; ++nf)
                    b[nf] = *(bf16x8*)(KT + (wid * 32 + nf * 16 + l15) * 136 + ks2 * 32 + kg);
#pragma unroll
                for (int mf = 0; mf < 2; ++mf)
#pragma unroll
                    for (int nf = 0; nf < 2; ++nf)
                        acc[mf][nf] = mm(a[mf], b[nf], acc[mf][nf]);
            }
            __syncthreads();
        }
#pragma unroll
        for (int nf = 0; nf < 2; ++nf) {
            float mx = -3.0e38f;
#pragma unroll
            for (int mf = 0; mf < 2; ++mf)
#pragma unroll
                for (int r = 0; r < 4; ++r) {
                    int row = mf * 16 + gb + r;
                    if (m1v[row]) mx = fmaxf(mx, acc[mf][nf][r] * rsumf[row]);
                }
            mx = fmaxf(mx, __shfl_xor(mx, 16));
            mx = fmaxf(mx, __shfl_xor(mx, 32));
            if (lane < 16) {
                int d = dc * 128 + wid * 32 + nf * 16 + lane;
                if (d < DV) atomicMax(&keys[(size_t)bg * DV + d], fkey(mx));
            }
        }
    }
}

// ---------------------------------------------------------------------------
__global__ __launch_bounds__(256) void k_wvproj(const u32* __restrict__ wvkeys,
                                                const float* __restrict__ Wp,
                                                const float* __restrict__ bp,
                                                float* __restrict__ outp) {
    int b = blockIdx.x;
    __shared__ float xv[DWW];
    int tid = threadIdx.x;
    if (tid < DWW) xv[tid] = fdec(wvkeys[b * DWW + tid]);
    __syncthreads();
    for (int h = tid; h < HH; h += 256) {
        float acc = bp[h];
        for (int d = 0; d < DWW; ++d) acc += xv[d] * Wp[d * HH + h];
        outp[b * HH + h] = acc;
    }
}

__global__ __launch_bounds__(256) void k_final(const float* __restrict__ x1h,
                                               const float* __restrict__ x2h,
                                               const u32* __restrict__ keys,
                                               const float* __restrict__ wvp,
                                               const float* __restrict__ lw,
                                               const float* __restrict__ lb,
                                               float* __restrict__ out) {
    int b = blockIdx.x;
    int tid = threadIdx.x;
    float acc = 0.f;
    for (int i = tid; i < HH; i += 256) {
        acc += x1h[b * HH + i] * lw[i];
        acc += x2h[b * HH + i] * lw[HH + i];
        acc += fdec(keys[b * HH + i]) * lw[2 * HH + i];
        acc += wvp[b * HH + i] * lw[3 * HH + i];
    }
    __shared__ float red[4];
    int wid = tid >> 6, lane = tid & 63;
#pragma unroll
    for (int off = 32; off; off >>= 1) acc += __shfl_down(acc, off);
    if (lane == 0) red[wid] = acc;
    __syncthreads();
    if (tid == 0) {
        float z = red[0] + red[1] + red[2] + red[3] + lb[0];
        out[b] = 1.f / (1.f + __expf(-z));
    }
}

// ---------------------------------------------------------------------------
extern "C" void kernel_launch(void* const* d_in, const int* in_sizes, int n_in,
                              void* d_out, int out_size, void* d_ws, size_t ws_size,
                              hipStream_t stream) {
    const float* x1   = (const float*)d_in[0];
    const float* x1h  = (const float*)d_in[1];
    const int*   m1   = (const int*)d_in[2];
    const float* y    = (const float*)d_in[3];
    const float* x2   = (const float*)d_in[4];
    const float* x2h  = (const float*)d_in[5];
    const int*   m2   = (const int*)d_in[6];
    const float* tt   = (const float*)d_in[7];
    const float* tt2  = (const float*)d_in[8];
    const float* Wb   = (const float*)d_in[9];
    const float* Wwv  = (const float*)d_in[10];
    const float* lwvw = (const float*)d_in[11];
    const float* lwvb = (const float*)d_in[12];
    const float* lw   = (const float*)d_in[13];
    const float* lb   = (const float*)d_in[14];
    float* out = (float*)d_out;

    char* ws = (char*)d_ws;
    u32*   x12key   = (u32*)ws;                 // 64*768*4   = 196608
    u32*   x12wvkey = (u32*)(ws + 196608);      // 64*200*4   = 51200
    float* x12wvp   = (float*)(ws + 247808);    // 64*768*4   = 196608
    u16*   wbTH     = (u16*)(ws + 444416);      // 768*800*2  = 1228800
    u16*   wbTL     = (u16*)(ws + 1673216);
    u16*   wwTH     = (u16*)(ws + 2902016);     // 256*224*2  = 114688
    u16*   wwTL     = (u16*)(ws + 3016704);
    const size_t CB = 3131392;

    const size_t SB = 786432;   // 512*768*2 bytes
    const size_t SV = 229376;   // 512*224*2
    const size_t ST = 262144;   // 256*512*2
    const size_t perb = 5 * SB + 4 * SV + ST;   // 5,111,808 B/batch

    int nb = 1;
    if (ws_size > CB + perb) nb = (int)((ws_size - CB) / perb);
    if (nb > BB) nb = BB;
    if (nb < 1) nb = 1;

    size_t off = CB;
    u16* xwbH = (u16*)(ws + off); off += (size_t)nb * SB;
    u16* xwbL = (u16*)(ws + off); off += (size_t)nb * SB;
    u16* xwvH = (u16*)(ws + off); off += (size_t)nb * SV;
    u16* xwvL = (u16*)(ws + off); off += (size_t)nb * SV;
    u16* kvbH = (u16*)(ws + off); off += (size_t)nb * SB;
    u16* kvbL = (u16*)(ws + off); off += (size_t)nb * SB;
    u16* kvbT = (u16*)(ws + off); off += (size_t)nb * SB;
    u16* kvvH = (u16*)(ws + off); off += (size_t)nb * SV;
    u16* kvvL = (u16*)(ws + off); off += (size_t)nb * SV;
    u16* kvvT = (u16*)(ws + off); off += (size_t)nb * ST;

    k_init<<<(BB * HH + 255) / 256, 256, 0, stream>>>(x12key, x12wvkey);
    k_masks<<<(BB * SS + 255) / 256, 256, 0, stream>>>(m1, m2, out);
    k_prep_w<<<(768 * 800 + 255) / 256, 256, 0, stream>>>(Wb, wbTH, wbTL, 769, 768, 800, 768);
    k_prep_w<<<(256 * 224 + 255) / 256, 256, 0, stream>>>(Wwv, wwTH, wwTL, 201, 200, 224, 256);

    for (int b0 = 0; b0 < BB; b0 += nb) {
        int cb = BB - b0 < nb ? BB - b0 : nb;
        k_prep_kv<768, 768, 768><<<dim3(cb * 8, 12), 256, 0, stream>>>(x2, kvbH, kvbL, kvbT, b0);
        k_prep_kv<200, 224, 256><<<dim3(cb * 8, 4), 256, 0, stream>>>(tt2, kvvH, kvvL, kvvT, b0);
        k_gemm1<25, 800><<<dim3(cb * 8, 6), 256, 0, stream>>>(x1, y, wbTH, wbTL, xwbH, xwbL, 768, 768, b0);
        k_gemm1<7, 224><<<dim3(cb * 8, 2), 256, 0, stream>>>(tt, y, wwTH, wwTL, xwvH, xwvL, 200, 224, b0);
        int nwg = cb * 16;
        k_attn<24, 768, 768, 6, 768><<<nwg, 256, 0, stream>>>(
            xwbH, xwbL, kvbH, kvbL, kvbT, m1, m2, x12key, b0, nwg);
        k_attn<7, 224, 256, 2, 200><<<nwg, 256, 0, stream>>>(
            xwvH, xwvL, kvvH, kvvL, kvvT, m1, m2, x12wvkey, b0, nwg);
    }

    k_wvproj<<<BB, 256, 0, stream>>>(x12wvkey, lwvw, lwvb, x12wvp);
    k_final<<<BB, 256, 0, stream>>>(x1h, x2h, x12key, x12wvp, lw, lb, out);
}

// Round 3
// 574.858 us; speedup vs baseline: 4.7707x; 1.6378x over previous
//
#include <hip/hip_runtime.h>

// ============================================================================
// Round 3: decomposed MFMA pipeline, fp16 single-split numerics.
//   xw    = Xcat(fp16) @ (W_hi + W_lo)          [k_mm2, SPLIT_A=false, EPI=1]
//   S     = (xw_hi + xw_lo) @ kv(fp16)^T        [k_mm2, SPLIT_A=true,  EPI=0]
//   P     = exp(S - rowmax), fp16, exact max    [k_softmax]
//   V-max = rowmask+normalize+maxpool fused     [k_pv epilogue, atomicMax]
// All GEMMs: 128x128 tile, 4 waves, BK=32, global_load_lds(16B) staging into
// bank-balanced [slot][row][8] LDS. Two phases (bert then wv) so the
// workspace high-water mark stays ~305 MB (proven >=330 from round 2 FETCH).
// ============================================================================

#define BB 64
#define SS 512
#define HH 768
#define DWW 200

typedef __attribute__((ext_vector_type(8))) _Float16 f16x8;
typedef __attribute__((ext_vector_type(4))) _Float16 f16x4;
typedef __attribute__((ext_vector_type(4))) float f32x4;
typedef unsigned int u32;

__device__ __forceinline__ u32 fkey(float f) {
    u32 u = __float_as_uint(f);
    return (u & 0x80000000u) ? ~u : (u | 0x80000000u);
}
__device__ __forceinline__ float fdec(u32 k) {
    u32 u = (k & 0x80000000u) ? (k & 0x7fffffffu) : ~k;
    return __uint_as_float(u);
}
__device__ __forceinline__ f32x4 mm(f16x8 a, f16x8 b, f32x4 c) {
    return __builtin_amdgcn_mfma_f32_16x16x32_f16(a, b, c, 0, 0, 0);
}
__device__ __forceinline__ void gl16(const void* g, void* l) {
    __builtin_amdgcn_global_load_lds(
        (const __attribute__((address_space(1))) void*)g,
        (__attribute__((address_space(3))) void*)l, 16, 0, 0);
}

// ---------------------------------------------------------------------------
__global__ __launch_bounds__(256) void k_masks(const int* __restrict__ m1,
                                               const int* __restrict__ m2,
                                               float* __restrict__ out) {
    int i = blockIdx.x * 256 + threadIdx.x;
    if (i < BB * SS) {
        out[BB + i]           = (float)(1 - m1[i]);
        out[BB + BB * SS + i] = (float)(1 - m2[i]);
    }
}

__global__ __launch_bounds__(256) void k_init(u32* __restrict__ k1,
                                              u32* __restrict__ k2) {
    int i = blockIdx.x * 256 + threadIdx.x;
    u32 v = fkey(-1e5f);
    if (i < BB * HH) k1[i] = v;
    if (i < BB * DWW) k2[i] = v;
}

// ---------------------------------------------------------------------------
// W [K][N] fp32 -> transposed padded fp16 hi/lo [NPAD][KPAD]
__global__ __launch_bounds__(256) void k_prep_w(const float* __restrict__ W,
                                                _Float16* __restrict__ tH,
                                                _Float16* __restrict__ tL,
                                                int K, int N, int KPAD, int NPAD) {
    int idx = blockIdx.x * 256 + threadIdx.x;
    if (idx >= NPAD * KPAD) return;
    int n = idx / KPAD, k = idx - n * KPAD;
    float v = (k < K && n < N) ? W[(size_t)k * N + n] : 0.f;
    _Float16 h = (_Float16)v;
    tH[idx] = h;
    tL[idx] = (_Float16)(v - (float)h);
}

// ---------------------------------------------------------------------------
// Xcat = [X | y | 0pad] fp32 -> fp16 [cb][512][KPAD]
__global__ __launch_bounds__(256) void k_prep_x(const float* __restrict__ X,
                                                const float* __restrict__ y,
                                                _Float16* __restrict__ out,
                                                int Din, int KPAD, int b0) {
    int cbi = blockIdx.y, bg = b0 + cbi;
    int idx = (blockIdx.x * 256 + threadIdx.x) * 4;
    int s = idx / KPAD, k0 = idx - s * KPAD;
    const float* Xr = X + ((size_t)bg * SS + s) * Din;
    f16x4 o;
#pragma unroll
    for (int j = 0; j < 4; ++j) {
        int k = k0 + j;
        float v = (k < Din) ? Xr[k] : ((k == Din) ? y[(size_t)bg * SS + s] : 0.f);
        o[j] = (_Float16)v;
    }
    *(f16x4*)(out + ((size_t)cbi * SS + s) * KPAD + k0) = o;
}

// ---------------------------------------------------------------------------
// KV [B][512][D] fp32 -> fp16 [cb][512][DPAD]  +  fp16 transposed [cb][DTPAD][512]
template<int D, int DPAD, int DTPAD>
__global__ __launch_bounds__(256) void k_prep_kv(const float* __restrict__ src,
                                                 _Float16* __restrict__ kv,
                                                 _Float16* __restrict__ kvT, int b0) {
    __shared__ float tile[64][65];
    int cbi = blockIdx.x >> 3, t0 = (blockIdx.x & 7) * 64, d0 = blockIdx.y * 64;
    int bg = b0 + cbi, tid = threadIdx.x;
    int tr = tid >> 4, dc = (tid & 15) * 4;
#pragma unroll
    for (int i = 0; i < 4; ++i) {
        int t = tr + i * 16;
        int gd = d0 + dc;
        float v[4];
#pragma unroll
        for (int j = 0; j < 4; ++j) {
            int d = gd + j;
            v[j] = (d < D) ? src[((size_t)bg * SS + t0 + t) * D + d] : 0.f;
            tile[t][dc + j] = v[j];
        }
        if (gd < DPAD) {
            f16x4 o;
#pragma unroll
            for (int j = 0; j < 4; ++j) o[j] = (_Float16)v[j];
            *(f16x4*)(kv + ((size_t)cbi * SS + t0 + t) * DPAD + gd) = o;
        }
    }
    __syncthreads();
#pragma unroll
    for (int i = 0; i < 4; ++i) {
        int dl = tr + i * 16, gdr = d0 + dl;
        if (gdr < DTPAD) {
            int tc = (tid & 15) * 4;
            f16x4 o;
#pragma unroll
            for (int j = 0; j < 4; ++j) o[j] = (_Float16)tile[tc + j][dl];
            *(f16x4*)(kvT + ((size_t)cbi * DTPAD + gdr) * SS + t0 + tc) = o;
        }
    }
}

// ---------------------------------------------------------------------------
// Generic 2-MFMA-term GEMM: C = A * B^T where the split operand is (hi+lo).
//   SPLIT_A: arrays {AH, AL, B};  !SPLIT_A: arrays {A, BH, BL}.
// A rows from [cbi*aStride + s0*KA], B rows from [cbi*bStride + n0*KA].
// EPI=0: write fp32 S [cb][512][512].  EPI=1: write fp16 hi/lo, stride SXW.
template<int KSTEPS, int TN, bool SPLIT_A, int EPI>
__global__ __launch_bounds__(256) void k_mm2(
    const _Float16* __restrict__ g0, const _Float16* __restrict__ g1,
    const _Float16* __restrict__ g2, int KA,
    size_t aStride, size_t bStride,
    float* __restrict__ outS,
    _Float16* __restrict__ outH, _Float16* __restrict__ outL, int SXW,
    int nwg) {
    __shared__ __align__(16) char lds[24576];  // 3 arrays x [4 slot][128 row][8 f16]
    int bid = blockIdx.x;
    int lb = (bid & 7) * (nwg >> 3) + (bid >> 3);
    int cbi = lb / (4 * TN);
    int rest = lb - cbi * (4 * TN);
    int ts = rest / TN, tn = rest - ts * TN;
    int s0 = ts * 128, n0 = tn * 128;
    int tid = threadIdx.x, lane = tid & 63, wid = tid >> 6;
    int wr = wid >> 1, wc = wid & 1;
    int l15 = lane & 15, sl = lane >> 4, gb = (lane >> 4) * 4;

    size_t aBase = (size_t)cbi * aStride + (size_t)s0 * KA;
    size_t bBase = (size_t)cbi * bStride + (size_t)n0 * KA;
    const _Float16* src0 = g0 + aBase;
    const _Float16* src1 = g1 + (SPLIT_A ? aBase : bBase);
    const _Float16* src2 = g2 + bBase;

    f32x4 zz = {0.f, 0.f, 0.f, 0.f};
    f32x4 acc[4][4];
#pragma unroll
    for (int i = 0; i < 4; ++i)
#pragma unroll
        for (int j = 0; j < 4; ++j) acc[i][j] = zz;

#define FRAG(arr, row) (*(const f16x8*)(lds + (arr)*8192 + sl * 2048 + (row)*16))

    for (int ks = 0; ks < KSTEPS; ++ks) {
        int k0 = ks * 32;
#pragma unroll
        for (int i = 0; i < 6; ++i) {
            int c = wid + 4 * i;           // 24 chunks of 1KB
            int arr = c >> 3, sub = c & 7;
            int slot = sub >> 1, rh = sub & 1;
            const _Float16* gp = (arr == 0) ? src0 : ((arr == 1) ? src1 : src2);
            gp += (size_t)(rh * 64 + lane) * KA + k0 + slot * 8;
            gl16(gp, lds + c * 1024);
        }
        __syncthreads();
        if constexpr (SPLIT_A) {
            f16x8 a0[4], a1[4], b[4];
#pragma unroll
            for (int mf = 0; mf < 4; ++mf) {
                int row = wr * 64 + mf * 16 + l15;
                a0[mf] = FRAG(0, row);
                a1[mf] = FRAG(1, row);
            }
#pragma unroll
            for (int nf = 0; nf < 4; ++nf) b[nf] = FRAG(2, wc * 64 + nf * 16 + l15);
#pragma unroll
            for (int mf = 0; mf < 4; ++mf)
#pragma unroll
                for (int nf = 0; nf < 4; ++nf) {
                    acc[mf][nf] = mm(a0[mf], b[nf], acc[mf][nf]);
                    acc[mf][nf] = mm(a1[mf], b[nf], acc[mf][nf]);
                }
        } else {
            f16x8 a[4], b0[4], b1[4];
#pragma unroll
            for (int mf = 0; mf < 4; ++mf) a[mf] = FRAG(0, wr * 64 + mf * 16 + l15);
#pragma unroll
            for (int nf = 0; nf < 4; ++nf) {
                int row = wc * 64 + nf * 16 + l15;
                b0[nf] = FRAG(1, row);
                b1[nf] = FRAG(2, row);
            }
#pragma unroll
            for (int mf = 0; mf < 4; ++mf)
#pragma unroll
                for (int nf = 0; nf < 4; ++nf) {
                    acc[mf][nf] = mm(a[mf], b0[nf], acc[mf][nf]);
                    acc[mf][nf] = mm(a[mf], b1[nf], acc[mf][nf]);
                }
        }
        __syncthreads();
    }
#undef FRAG

#pragma unroll
    for (int mf = 0; mf < 4; ++mf)
#pragma unroll
        for (int nf = 0; nf < 4; ++nf)
#pragma unroll
            for (int r = 0; r < 4; ++r) {
                int s = s0 + wr * 64 + mf * 16 + gb + r;
                int col = n0 + wc * 64 + nf * 16 + l15;
                float v = acc[mf][nf][r];
                if constexpr (EPI == 0) {
                    outS[((size_t)cbi * SS + s) * SS + col] = v;
                } else {
                    if (col < SXW) {
                        _Float16 h = (_Float16)v;
                        size_t o = ((size_t)cbi * SS + s) * SXW + col;
                        outH[o] = h;
                        outL[o] = (_Float16)(v - (float)h);
                    }
                }
            }
}

// ---------------------------------------------------------------------------
// Row softmax: exact max, unnormalized fp16 P, reciprocal sums.
__global__ __launch_bounds__(256) void k_softmax(const float* __restrict__ S,
                                                 const int* __restrict__ m2,
                                                 _Float16* __restrict__ P,
                                                 float* __restrict__ rs, int b0) {
    int bid = blockIdx.x;
    int cbi = bid >> 7, rb = bid & 127;
    int wid = threadIdx.x >> 6, lane = threadIdx.x & 63;
    int row = rb * 4 + wid, bg = b0 + cbi;
    const float* Sr = S + ((size_t)cbi * SS + row) * SS + lane * 8;
    float4 v0 = *(const float4*)(Sr);
    float4 v1 = *(const float4*)(Sr + 4);
    int4 q0 = *(const int4*)(m2 + bg * SS + lane * 8);
    int4 q1 = *(const int4*)(m2 + bg * SS + lane * 8 + 4);
    float c[8] = {q0.x ? v0.x : -1e-5f, q0.y ? v0.y : -1e-5f,
                  q0.z ? v0.z : -1e-5f, q0.w ? v0.w : -1e-5f,
                  q1.x ? v1.x : -1e-5f, q1.y ? v1.y : -1e-5f,
                  q1.z ? v1.z : -1e-5f, q1.w ? v1.w : -1e-5f};
    float mx = c[0];
#pragma unroll
    for (int j = 1; j < 8; ++j) mx = fmaxf(mx, c[j]);
#pragma unroll
    for (int off = 1; off <= 32; off <<= 1) mx = fmaxf(mx, __shfl_xor(mx, off));
    f16x8 o;
    float sm = 0.f;
#pragma unroll
    for (int j = 0; j < 8; ++j) {
        _Float16 h = (_Float16)__expf(c[j] - mx);
        o[j] = h;
        sm += (float)h;
    }
#pragma unroll
    for (int off = 1; off <= 32; off <<= 1) sm += __shfl_xor(sm, off);
    *(f16x8*)(P + ((size_t)cbi * SS + row) * SS + lane * 8) = o;
    if (lane == 0) rs[cbi * SS + row] = 1.0f / sm;
}

// ---------------------------------------------------------------------------
// PV GEMM + fused normalize + row-mask + max-pool (atomicMax on ordered keys).
template<int TN, int DV>
__global__ __launch_bounds__(256) void k_pv(
    const _Float16* __restrict__ P, const _Float16* __restrict__ kvT,
    const float* __restrict__ rsum, const int* __restrict__ m1,
    u32* __restrict__ keys, int b0, int nwg) {
    __shared__ __align__(16) char lds[16384];  // 2 arrays
    __shared__ int m1v[128];
    __shared__ float rsv[128];
    int bid = blockIdx.x;
    int lb = (bid & 7) * (nwg >> 3) + (bid >> 3);
    int cbi = lb / (4 * TN);
    int rest = lb - cbi * (4 * TN);
    int ts = rest / TN, tn = rest - ts * TN;
    int s0 = ts * 128, d0 = tn * 128;
    int bg = b0 + cbi;
    int tid = threadIdx.x, lane = tid & 63, wid = tid >> 6;
    int wr = wid >> 1, wc = wid & 1;
    int l15 = lane & 15, sl = lane >> 4, gb = (lane >> 4) * 4;

    if (tid < 128) {
        m1v[tid] = m1[bg * SS + s0 + tid];
        rsv[tid] = rsum[cbi * SS + s0 + tid];
    }
    const _Float16* srcA = P + ((size_t)cbi * SS + s0) * SS;
    const _Float16* srcB = kvT + ((size_t)cbi * (TN * 128) + d0) * SS;

    f32x4 zz = {0.f, 0.f, 0.f, 0.f};
    f32x4 acc[4][4];
#pragma unroll
    for (int i = 0; i < 4; ++i)
#pragma unroll
        for (int j = 0; j < 4; ++j) acc[i][j] = zz;

#define FRAG(arr, row) (*(const f16x8*)(lds + (arr)*8192 + sl * 2048 + (row)*16))
    for (int ks = 0; ks < 16; ++ks) {
        int k0 = ks * 32;
#pragma unroll
        for (int i = 0; i < 4; ++i) {
            int c = wid + 4 * i;
            int arr = c >> 3, sub = c & 7;
            int slot = sub >> 1, rh = sub & 1;
            const _Float16* gp = (arr ? srcB : srcA) +
                                 (size_t)(rh * 64 + lane) * SS + k0 + slot * 8;
            gl16(gp, lds + c * 1024);
        }
        __syncthreads();
        f16x8 a[4], b[4];
#pragma unroll
        for (int mf = 0; mf < 4; ++mf) a[mf] = FRAG(0, wr * 64 + mf * 16 + l15);
#pragma unroll
        for (int nf = 0; nf < 4; ++nf) b[nf] = FRAG(1, wc * 64 + nf * 16 + l15);
#pragma unroll
        for (int mf = 0; mf < 4; ++mf)
#pragma unroll
            for (int nf = 0; nf < 4; ++nf) acc[mf][nf] = mm(a[mf], b[nf], acc[mf][nf]);
        __syncthreads();
    }
#undef FRAG

#pragma unroll
    for (int nf = 0; nf < 4; ++nf) {
        float mx = -3.0e38f;
#pragma unroll
        for (int mf = 0; mf < 4; ++mf)
#pragma unroll
            for (int r = 0; r < 4; ++r) {
                int srow = wr * 64 + mf * 16 + gb + r;
                if (m1v[srow]) mx = fmaxf(mx, acc[mf][nf][r] * rsv[srow]);
            }
        mx = fmaxf(mx, __shfl_xor(mx, 16));
        mx = fmaxf(mx, __shfl_xor(mx, 32));
        if (lane < 16) {
            int d = d0 + wc * 64 + nf * 16 + lane;
            if (d < DV) atomicMax(&keys[(size_t)bg * DV + d], fkey(mx));
        }
    }
}

// ---------------------------------------------------------------------------
__global__ __launch_bounds__(256) void k_wvproj(const u32* __restrict__ wvkeys,
                                                const float* __restrict__ Wp,
                                                const float* __restrict__ bp,
                                                float* __restrict__ outp) {
    int b = blockIdx.x;
    __shared__ float xv[DWW];
    int tid = threadIdx.x;
    if (tid < DWW) xv[tid] = fdec(wvkeys[b * DWW + tid]);
    __syncthreads();
    for (int h = tid; h < HH; h += 256) {
        float acc = bp[h];
        for (int d = 0; d < DWW; ++d) acc += xv[d] * Wp[d * HH + h];
        outp[b * HH + h] = acc;
    }
}

__global__ __launch_bounds__(256) void k_final(const float* __restrict__ x1h,
                                               const float* __restrict__ x2h,
                                               const u32* __restrict__ keys,
                                               const float* __restrict__ wvp,
                                               const float* __restrict__ lw,
                                               const float* __restrict__ lb,
                                               float* __restrict__ out) {
    int b = blockIdx.x;
    int tid = threadIdx.x;
    float acc = 0.f;
    for (int i = tid; i < HH; i += 256) {
        acc += x1h[b * HH + i] * lw[i];
        acc += x2h[b * HH + i] * lw[HH + i];
        acc += fdec(keys[b * HH + i]) * lw[2 * HH + i];
        acc += wvp[b * HH + i] * lw[3 * HH + i];
    }
    __shared__ float red[4];
    int wid = tid >> 6, lane = tid & 63;
#pragma unroll
    for (int off = 32; off; off >>= 1) acc += __shfl_down(acc, off);
    if (lane == 0) red[wid] = acc;
    __syncthreads();
    if (tid == 0) {
        float z = red[0] + red[1] + red[2] + red[3] + lb[0];
        out[b] = 1.f / (1.f + __expf(-z));
    }
}

// ---------------------------------------------------------------------------
extern "C" void kernel_launch(void* const* d_in, const int* in_sizes, int n_in,
                              void* d_out, int out_size, void* d_ws, size_t ws_size,
                              hipStream_t stream) {
    const float* x1   = (const float*)d_in[0];
    const float* x1h  = (const float*)d_in[1];
    const int*   m1   = (const int*)d_in[2];
    const float* y    = (const float*)d_in[3];
    const float* x2   = (const float*)d_in[4];
    const float* x2h  = (const float*)d_in[5];
    const int*   m2   = (const int*)d_in[6];
    const float* tt   = (const float*)d_in[7];
    const float* tt2  = (const float*)d_in[8];
    const float* Wb   = (const float*)d_in[9];
    const float* Wwv  = (const float*)d_in[10];
    const float* lwvw = (const float*)d_in[11];
    const float* lwvb = (const float*)d_in[12];
    const float* lw   = (const float*)d_in[13];
    const float* lb   = (const float*)d_in[14];
    float* out = (float*)d_out;
    char* ws = (char*)d_ws;

    // fixed region
    u32*      x12key   = (u32*)ws;                    // 196608
    u32*      x12wvkey = (u32*)(ws + 196608);         // 51200
    float*    x12wvp   = (float*)(ws + 247808);       // 196608
    float*    rsumBuf  = (float*)(ws + 444416);       // 131072
    _Float16* wbTH     = (_Float16*)(ws + 575488);    // 768*800*2 = 1228800
    _Float16* wbTL     = (_Float16*)(ws + 1804288);   // 1228800
    _Float16* wwTH     = (_Float16*)(ws + 3033088);   // 256*224*2 = 114688
    _Float16* wwTL     = (_Float16*)(ws + 3147776);   // 114688
    const size_t D0 = 3262464;

    k_init<<<(BB * HH + 255) / 256, 256, 0, stream>>>(x12key, x12wvkey);
    k_masks<<<(BB * SS + 255) / 256, 256, 0, stream>>>(m1, m2, out);
    k_prep_w<<<(768 * 800 + 255) / 256, 256, 0, stream>>>(Wb, wbTH, wbTL, 769, 768, 800, 768);
    k_prep_w<<<(256 * 224 + 255) / 256, 256, 0, stream>>>(Wwv, wwTH, wwTL, 201, 200, 224, 256);

    // ---------------- bert phase ----------------
    {
        const size_t perA = 1572864;                 // S(1MB)+P(0.5MB) / Xcat(0.82MB)
        const size_t perXW = 786432, perKV = 786432, perKT = 786432;
        const size_t perb = perA + 2 * perXW + perKV + perKT;  // 4718592
        int nb = 1;
        if (ws_size > D0 + perb) nb = (int)((ws_size - D0) / perb);
        if (nb > BB) nb = BB;
        if (nb < 1) nb = 1;

        _Float16* Xcat = (_Float16*)(ws + D0);
        float*    SBuf = (float*)(ws + D0);
        _Float16* PBuf = (_Float16*)(ws + D0 + (size_t)nb * 1048576);
        _Float16* xwH  = (_Float16*)(ws + D0 + (size_t)nb * perA);
        _Float16* xwL  = (_Float16*)((char*)xwH + (size_t)nb * perXW);
        _Float16* kv   = (_Float16*)((char*)xwL + (size_t)nb * perXW);
        _Float16* kvT  = (_Float16*)((char*)kv + (size_t)nb * perKV);

        for (int b0 = 0; b0 < BB; b0 += nb) {
            int cb = (BB - b0 < nb) ? (BB - b0) : nb;
            k_prep_kv<768, 768, 768><<<dim3(cb * 8, 12), 256, 0, stream>>>(x2, kv, kvT, b0);
            k_prep_x<<<dim3(400, cb), 256, 0, stream>>>(x1, y, Xcat, 768, 800, b0);
            k_mm2<25, 6, false, 1><<<cb * 24, 256, 0, stream>>>(
                Xcat, wbTH, wbTL, 800, (size_t)SS * 800, 0,
                nullptr, xwH, xwL, 768, cb * 24);
            k_mm2<24, 4, true, 0><<<cb * 16, 256, 0, stream>>>(
                xwH, xwL, kv, 768, (size_t)SS * 768, (size_t)SS * 768,
                SBuf, nullptr, nullptr, 0, cb * 16);
            k_softmax<<<cb * 128, 256, 0, stream>>>(SBuf, m2, PBuf, rsumBuf, b0);
            k_pv<6, 768><<<cb * 24, 256, 0, stream>>>(PBuf, kvT, rsumBuf, m1, x12key, b0, cb * 24);
        }
    }

    // ---------------- wv phase ----------------
    {
        const size_t perA = 1572864;
        const size_t perXW = 229376, perKV = 229376, perKT = 262144;
        const size_t perb = perA + 2 * perXW + perKV + perKT;  // 2523136
        int nb = 1;
        if (ws_size > D0 + perb) nb = (int)((ws_size - D0) / perb);
        if (nb > BB) nb = BB;
        if (nb < 1) nb = 1;

        _Float16* Xcat = (_Float16*)(ws + D0);
        float*    SBuf = (float*)(ws + D0);
        _Float16* PBuf = (_Float16*)(ws + D0 + (size_t)nb * 1048576);
        _Float16* xwH  = (_Float16*)(ws + D0 + (size_t)nb * perA);
        _Float16* xwL  = (_Float16*)((char*)xwH + (size_t)nb * perXW);
        _Float16* kv   = (_Float16*)((char*)xwL + (size_t)nb * perXW);
        _Float16* kvT  = (_Float16*)((char*)kv + (size_t)nb * perKV);

        for (int b0 = 0; b0 < BB; b0 += nb) {
            int cb = (BB - b0 < nb) ? (BB - b0) : nb;
            k_prep_kv<200, 224, 256><<<dim3(cb * 8, 4), 256, 0, stream>>>(tt2, kv, kvT, b0);
            k_prep_x<<<dim3(112, cb), 256, 0, stream>>>(tt, y, Xcat, 200, 224, b0);
            k_mm2<7, 2, false, 1><<<cb * 8, 256, 0, stream>>>(
                Xcat, wwTH, wwTL, 224, (size_t)SS * 224, 0,
                nullptr, xwH, xwL, 224, cb * 8);
            k_mm2<7, 4, true, 0><<<cb * 16, 256, 0, stream>>>(
                xwH, xwL, kv, 224, (size_t)SS * 224, (size_t)SS * 224,
                SBuf, nullptr, nullptr, 0, cb * 16);
            k_softmax<<<cb * 128, 256, 0, stream>>>(SBuf, m2, PBuf, rsumBuf, b0);
            k_pv<2, 200><<<cb * 8, 256, 0, stream>>>(PBuf, kvT, rsumBuf, m1, x12wvkey, b0, cb * 8);
        }
    }

    k_wvproj<<<BB, 256, 0, stream>>>(x12wvkey, lwvw, lwvb, x12wvp);
    k_final<<<BB, 256, 0, stream>>>(x1h, x2h, x12key, x12wvp, lw, lb, out);
}

// Round 4
// 566.716 us; speedup vs baseline: 4.8393x; 1.0144x over previous
//
#include <hip/hip_runtime.h>

// ============================================================================
// Round 4: same decomposition as round 3 (fp16 single-split numerics), plus:
//   - k_mmxw: xw GEMM reg-stages A from x1/y fp32 directly (prep_x removed),
//     T14 async-split (load early, cvt+ds_write after compute).
//   - All GEMMs double-buffered 2-phase: STAGE(buf^1,k+1) before compute(buf),
//     ONE barrier per K-step (loads drain under MFMA, not serially).
//   - k_prep_kv vectorized (float4 loads).
// Pipeline: xw = Xcat@(Wh+Wl) -> S = (xwH+xwL)@kv^T -> softmax -> PV+max fused.
// ============================================================================

#define BB 64
#define SS 512
#define HH 768
#define DWW 200

typedef __attribute__((ext_vector_type(8))) _Float16 f16x8;
typedef __attribute__((ext_vector_type(4))) _Float16 f16x4;
typedef __attribute__((ext_vector_type(4))) float f32x4;
typedef unsigned int u32;

__device__ __forceinline__ u32 fkey(float f) {
    u32 u = __float_as_uint(f);
    return (u & 0x80000000u) ? ~u : (u | 0x80000000u);
}
__device__ __forceinline__ float fdec(u32 k) {
    u32 u = (k & 0x80000000u) ? (k & 0x7fffffffu) : ~k;
    return __uint_as_float(u);
}
__device__ __forceinline__ f32x4 mm(f16x8 a, f16x8 b, f32x4 c) {
    return __builtin_amdgcn_mfma_f32_16x16x32_f16(a, b, c, 0, 0, 0);
}
__device__ __forceinline__ void gl16(const void* g, void* l) {
    __builtin_amdgcn_global_load_lds(
        (const __attribute__((address_space(1))) void*)g,
        (__attribute__((address_space(3))) void*)l, 16, 0, 0);
}

// ---------------------------------------------------------------------------
__global__ __launch_bounds__(256) void k_masks(const int* __restrict__ m1,
                                               const int* __restrict__ m2,
                                               float* __restrict__ out) {
    int i = blockIdx.x * 256 + threadIdx.x;
    if (i < BB * SS) {
        out[BB + i]           = (float)(1 - m1[i]);
        out[BB + BB * SS + i] = (float)(1 - m2[i]);
    }
}

__global__ __launch_bounds__(256) void k_init(u32* __restrict__ k1,
                                              u32* __restrict__ k2) {
    int i = blockIdx.x * 256 + threadIdx.x;
    u32 v = fkey(-1e5f);
    if (i < BB * HH) k1[i] = v;
    if (i < BB * DWW) k2[i] = v;
}

// ---------------------------------------------------------------------------
// W [K][N] fp32 -> transposed padded fp16 hi/lo [NPAD][KPAD]
__global__ __launch_bounds__(256) void k_prep_w(const float* __restrict__ W,
                                                _Float16* __restrict__ tH,
                                                _Float16* __restrict__ tL,
                                                int K, int N, int KPAD, int NPAD) {
    int idx = blockIdx.x * 256 + threadIdx.x;
    if (idx >= NPAD * KPAD) return;
    int n = idx / KPAD, k = idx - n * KPAD;
    float v = (k < K && n < N) ? W[(size_t)k * N + n] : 0.f;
    _Float16 h = (_Float16)v;
    tH[idx] = h;
    tL[idx] = (_Float16)(v - (float)h);
}

// ---------------------------------------------------------------------------
// KV [B][512][D] fp32 -> fp16 [cb][512][DPAD] + fp16 transposed [cb][DTPAD][512]
template<int D, int DPAD, int DTPAD>
__global__ __launch_bounds__(256) void k_prep_kv(const float* __restrict__ src,
                                                 _Float16* __restrict__ kv,
                                                 _Float16* __restrict__ kvT, int b0) {
    __shared__ float tile[64][65];
    int cbi = blockIdx.x >> 3, t0 = (blockIdx.x & 7) * 64, d0 = blockIdx.y * 64;
    int bg = b0 + cbi, tid = threadIdx.x;
    int tr = tid >> 4, dc = (tid & 15) * 4;
#pragma unroll
    for (int i = 0; i < 4; ++i) {
        int t = tr + i * 16;
        int gd = d0 + dc;
        float v[4];
        if (gd + 3 < D) {
            float4 p = *(const float4*)(src + ((size_t)bg * SS + t0 + t) * D + gd);
            v[0] = p.x; v[1] = p.y; v[2] = p.z; v[3] = p.w;
        } else {
#pragma unroll
            for (int j = 0; j < 4; ++j) {
                int d = gd + j;
                v[j] = (d < D) ? src[((size_t)bg * SS + t0 + t) * D + d] : 0.f;
            }
        }
#pragma unroll
        for (int j = 0; j < 4; ++j) tile[t][dc + j] = v[j];
        if (gd < DPAD) {
            f16x4 o;
#pragma unroll
            for (int j = 0; j < 4; ++j) o[j] = (_Float16)v[j];
            *(f16x4*)(kv + ((size_t)cbi * SS + t0 + t) * DPAD + gd) = o;
        }
    }
    __syncthreads();
#pragma unroll
    for (int i = 0; i < 4; ++i) {
        int dl = tr + i * 16, gdr = d0 + dl;
        if (gdr < DTPAD) {
            int tc = (tid & 15) * 4;
            f16x4 o;
#pragma unroll
            for (int j = 0; j < 4; ++j) o[j] = (_Float16)tile[tc + j][dl];
            *(f16x4*)(kvT + ((size_t)cbi * DTPAD + gdr) * SS + t0 + tc) = o;
        }
    }
}

// ---------------------------------------------------------------------------
// xw GEMM: [X|y](fp32, reg-staged+cvt) @ (W_hi + W_lo)(gl16) -> fp16 hi/lo.
// 128x128 tile, 4 waves, BK=32, double-buffered 2-phase.
template<int KSTEPS, int TN, int KPAD>
__global__ __launch_bounds__(256) void k_mmxw(
    const float* __restrict__ X, const float* __restrict__ yv,
    const _Float16* __restrict__ wTH, const _Float16* __restrict__ wTL,
    _Float16* __restrict__ outH, _Float16* __restrict__ outL,
    int Din, int SXW, int b0, int nwg) {
    __shared__ __align__(16) char lds[49152];   // 2 bufs x (A 8K | BH 8K | BL 8K)
    int bid = blockIdx.x;
    int lb = (bid & 7) * (nwg >> 3) + (bid >> 3);
    int cbi = lb / (4 * TN);
    int rest = lb - cbi * (4 * TN);
    int ts = rest / TN, tn = rest - ts * TN;
    int s0 = ts * 128, n0 = tn * 128;
    int tid = threadIdx.x, lane = tid & 63, wid = tid >> 6;
    int wr = wid >> 1, wc = wid & 1;
    int l15 = lane & 15, sl = lane >> 4, gb = sl * 4;
    int bg = b0 + cbi;

    const float* Xb = X + (size_t)bg * SS * Din;
    const float* yb = yv + (size_t)bg * SS;

    f32x4 zz = {0.f, 0.f, 0.f, 0.f};
    f32x4 acc[4][4];
#pragma unroll
    for (int i = 0; i < 4; ++i)
#pragma unroll
        for (int j = 0; j < 4; ++j) acc[i][j] = zz;

    float va[2][8];

#define LOADA(ks, q)                                                          \
    {                                                                         \
        int id = tid + (q) * 256;                                             \
        int row = id & 127, slot = id >> 7;                                   \
        int gc = (ks) * 32 + slot * 8;                                        \
        const float* Xr = Xb + (size_t)(s0 + row) * Din;                      \
        if (gc + 7 < Din) {                                                   \
            float4 p0 = *(const float4*)(Xr + gc);                            \
            float4 p1 = *(const float4*)(Xr + gc + 4);                        \
            va[q][0] = p0.x; va[q][1] = p0.y; va[q][2] = p0.z; va[q][3] = p0.w;\
            va[q][4] = p1.x; va[q][5] = p1.y; va[q][6] = p1.z; va[q][7] = p1.w;\
        } else {                                                              \
            _Pragma("unroll") for (int j = 0; j < 8; ++j) {                   \
                int gk = gc + j;                                              \
                va[q][j] = (gk < Din) ? Xr[gk]                                \
                                      : ((gk == Din) ? yb[s0 + row] : 0.f);   \
            }                                                                 \
        }                                                                     \
    }
#define WRITEA(buf, q)                                                        \
    {                                                                         \
        int id = tid + (q) * 256;                                             \
        int row = id & 127, slot = id >> 7;                                   \
        f16x8 o;                                                              \
        _Pragma("unroll") for (int j = 0; j < 8; ++j) o[j] = (_Float16)va[q][j];\
        *(f16x8*)(lds + (buf) * 24576 + slot * 2048 + row * 16) = o;          \
    }
#define STAGEB(buf, ks)                                                       \
    _Pragma("unroll") for (int i = 0; i < 4; ++i) {                           \
        int c = wid + 4 * i;                                                  \
        int arr = c >> 3, sub = c & 7, slot = sub >> 1, rh = sub & 1;         \
        const _Float16* gp = (arr ? wTL : wTH) +                              \
            (size_t)(n0 + rh * 64 + lane) * KPAD + (ks) * 32 + slot * 8;      \
        gl16(gp, lds + (buf) * 24576 + 8192 + c * 1024);                      \
    }

    LOADA(0, 0); LOADA(0, 1);
    STAGEB(0, 0);
    WRITEA(0, 0); WRITEA(0, 1);
    __syncthreads();
    int buf = 0;
    for (int ks = 0; ks < KSTEPS; ++ks) {
        if (ks + 1 < KSTEPS) {
            LOADA(ks + 1, 0); LOADA(ks + 1, 1);
            STAGEB(buf ^ 1, ks + 1);
        }
        char* base = lds + buf * 24576;
        f16x8 a[4], b0v[4], b1v[4];
#pragma unroll
        for (int mf = 0; mf < 4; ++mf)
            a[mf] = *(const f16x8*)(base + sl * 2048 + (wr * 64 + mf * 16 + l15) * 16);
#pragma unroll
        for (int nf = 0; nf < 4; ++nf) {
            int row = wc * 64 + nf * 16 + l15;
            b0v[nf] = *(const f16x8*)(base + 8192 + sl * 2048 + row * 16);
            b1v[nf] = *(const f16x8*)(base + 16384 + sl * 2048 + row * 16);
        }
#pragma unroll
        for (int mf = 0; mf < 4; ++mf)
#pragma unroll
            for (int nf = 0; nf < 4; ++nf) {
                acc[mf][nf] = mm(a[mf], b0v[nf], acc[mf][nf]);
                acc[mf][nf] = mm(a[mf], b1v[nf], acc[mf][nf]);
            }
        if (ks + 1 < KSTEPS) { WRITEA(buf ^ 1, 0); WRITEA(buf ^ 1, 1); }
        __syncthreads();
        buf ^= 1;
    }
#undef LOADA
#undef WRITEA
#undef STAGEB

#pragma unroll
    for (int mf = 0; mf < 4; ++mf)
#pragma unroll
        for (int nf = 0; nf < 4; ++nf)
#pragma unroll
            for (int r = 0; r < 4; ++r) {
                int s = s0 + wr * 64 + mf * 16 + gb + r;
                int col = n0 + wc * 64 + nf * 16 + l15;
                if (col < SXW) {
                    float v = acc[mf][nf][r];
                    _Float16 h = (_Float16)v;
                    size_t o = ((size_t)cbi * SS + s) * SXW + col;
                    outH[o] = h;
                    outL[o] = (_Float16)(v - (float)h);
                }
            }
}

// ---------------------------------------------------------------------------
// Scores GEMM: S = (xwH + xwL) @ kv^T, fp32 out. Double-buffered 2-phase.
template<int KSTEPS, int TN>
__global__ __launch_bounds__(256) void k_mm2(
    const _Float16* __restrict__ xwH, const _Float16* __restrict__ xwL,
    const _Float16* __restrict__ kv, int KA,
    size_t aStride, size_t bStride,
    float* __restrict__ outS, int nwg) {
    __shared__ __align__(16) char lds[49152];   // 2 bufs x 24KB
    int bid = blockIdx.x;
    int lb = (bid & 7) * (nwg >> 3) + (bid >> 3);
    int cbi = lb / (4 * TN);
    int rest = lb - cbi * (4 * TN);
    int ts = rest / TN, tn = rest - ts * TN;
    int s0 = ts * 128, n0 = tn * 128;
    int tid = threadIdx.x, lane = tid & 63, wid = tid >> 6;
    int wr = wid >> 1, wc = wid & 1;
    int l15 = lane & 15, sl = lane >> 4, gb = sl * 4;

    const _Float16* src0 = xwH + (size_t)cbi * aStride + (size_t)s0 * KA;
    const _Float16* src1 = xwL + (size_t)cbi * aStride + (size_t)s0 * KA;
    const _Float16* src2 = kv + (size_t)cbi * bStride + (size_t)n0 * KA;

    f32x4 zz = {0.f, 0.f, 0.f, 0.f};
    f32x4 acc[4][4];
#pragma unroll
    for (int i = 0; i < 4; ++i)
#pragma unroll
        for (int j = 0; j < 4; ++j) acc[i][j] = zz;

#define STAGE(buf, ks)                                                        \
    _Pragma("unroll") for (int i = 0; i < 6; ++i) {                           \
        int c = wid + 4 * i;                                                  \
        int arr = c >> 3, sub = c & 7, slot = sub >> 1, rh = sub & 1;         \
        const _Float16* gp = ((arr == 0) ? src0 : ((arr == 1) ? src1 : src2)) \
            + (size_t)(rh * 64 + lane) * KA + (ks) * 32 + slot * 8;           \
        gl16(gp, lds + (buf) * 24576 + c * 1024);                             \
    }

    STAGE(0, 0);
    __syncthreads();
    int buf = 0;
    for (int ks = 0; ks < KSTEPS; ++ks) {
        if (ks + 1 < KSTEPS) STAGE(buf ^ 1, ks + 1);
        char* base = lds + buf * 24576;
        f16x8 a0[4], a1[4], b[4];
#pragma unroll
        for (int mf = 0; mf < 4; ++mf) {
            int row = wr * 64 + mf * 16 + l15;
            a0[mf] = *(const f16x8*)(base + sl * 2048 + row * 16);
            a1[mf] = *(const f16x8*)(base + 8192 + sl * 2048 + row * 16);
        }
#pragma unroll
        for (int nf = 0; nf < 4; ++nf)
            b[nf] = *(const f16x8*)(base + 16384 + sl * 2048 + (wc * 64 + nf * 16 + l15) * 16);
#pragma unroll
        for (int mf = 0; mf < 4; ++mf)
#pragma unroll
            for (int nf = 0; nf < 4; ++nf) {
                acc[mf][nf] = mm(a0[mf], b[nf], acc[mf][nf]);
                acc[mf][nf] = mm(a1[mf], b[nf], acc[mf][nf]);
            }
        __syncthreads();
        buf ^= 1;
    }
#undef STAGE

#pragma unroll
    for (int mf = 0; mf < 4; ++mf)
#pragma unroll
        for (int nf = 0; nf < 4; ++nf)
#pragma unroll
            for (int r = 0; r < 4; ++r) {
                int s = s0 + wr * 64 + mf * 16 + gb + r;
                int col = n0 + wc * 64 + nf * 16 + l15;
                outS[((size_t)cbi * SS + s) * SS + col] = acc[mf][nf][r];
            }
}

// ---------------------------------------------------------------------------
// Row softmax: exact max, unnormalized fp16 P, reciprocal sums.
__global__ __launch_bounds__(256) void k_softmax(const float* __restrict__ S,
                                                 const int* __restrict__ m2,
                                                 _Float16* __restrict__ P,
                                                 float* __restrict__ rs, int b0) {
    int bid = blockIdx.x;
    int cbi = bid >> 7, rb = bid & 127;
    int wid = threadIdx.x >> 6, lane = threadIdx.x & 63;
    int row = rb * 4 + wid, bg = b0 + cbi;
    const float* Sr = S + ((size_t)cbi * SS + row) * SS + lane * 8;
    float4 v0 = *(const float4*)(Sr);
    float4 v1 = *(const float4*)(Sr + 4);
    int4 q0 = *(const int4*)(m2 + bg * SS + lane * 8);
    int4 q1 = *(const int4*)(m2 + bg * SS + lane * 8 + 4);
    float c[8] = {q0.x ? v0.x : -1e-5f, q0.y ? v0.y : -1e-5f,
                  q0.z ? v0.z : -1e-5f, q0.w ? v0.w : -1e-5f,
                  q1.x ? v1.x : -1e-5f, q1.y ? v1.y : -1e-5f,
                  q1.z ? v1.z : -1e-5f, q1.w ? v1.w : -1e-5f};
    float mx = c[0];
#pragma unroll
    for (int j = 1; j < 8; ++j) mx = fmaxf(mx, c[j]);
#pragma unroll
    for (int off = 1; off <= 32; off <<= 1) mx = fmaxf(mx, __shfl_xor(mx, off));
    f16x8 o;
    float sm = 0.f;
#pragma unroll
    for (int j = 0; j < 8; ++j) {
        _Float16 h = (_Float16)__expf(c[j] - mx);
        o[j] = h;
        sm += (float)h;
    }
#pragma unroll
    for (int off = 1; off <= 32; off <<= 1) sm += __shfl_xor(sm, off);
    *(f16x8*)(P + ((size_t)cbi * SS + row) * SS + lane * 8) = o;
    if (lane == 0) rs[cbi * SS + row] = 1.0f / sm;
}

// ---------------------------------------------------------------------------
// PV GEMM + fused normalize + row-mask + max-pool. Double-buffered 2-phase.
template<int TN, int DV>
__global__ __launch_bounds__(256) void k_pv(
    const _Float16* __restrict__ P, const _Float16* __restrict__ kvT,
    const float* __restrict__ rsum, const int* __restrict__ m1,
    u32* __restrict__ keys, int b0, int nwg) {
    __shared__ __align__(16) char lds[32768];   // 2 bufs x 16KB
    __shared__ int m1v[128];
    __shared__ float rsv[128];
    int bid = blockIdx.x;
    int lb = (bid & 7) * (nwg >> 3) + (bid >> 3);
    int cbi = lb / (4 * TN);
    int rest = lb - cbi * (4 * TN);
    int ts = rest / TN, tn = rest - ts * TN;
    int s0 = ts * 128, d0 = tn * 128;
    int bg = b0 + cbi;
    int tid = threadIdx.x, lane = tid & 63, wid = tid >> 6;
    int wr = wid >> 1, wc = wid & 1;
    int l15 = lane & 15, sl = lane >> 4, gb = sl * 4;

    if (tid < 128) {
        m1v[tid] = m1[bg * SS + s0 + tid];
        rsv[tid] = rsum[cbi * SS + s0 + tid];
    }
    const _Float16* srcA = P + ((size_t)cbi * SS + s0) * SS;
    const _Float16* srcB = kvT + ((size_t)cbi * (TN * 128) + d0) * SS;

    f32x4 zz = {0.f, 0.f, 0.f, 0.f};
    f32x4 acc[4][4];
#pragma unroll
    for (int i = 0; i < 4; ++i)
#pragma unroll
        for (int j = 0; j < 4; ++j) acc[i][j] = zz;

#define STAGE(buf, ks)                                                        \
    _Pragma("unroll") for (int i = 0; i < 4; ++i) {                           \
        int c = wid + 4 * i;                                                  \
        int arr = c >> 3, sub = c & 7, slot = sub >> 1, rh = sub & 1;         \
        const _Float16* gp = (arr ? srcB : srcA) +                            \
            (size_t)(rh * 64 + lane) * SS + (ks) * 32 + slot * 8;             \
        gl16(gp, lds + (buf) * 16384 + c * 1024);                             \
    }

    STAGE(0, 0);
    __syncthreads();
    int buf = 0;
    for (int ks = 0; ks < 16; ++ks) {
        if (ks + 1 < 16) STAGE(buf ^ 1, ks + 1);
        char* base = lds + buf * 16384;
        f16x8 a[4], b[4];
#pragma unroll
        for (int mf = 0; mf < 4; ++mf)
            a[mf] = *(const f16x8*)(base + sl * 2048 + (wr * 64 + mf * 16 + l15) * 16);
#pragma unroll
        for (int nf = 0; nf < 4; ++nf)
            b[nf] = *(const f16x8*)(base + 8192 + sl * 2048 + (wc * 64 + nf * 16 + l15) * 16);
#pragma unroll
        for (int mf = 0; mf < 4; ++mf)
#pragma unroll
            for (int nf = 0; nf < 4; ++nf) acc[mf][nf] = mm(a[mf], b[nf], acc[mf][nf]);
        __syncthreads();
        buf ^= 1;
    }
#undef STAGE

#pragma unroll
    for (int nf = 0; nf < 4; ++nf) {
        float mx = -3.0e38f;
#pragma unroll
        for (int mf = 0; mf < 4; ++mf)
#pragma unroll
            for (int r = 0; r < 4; ++r) {
                int srow = wr * 64 + mf * 16 + gb + r;
                if (m1v[srow]) mx = fmaxf(mx, acc[mf][nf][r] * rsv[srow]);
            }
        mx = fmaxf(mx, __shfl_xor(mx, 16));
        mx = fmaxf(mx, __shfl_xor(mx, 32));
        if (lane < 16) {
            int d = d0 + wc * 64 + nf * 16 + lane;
            if (d < DV) atomicMax(&keys[(size_t)bg * DV + d], fkey(mx));
        }
    }
}

// ---------------------------------------------------------------------------
__global__ __launch_bounds__(256) void k_wvproj(const u32* __restrict__ wvkeys,
                                                const float* __restrict__ Wp,
                                                const float* __restrict__ bp,
                                                float* __restrict__ outp) {
    int b = blockIdx.x;
    __shared__ float xv[DWW];
    int tid = threadIdx.x;
    if (tid < DWW) xv[tid] = fdec(wvkeys[b * DWW + tid]);
    __syncthreads();
    for (int h = tid; h < HH; h += 256) {
        float acc = bp[h];
        for (int d = 0; d < DWW; ++d) acc += xv[d] * Wp[d * HH + h];
        outp[b * HH + h] = acc;
    }
}

__global__ __launch_bounds__(256) void k_final(const float* __restrict__ x1h,
                                               const float* __restrict__ x2h,
                                               const u32* __restrict__ keys,
                                               const float* __restrict__ wvp,
                                               const float* __restrict__ lw,
                                               const float* __restrict__ lb,
                                               float* __restrict__ out) {
    int b = blockIdx.x;
    int tid = threadIdx.x;
    float acc = 0.f;
    for (int i = tid; i < HH; i += 256) {
        acc += x1h[b * HH + i] * lw[i];
        acc += x2h[b * HH + i] * lw[HH + i];
        acc += fdec(keys[b * HH + i]) * lw[2 * HH + i];
        acc += wvp[b * HH + i] * lw[3 * HH + i];
    }
    __shared__ float red[4];
    int wid = tid >> 6, lane = tid & 63;
#pragma unroll
    for (int off = 32; off; off >>= 1) acc += __shfl_down(acc, off);
    if (lane == 0) red[wid] = acc;
    __syncthreads();
    if (tid == 0) {
        float z = red[0] + red[1] + red[2] + red[3] + lb[0];
        out[b] = 1.f / (1.f + __expf(-z));
    }
}

// ---------------------------------------------------------------------------
extern "C" void kernel_launch(void* const* d_in, const int* in_sizes, int n_in,
                              void* d_out, int out_size, void* d_ws, size_t ws_size,
                              hipStream_t stream) {
    const float* x1   = (const float*)d_in[0];
    const float* x1h  = (const float*)d_in[1];
    const int*   m1   = (const int*)d_in[2];
    const float* y    = (const float*)d_in[3];
    const float* x2   = (const float*)d_in[4];
    const float* x2h  = (const float*)d_in[5];
    const int*   m2   = (const int*)d_in[6];
    const float* tt   = (const float*)d_in[7];
    const float* tt2  = (const float*)d_in[8];
    const float* Wb   = (const float*)d_in[9];
    const float* Wwv  = (const float*)d_in[10];
    const float* lwvw = (const float*)d_in[11];
    const float* lwvb = (const float*)d_in[12];
    const float* lw   = (const float*)d_in[13];
    const float* lb   = (const float*)d_in[14];
    float* out = (float*)d_out;
    char* ws = (char*)d_ws;

    // fixed region
    u32*      x12key   = (u32*)ws;                    // 196608
    u32*      x12wvkey = (u32*)(ws + 196608);         // 51200
    float*    x12wvp   = (float*)(ws + 247808);       // 196608
    float*    rsumBuf  = (float*)(ws + 444416);       // 131072
    _Float16* wbTH     = (_Float16*)(ws + 575488);    // 768*800*2 = 1228800
    _Float16* wbTL     = (_Float16*)(ws + 1804288);   // 1228800
    _Float16* wwTH     = (_Float16*)(ws + 3033088);   // 256*224*2 = 114688
    _Float16* wwTL     = (_Float16*)(ws + 3147776);   // 114688
    const size_t D0 = 3262464;

    k_init<<<(BB * HH + 255) / 256, 256, 0, stream>>>(x12key, x12wvkey);
    k_masks<<<(BB * SS + 255) / 256, 256, 0, stream>>>(m1, m2, out);
    k_prep_w<<<(768 * 800 + 255) / 256, 256, 0, stream>>>(Wb, wbTH, wbTL, 769, 768, 800, 768);
    k_prep_w<<<(256 * 224 + 255) / 256, 256, 0, stream>>>(Wwv, wwTH, wwTL, 201, 200, 224, 256);

    // ---------------- bert phase ----------------
    {
        const size_t perA = 1572864;                 // S (1MB) + P (0.5MB)
        const size_t perXW = 786432, perKV = 786432, perKT = 786432;
        const size_t perb = perA + 2 * perXW + perKV + perKT;
        int nb = 1;
        if (ws_size > D0 + perb) nb = (int)((ws_size - D0) / perb);
        if (nb > BB) nb = BB;
        if (nb < 1) nb = 1;

        float*    SBuf = (float*)(ws + D0);
        _Float16* PBuf = (_Float16*)(ws + D0 + (size_t)nb * 1048576);
        _Float16* xwH  = (_Float16*)(ws + D0 + (size_t)nb * perA);
        _Float16* xwL  = (_Float16*)((char*)xwH + (size_t)nb * perXW);
        _Float16* kv   = (_Float16*)((char*)xwL + (size_t)nb * perXW);
        _Float16* kvT  = (_Float16*)((char*)kv + (size_t)nb * perKV);

        for (int b0 = 0; b0 < BB; b0 += nb) {
            int cb = (BB - b0 < nb) ? (BB - b0) : nb;
            k_prep_kv<768, 768, 768><<<dim3(cb * 8, 12), 256, 0, stream>>>(x2, kv, kvT, b0);
            k_mmxw<25, 6, 800><<<cb * 24, 256, 0, stream>>>(
                x1, y, wbTH, wbTL, xwH, xwL, 768, 768, b0, cb * 24);
            k_mm2<24, 4><<<cb * 16, 256, 0, stream>>>(
                xwH, xwL, kv, 768, (size_t)SS * 768, (size_t)SS * 768, SBuf, cb * 16);
            k_softmax<<<cb * 128, 256, 0, stream>>>(SBuf, m2, PBuf, rsumBuf, b0);
            k_pv<6, 768><<<cb * 24, 256, 0, stream>>>(PBuf, kvT, rsumBuf, m1, x12key, b0, cb * 24);
        }
    }

    // ---------------- wv phase ----------------
    {
        const size_t perA = 1572864;
        const size_t perXW = 229376, perKV = 229376, perKT = 262144;
        const size_t perb = perA + 2 * perXW + perKV + perKT;
        int nb = 1;
        if (ws_size > D0 + perb) nb = (int)((ws_size - D0) / perb);
        if (nb > BB) nb = BB;
        if (nb < 1) nb = 1;

        float*    SBuf = (float*)(ws + D0);
        _Float16* PBuf = (_Float16*)(ws + D0 + (size_t)nb * 1048576);
        _Float16* xwH  = (_Float16*)(ws + D0 + (size_t)nb * perA);
        _Float16* xwL  = (_Float16*)((char*)xwH + (size_t)nb * perXW);
        _Float16* kv   = (_Float16*)((char*)xwL + (size_t)nb * perXW);
        _Float16* kvT  = (_Float16*)((char*)kv + (size_t)nb * perKV);

        for (int b0 = 0; b0 < BB; b0 += nb) {
            int cb = (BB - b0 < nb) ? (BB - b0) : nb;
            k_prep_kv<200, 224, 256><<<dim3(cb * 8, 4), 256, 0, stream>>>(tt2, kv, kvT, b0);
            k_mmxw<7, 2, 224><<<cb * 8, 256, 0, stream>>>(
                tt, y, wwTH, wwTL, xwH, xwL, 200, 224, b0, cb * 8);
            k_mm2<7, 4><<<cb * 16, 256, 0, stream>>>(
                xwH, xwL, kv, 224, (size_t)SS * 224, (size_t)SS * 224, SBuf, cb * 16);
            k_softmax<<<cb * 128, 256, 0, stream>>>(SBuf, m2, PBuf, rsumBuf, b0);
            k_pv<2, 200><<<cb * 8, 256, 0, stream>>>(PBuf, kvT, rsumBuf, m1, x12wvkey, b0, cb * 8);
        }
    }

    k_wvproj<<<BB, 256, 0, stream>>>(x12wvkey, lwvw, lwvb, x12wvp);
    k_final<<<BB, 256, 0, stream>>>(x1h, x2h, x12key, x12wvp, lw, lb, out);
}

// Round 5
// 469.416 us; speedup vs baseline: 5.8423x; 1.2073x over previous
//
#include <hip/hip_runtime.h>

// ============================================================================
// Round 5: all GEMMs 1-term fp16 (dropped W-lo and xw-lo; error analysis:
// X-cast+kv-cast already dominate, score RMS err 1.1e-2 -> 1.55e-2, absmax
// ~0.0055 vs thr 0.02). Unified k_mm1: 128x128 tile, 4 waves, BK=64,
// single-buffer 2-barrier (32 MFMA per barrier pair), 32KB LDS (5 blocks/CU),
// gl16 staging. Epilogues: EPI=0 fp32 S, EPI=1 fp16 out, EPI=2 fused
// normalize+rowmask+maxpool (atomicMax on ordered keys).
// Pipeline: prep_kv, prep_x -> xw -> scores -> softmax -> pv.
// ============================================================================

#define BB 64
#define SS 512
#define HH 768
#define DWW 200

typedef __attribute__((ext_vector_type(8))) _Float16 f16x8;
typedef __attribute__((ext_vector_type(4))) _Float16 f16x4;
typedef __attribute__((ext_vector_type(4))) float f32x4;
typedef unsigned int u32;

__device__ __forceinline__ u32 fkey(float f) {
    u32 u = __float_as_uint(f);
    return (u & 0x80000000u) ? ~u : (u | 0x80000000u);
}
__device__ __forceinline__ float fdec(u32 k) {
    u32 u = (k & 0x80000000u) ? (k & 0x7fffffffu) : ~k;
    return __uint_as_float(u);
}
__device__ __forceinline__ f32x4 mm(f16x8 a, f16x8 b, f32x4 c) {
    return __builtin_amdgcn_mfma_f32_16x16x32_f16(a, b, c, 0, 0, 0);
}
__device__ __forceinline__ void gl16(const void* g, void* l) {
    __builtin_amdgcn_global_load_lds(
        (const __attribute__((address_space(1))) void*)g,
        (__attribute__((address_space(3))) void*)l, 16, 0, 0);
}

// ---------------------------------------------------------------------------
__global__ __launch_bounds__(256) void k_masks(const int* __restrict__ m1,
                                               const int* __restrict__ m2,
                                               float* __restrict__ out) {
    int i = blockIdx.x * 256 + threadIdx.x;
    if (i < BB * SS) {
        out[BB + i]           = (float)(1 - m1[i]);
        out[BB + BB * SS + i] = (float)(1 - m2[i]);
    }
}

__global__ __launch_bounds__(256) void k_init(u32* __restrict__ k1,
                                              u32* __restrict__ k2) {
    int i = blockIdx.x * 256 + threadIdx.x;
    u32 v = fkey(-1e5f);
    if (i < BB * HH) k1[i] = v;
    if (i < BB * DWW) k2[i] = v;
}

// ---------------------------------------------------------------------------
// W [K][N] fp32 -> transposed padded fp16 [NPAD][KPAD]
__global__ __launch_bounds__(256) void k_prep_w(const float* __restrict__ W,
                                                _Float16* __restrict__ tH,
                                                int K, int N, int KPAD, int NPAD) {
    int idx = blockIdx.x * 256 + threadIdx.x;
    if (idx >= NPAD * KPAD) return;
    int n = idx / KPAD, k = idx - n * KPAD;
    float v = (k < K && n < N) ? W[(size_t)k * N + n] : 0.f;
    tH[idx] = (_Float16)v;
}

// ---------------------------------------------------------------------------
// Xcat = [X | y | 0pad] fp32 -> fp16 [cb][512][KPAD]
__global__ __launch_bounds__(256) void k_prep_x(const float* __restrict__ X,
                                                const float* __restrict__ y,
                                                _Float16* __restrict__ out,
                                                int Din, int KPAD, int b0) {
    int cbi = blockIdx.y, bg = b0 + cbi;
    int idx = (blockIdx.x * 256 + threadIdx.x) * 4;
    int s = idx / KPAD, k0 = idx - s * KPAD;
    const float* Xr = X + ((size_t)bg * SS + s) * Din;
    f16x4 o;
    if (k0 + 3 < Din) {
        float4 p = *(const float4*)(Xr + k0);
        o[0] = (_Float16)p.x; o[1] = (_Float16)p.y;
        o[2] = (_Float16)p.z; o[3] = (_Float16)p.w;
    } else {
#pragma unroll
        for (int j = 0; j < 4; ++j) {
            int k = k0 + j;
            float v = (k < Din) ? Xr[k] : ((k == Din) ? y[(size_t)bg * SS + s] : 0.f);
            o[j] = (_Float16)v;
        }
    }
    *(f16x4*)(out + ((size_t)cbi * SS + s) * KPAD + k0) = o;
}

// ---------------------------------------------------------------------------
// KV [B][512][D] fp32 -> fp16 [cb][512][DPAD] + fp16 transposed [cb][DTPAD][512]
template<int D, int DPAD, int DTPAD>
__global__ __launch_bounds__(256) void k_prep_kv(const float* __restrict__ src,
                                                 _Float16* __restrict__ kv,
                                                 _Float16* __restrict__ kvT, int b0) {
    __shared__ float tile[64][65];
    int cbi = blockIdx.x >> 3, t0 = (blockIdx.x & 7) * 64, d0 = blockIdx.y * 64;
    int bg = b0 + cbi, tid = threadIdx.x;
    int tr = tid >> 4, dc = (tid & 15) * 4;
#pragma unroll
    for (int i = 0; i < 4; ++i) {
        int t = tr + i * 16;
        int gd = d0 + dc;
        float v[4];
        if (gd + 3 < D) {
            float4 p = *(const float4*)(src + ((size_t)bg * SS + t0 + t) * D + gd);
            v[0] = p.x; v[1] = p.y; v[2] = p.z; v[3] = p.w;
        } else {
#pragma unroll
            for (int j = 0; j < 4; ++j) {
                int d = gd + j;
                v[j] = (d < D) ? src[((size_t)bg * SS + t0 + t) * D + d] : 0.f;
            }
        }
#pragma unroll
        for (int j = 0; j < 4; ++j) tile[t][dc + j] = v[j];
        if (gd < DPAD) {
            f16x4 o;
#pragma unroll
            for (int j = 0; j < 4; ++j) o[j] = (_Float16)v[j];
            *(f16x4*)(kv + ((size_t)cbi * SS + t0 + t) * DPAD + gd) = o;
        }
    }
    __syncthreads();
#pragma unroll
    for (int i = 0; i < 4; ++i) {
        int dl = tr + i * 16, gdr = d0 + dl;
        if (gdr < DTPAD) {
            int tc = (tid & 15) * 4;
            f16x4 o;
#pragma unroll
            for (int j = 0; j < 4; ++j) o[j] = (_Float16)tile[tc + j][dl];
            *(f16x4*)(kvT + ((size_t)cbi * DTPAD + gdr) * SS + t0 + tc) = o;
        }
    }
}

// ---------------------------------------------------------------------------
// Unified 1-term GEMM: C[128x128] = A[128xK] * B[128xK]^T per tile.
// BK=64, single 32KB LDS buffer, 2 barriers / K-step, 32 MFMA between.
// EPI=0: fp32 S out. EPI=1: fp16 out (stride SXW = TN*128). EPI=2: PV epilogue.
template<int KSTEPS, int TN, int EPI>
__global__ __launch_bounds__(256) void k_mm1(
    const _Float16* __restrict__ A, const _Float16* __restrict__ B, int KA,
    size_t aStride, size_t bStride,
    float* __restrict__ outS,
    _Float16* __restrict__ outH, int SXW,
    const float* __restrict__ rsum, const int* __restrict__ m1,
    u32* __restrict__ keys, int DV,
    int b0, int nwg) {
    __shared__ __align__(16) char lds[32768];  // [2 arr][8 slot][128 row][8 f16]
    __shared__ int m1v[128];
    __shared__ float rsv[128];

    int bid = blockIdx.x;
    int lb = (bid & 7) * (nwg >> 3) + (bid >> 3);  // XCD-contiguous remap
    int cbi = lb / (4 * TN);
    int rest = lb - cbi * (4 * TN);
    int ts = rest / TN, tn = rest - ts * TN;
    int s0 = ts * 128, n0 = tn * 128;
    int tid = threadIdx.x, lane = tid & 63, wid = tid >> 6;
    int wr = wid >> 1, wc = wid & 1;
    int l15 = lane & 15, sl = lane >> 4, gb = sl * 4;

    const _Float16* srcA = A + (size_t)cbi * aStride + (size_t)s0 * KA;
    const _Float16* srcB = B + (size_t)cbi * bStride + (size_t)n0 * KA;

    if constexpr (EPI == 2) {
        if (tid < 128) {
            int bg = b0 + cbi;
            m1v[tid] = m1[bg * SS + s0 + tid];
            rsv[tid] = rsum[cbi * SS + s0 + tid];
        }
    }

    f32x4 zz = {0.f, 0.f, 0.f, 0.f};
    f32x4 acc[4][4];
#pragma unroll
    for (int i = 0; i < 4; ++i)
#pragma unroll
        for (int j = 0; j < 4; ++j) acc[i][j] = zz;

    for (int ks = 0; ks < KSTEPS; ++ks) {
        // stage 32 chunks of 1KB: arr = c>>4, slot = (c&15)>>1, rowhalf = c&1
#pragma unroll
        for (int i = 0; i < 8; ++i) {
            int c = wid + 4 * i;
            int arr = c >> 4, sub = c & 15, slot = sub >> 1, rh = sub & 1;
            const _Float16* gp = (arr ? srcB : srcA) +
                (size_t)(rh * 64 + lane) * KA + ks * 64 + slot * 8;
            gl16(gp, lds + c * 1024);
        }
        __syncthreads();
#pragma unroll
        for (int kk = 0; kk < 2; ++kk) {
            f16x8 a[4], b[4];
#pragma unroll
            for (int mf = 0; mf < 4; ++mf)
                a[mf] = *(const f16x8*)(lds + kk * 8192 + sl * 2048 +
                                        (wr * 64 + mf * 16 + l15) * 16);
#pragma unroll
            for (int nf = 0; nf < 4; ++nf)
                b[nf] = *(const f16x8*)(lds + 16384 + kk * 8192 + sl * 2048 +
                                        (wc * 64 + nf * 16 + l15) * 16);
#pragma unroll
            for (int mf = 0; mf < 4; ++mf)
#pragma unroll
                for (int nf = 0; nf < 4; ++nf)
                    acc[mf][nf] = mm(a[mf], b[nf], acc[mf][nf]);
        }
        __syncthreads();
    }

    if constexpr (EPI == 0) {
#pragma unroll
        for (int mf = 0; mf < 4; ++mf)
#pragma unroll
            for (int nf = 0; nf < 4; ++nf)
#pragma unroll
                for (int r = 0; r < 4; ++r) {
                    int s = s0 + wr * 64 + mf * 16 + gb + r;
                    int col = n0 + wc * 64 + nf * 16 + l15;
                    outS[((size_t)cbi * SS + s) * SS + col] = acc[mf][nf][r];
                }
    } else if constexpr (EPI == 1) {
#pragma unroll
        for (int mf = 0; mf < 4; ++mf)
#pragma unroll
            for (int nf = 0; nf < 4; ++nf)
#pragma unroll
                for (int r = 0; r < 4; ++r) {
                    int s = s0 + wr * 64 + mf * 16 + gb + r;
                    int col = n0 + wc * 64 + nf * 16 + l15;
                    outH[((size_t)cbi * SS + s) * SXW + col] = (_Float16)acc[mf][nf][r];
                }
    } else {
        int bg = b0 + cbi;
#pragma unroll
        for (int nf = 0; nf < 4; ++nf) {
            float mx = -3.0e38f;
#pragma unroll
            for (int mf = 0; mf < 4; ++mf)
#pragma unroll
                for (int r = 0; r < 4; ++r) {
                    int srow = wr * 64 + mf * 16 + gb + r;
                    if (m1v[srow]) mx = fmaxf(mx, acc[mf][nf][r] * rsv[srow]);
                }
            mx = fmaxf(mx, __shfl_xor(mx, 16));
            mx = fmaxf(mx, __shfl_xor(mx, 32));
            if (lane < 16) {
                int d = n0 + wc * 64 + nf * 16 + lane;
                if (d < DV) atomicMax(&keys[(size_t)bg * DV + d], fkey(mx));
            }
        }
    }
}

// ---------------------------------------------------------------------------
// Row softmax: exact max, unnormalized fp16 P, reciprocal sums.
__global__ __launch_bounds__(256) void k_softmax(const float* __restrict__ S,
                                                 const int* __restrict__ m2,
                                                 _Float16* __restrict__ P,
                                                 float* __restrict__ rs, int b0) {
    int bid = blockIdx.x;
    int cbi = bid >> 7, rb = bid & 127;
    int wid = threadIdx.x >> 6, lane = threadIdx.x & 63;
    int row = rb * 4 + wid, bg = b0 + cbi;
    const float* Sr = S + ((size_t)cbi * SS + row) * SS + lane * 8;
    float4 v0 = *(const float4*)(Sr);
    float4 v1 = *(const float4*)(Sr + 4);
    int4 q0 = *(const int4*)(m2 + bg * SS + lane * 8);
    int4 q1 = *(const int4*)(m2 + bg * SS + lane * 8 + 4);
    float c[8] = {q0.x ? v0.x : -1e-5f, q0.y ? v0.y : -1e-5f,
                  q0.z ? v0.z : -1e-5f, q0.w ? v0.w : -1e-5f,
                  q1.x ? v1.x : -1e-5f, q1.y ? v1.y : -1e-5f,
                  q1.z ? v1.z : -1e-5f, q1.w ? v1.w : -1e-5f};
    float mx = c[0];
#pragma unroll
    for (int j = 1; j < 8; ++j) mx = fmaxf(mx, c[j]);
#pragma unroll
    for (int off = 1; off <= 32; off <<= 1) mx = fmaxf(mx, __shfl_xor(mx, off));
    f16x8 o;
    float sm = 0.f;
#pragma unroll
    for (int j = 0; j < 8; ++j) {
        _Float16 h = (_Float16)__expf(c[j] - mx);
        o[j] = h;
        sm += (float)h;
    }
#pragma unroll
    for (int off = 1; off <= 32; off <<= 1) sm += __shfl_xor(sm, off);
    *(f16x8*)(P + ((size_t)cbi * SS + row) * SS + lane * 8) = o;
    if (lane == 0) rs[cbi * SS + row] = 1.0f / sm;
}

// ---------------------------------------------------------------------------
__global__ __launch_bounds__(256) void k_wvproj(const u32* __restrict__ wvkeys,
                                                const float* __restrict__ Wp,
                                                const float* __restrict__ bp,
                                                float* __restrict__ outp) {
    int b = blockIdx.x;
    __shared__ float xv[DWW];
    int tid = threadIdx.x;
    if (tid < DWW) xv[tid] = fdec(wvkeys[b * DWW + tid]);
    __syncthreads();
    for (int h = tid; h < HH; h += 256) {
        float acc = bp[h];
        for (int d = 0; d < DWW; ++d) acc += xv[d] * Wp[d * HH + h];
        outp[b * HH + h] = acc;
    }
}

__global__ __launch_bounds__(256) void k_final(const float* __restrict__ x1h,
                                               const float* __restrict__ x2h,
                                               const u32* __restrict__ keys,
                                               const float* __restrict__ wvp,
                                               const float* __restrict__ lw,
                                               const float* __restrict__ lb,
                                               float* __restrict__ out) {
    int b = blockIdx.x;
    int tid = threadIdx.x;
    float acc = 0.f;
    for (int i = tid; i < HH; i += 256) {
        acc += x1h[b * HH + i] * lw[i];
        acc += x2h[b * HH + i] * lw[HH + i];
        acc += fdec(keys[b * HH + i]) * lw[2 * HH + i];
        acc += wvp[b * HH + i] * lw[3 * HH + i];
    }
    __shared__ float red[4];
    int wid = tid >> 6, lane = tid & 63;
#pragma unroll
    for (int off = 32; off; off >>= 1) acc += __shfl_down(acc, off);
    if (lane == 0) red[wid] = acc;
    __syncthreads();
    if (tid == 0) {
        float z = red[0] + red[1] + red[2] + red[3] + lb[0];
        out[b] = 1.f / (1.f + __expf(-z));
    }
}

// ---------------------------------------------------------------------------
extern "C" void kernel_launch(void* const* d_in, const int* in_sizes, int n_in,
                              void* d_out, int out_size, void* d_ws, size_t ws_size,
                              hipStream_t stream) {
    const float* x1   = (const float*)d_in[0];
    const float* x1h  = (const float*)d_in[1];
    const int*   m1   = (const int*)d_in[2];
    const float* y    = (const float*)d_in[3];
    const float* x2   = (const float*)d_in[4];
    const float* x2h  = (const float*)d_in[5];
    const int*   m2   = (const int*)d_in[6];
    const float* tt   = (const float*)d_in[7];
    const float* tt2  = (const float*)d_in[8];
    const float* Wb   = (const float*)d_in[9];
    const float* Wwv  = (const float*)d_in[10];
    const float* lwvw = (const float*)d_in[11];
    const float* lwvb = (const float*)d_in[12];
    const float* lw   = (const float*)d_in[13];
    const float* lb   = (const float*)d_in[14];
    float* out = (float*)d_out;
    char* ws = (char*)d_ws;

    // fixed region
    u32*      x12key   = (u32*)ws;                    // 196608
    u32*      x12wvkey = (u32*)(ws + 196608);         // 51200
    float*    x12wvp   = (float*)(ws + 247808);       // 196608
    float*    rsumBuf  = (float*)(ws + 444416);       // 131072
    _Float16* wbTH     = (_Float16*)(ws + 575488);    // 768*832*2 = 1277952
    _Float16* wwTH     = (_Float16*)(ws + 1853440);   // 256*256*2 = 131072
    const size_t D0 = 1984512;

    k_init<<<(BB * HH + 255) / 256, 256, 0, stream>>>(x12key, x12wvkey);
    k_masks<<<(BB * SS + 255) / 256, 256, 0, stream>>>(m1, m2, out);
    k_prep_w<<<(768 * 832 + 255) / 256, 256, 0, stream>>>(Wb, wbTH, 769, 768, 832, 768);
    k_prep_w<<<(256 * 256 + 255) / 256, 256, 0, stream>>>(Wwv, wwTH, 201, 200, 256, 256);

    // ---------------- bert phase ----------------
    {
        const size_t perA = 1572864;                 // S (1MB) + P (0.5MB); Xcat aliases S
        const size_t perXW = 786432, perKV = 786432, perKT = 786432;
        const size_t perb = perA + perXW + perKV + perKT;   // 3,932,160
        int nb = 1;
        if (ws_size > D0 + perb) nb = (int)((ws_size - D0) / perb);
        if (nb > BB) nb = BB;
        if (nb < 1) nb = 1;

        _Float16* Xcat = (_Float16*)(ws + D0);       // [nb][512][832] = 851968/b < 1MB
        float*    SBuf = (float*)(ws + D0);          // aliases Xcat (sequential use)
        _Float16* PBuf = (_Float16*)(ws + D0 + (size_t)nb * 1048576);
        _Float16* xwH  = (_Float16*)(ws + D0 + (size_t)nb * perA);
        _Float16* kv   = (_Float16*)((char*)xwH + (size_t)nb * perXW);
        _Float16* kvT  = (_Float16*)((char*)kv + (size_t)nb * perKV);

        for (int b0 = 0; b0 < BB; b0 += nb) {
            int cb = (BB - b0 < nb) ? (BB - b0) : nb;
            k_prep_kv<768, 768, 768><<<dim3(cb * 8, 12), 256, 0, stream>>>(x2, kv, kvT, b0);
            k_prep_x<<<dim3(416, cb), 256, 0, stream>>>(x1, y, Xcat, 768, 832, b0);
            // xw = Xcat @ W^T : KA=832, 13 steps, out fp16 [cb][512][768]
            k_mm1<13, 6, 1><<<cb * 24, 256, 0, stream>>>(
                Xcat, wbTH, 832, (size_t)SS * 832, 0,
                nullptr, xwH, 768, nullptr, nullptr, nullptr, 0, b0, cb * 24);
            // S = xwH @ kv^T : KA=768, 12 steps, out fp32 (overwrites Xcat region)
            k_mm1<12, 4, 0><<<cb * 16, 256, 0, stream>>>(
                xwH, kv, 768, (size_t)SS * 768, (size_t)SS * 768,
                SBuf, nullptr, 0, nullptr, nullptr, nullptr, 0, b0, cb * 16);
            k_softmax<<<cb * 128, 256, 0, stream>>>(SBuf, m2, PBuf, rsumBuf, b0);
            // V = P @ kvT^T + fused max : KA=512, 8 steps
            k_mm1<8, 6, 2><<<cb * 24, 256, 0, stream>>>(
                PBuf, kvT, 512, (size_t)SS * 512, (size_t)768 * 512,
                nullptr, nullptr, 0, rsumBuf, m1, x12key, 768, b0, cb * 24);
        }
    }

    // ---------------- wv phase ----------------
    {
        const size_t perA = 1572864;
        const size_t perXW = 262144, perKV = 262144, perKT = 262144;
        const size_t perb = perA + perXW + perKV + perKT;   // 2,359,296
        int nb = 1;
        if (ws_size > D0 + perb) nb = (int)((ws_size - D0) / perb);
        if (nb > BB) nb = BB;
        if (nb < 1) nb = 1;

        _Float16* Xcat = (_Float16*)(ws + D0);       // [nb][512][256] = 262144/b
        float*    SBuf = (float*)(ws + D0);
        _Float16* PBuf = (_Float16*)(ws + D0 + (size_t)nb * 1048576);
        _Float16* xwH  = (_Float16*)(ws + D0 + (size_t)nb * perA);
        _Float16* kv   = (_Float16*)((char*)xwH + (size_t)nb * perXW);
        _Float16* kvT  = (_Float16*)((char*)kv + (size_t)nb * perKV);

        for (int b0 = 0; b0 < BB; b0 += nb) {
            int cb = (BB - b0 < nb) ? (BB - b0) : nb;
            k_prep_kv<200, 256, 256><<<dim3(cb * 8, 4), 256, 0, stream>>>(tt2, kv, kvT, b0);
            k_prep_x<<<dim3(128, cb), 256, 0, stream>>>(tt, y, Xcat, 200, 256, b0);
            // xw : KA=256, 4 steps, out fp16 [cb][512][256] (cols>=224 are exact 0)
            k_mm1<4, 2, 1><<<cb * 8, 256, 0, stream>>>(
                Xcat, wwTH, 256, (size_t)SS * 256, 0,
                nullptr, xwH, 256, nullptr, nullptr, nullptr, 0, b0, cb * 8);
            // S = xwH @ kv^T : KA=256, 4 steps (padded dims contribute 0)
            k_mm1<4, 4, 0><<<cb * 16, 256, 0, stream>>>(
                xwH, kv, 256, (size_t)SS * 256, (size_t)SS * 256,
                SBuf, nullptr, 0, nullptr, nullptr, nullptr, 0, b0, cb * 16);
            k_softmax<<<cb * 128, 256, 0, stream>>>(SBuf, m2, PBuf, rsumBuf, b0);
            // V = P @ kvT^T + fused max : KA=512, 8 steps, DV=200 guard
            k_mm1<8, 2, 2><<<cb * 8, 256, 0, stream>>>(
                PBuf, kvT, 512, (size_t)SS * 512, (size_t)256 * 512,
                nullptr, nullptr, 0, rsumBuf, m1, x12wvkey, 200, b0, cb * 8);
        }
    }

    k_wvproj<<<BB, 256, 0, stream>>>(x12wvkey, lwvw, lwvb, x12wvp);
    k_final<<<BB, 256, 0, stream>>>(x1h, x2h, x12key, x12wvp, lw, lb, out);
}

// Round 6
// 468.015 us; speedup vs baseline: 5.8598x; 1.0030x over previous
//
#include <hip/hip_runtime.h>

// ============================================================================
// Round 6: round-5 pipeline + T3-minimum prefetch GEMM.
//   k_mm1: BK=32, double-buffered 2 x 16KB = 32KB LDS (same occupancy as r5),
//   loop = { STAGE(buf^1, ks+1); ds_read+16 MFMA on buf; barrier } so load
//   flight time hides under MFMA (r5 issued loads then drained immediately).
//   EPI=1 epilogue: LDS-staged vectorized stores (8x16B/thread vs 64x2B).
// Numerics unchanged: 1-term fp16 everywhere (absmax 0.0039 vs thr 0.02).
// ============================================================================

#define BB 64
#define SS 512
#define HH 768
#define DWW 200

typedef __attribute__((ext_vector_type(8))) _Float16 f16x8;
typedef __attribute__((ext_vector_type(4))) _Float16 f16x4;
typedef __attribute__((ext_vector_type(4))) float f32x4;
typedef unsigned int u32;

__device__ __forceinline__ u32 fkey(float f) {
    u32 u = __float_as_uint(f);
    return (u & 0x80000000u) ? ~u : (u | 0x80000000u);
}
__device__ __forceinline__ float fdec(u32 k) {
    u32 u = (k & 0x80000000u) ? (k & 0x7fffffffu) : ~k;
    return __uint_as_float(u);
}
__device__ __forceinline__ f32x4 mm(f16x8 a, f16x8 b, f32x4 c) {
    return __builtin_amdgcn_mfma_f32_16x16x32_f16(a, b, c, 0, 0, 0);
}
__device__ __forceinline__ void gl16(const void* g, void* l) {
    __builtin_amdgcn_global_load_lds(
        (const __attribute__((address_space(1))) void*)g,
        (__attribute__((address_space(3))) void*)l, 16, 0, 0);
}

// ---------------------------------------------------------------------------
__global__ __launch_bounds__(256) void k_masks(const int* __restrict__ m1,
                                               const int* __restrict__ m2,
                                               float* __restrict__ out) {
    int i = blockIdx.x * 256 + threadIdx.x;
    if (i < BB * SS) {
        out[BB + i]           = (float)(1 - m1[i]);
        out[BB + BB * SS + i] = (float)(1 - m2[i]);
    }
}

__global__ __launch_bounds__(256) void k_init(u32* __restrict__ k1,
                                              u32* __restrict__ k2) {
    int i = blockIdx.x * 256 + threadIdx.x;
    u32 v = fkey(-1e5f);
    if (i < BB * HH) k1[i] = v;
    if (i < BB * DWW) k2[i] = v;
}

// ---------------------------------------------------------------------------
// W [K][N] fp32 -> transposed padded fp16 [NPAD][KPAD]
__global__ __launch_bounds__(256) void k_prep_w(const float* __restrict__ W,
                                                _Float16* __restrict__ tH,
                                                int K, int N, int KPAD, int NPAD) {
    int idx = blockIdx.x * 256 + threadIdx.x;
    if (idx >= NPAD * KPAD) return;
    int n = idx / KPAD, k = idx - n * KPAD;
    float v = (k < K && n < N) ? W[(size_t)k * N + n] : 0.f;
    tH[idx] = (_Float16)v;
}

// ---------------------------------------------------------------------------
// Xcat = [X | y | 0pad] fp32 -> fp16 [cb][512][KPAD]
__global__ __launch_bounds__(256) void k_prep_x(const float* __restrict__ X,
                                                const float* __restrict__ y,
                                                _Float16* __restrict__ out,
                                                int Din, int KPAD, int b0) {
    int cbi = blockIdx.y, bg = b0 + cbi;
    int idx = (blockIdx.x * 256 + threadIdx.x) * 4;
    int s = idx / KPAD, k0 = idx - s * KPAD;
    const float* Xr = X + ((size_t)bg * SS + s) * Din;
    f16x4 o;
    if (k0 + 3 < Din) {
        float4 p = *(const float4*)(Xr + k0);
        o[0] = (_Float16)p.x; o[1] = (_Float16)p.y;
        o[2] = (_Float16)p.z; o[3] = (_Float16)p.w;
    } else {
#pragma unroll
        for (int j = 0; j < 4; ++j) {
            int k = k0 + j;
            float v = (k < Din) ? Xr[k] : ((k == Din) ? y[(size_t)bg * SS + s] : 0.f);
            o[j] = (_Float16)v;
        }
    }
    *(f16x4*)(out + ((size_t)cbi * SS + s) * KPAD + k0) = o;
}

// ---------------------------------------------------------------------------
// KV [B][512][D] fp32 -> fp16 [cb][512][DPAD] + fp16 transposed [cb][DTPAD][512]
template<int D, int DPAD, int DTPAD>
__global__ __launch_bounds__(256) void k_prep_kv(const float* __restrict__ src,
                                                 _Float16* __restrict__ kv,
                                                 _Float16* __restrict__ kvT, int b0) {
    __shared__ float tile[64][65];
    int cbi = blockIdx.x >> 3, t0 = (blockIdx.x & 7) * 64, d0 = blockIdx.y * 64;
    int bg = b0 + cbi, tid = threadIdx.x;
    int tr = tid >> 4, dc = (tid & 15) * 4;
#pragma unroll
    for (int i = 0; i < 4; ++i) {
        int t = tr + i * 16;
        int gd = d0 + dc;
        float v[4];
        if (gd + 3 < D) {
            float4 p = *(const float4*)(src + ((size_t)bg * SS + t0 + t) * D + gd);
            v[0] = p.x; v[1] = p.y; v[2] = p.z; v[3] = p.w;
        } else {
#pragma unroll
            for (int j = 0; j < 4; ++j) {
                int d = gd + j;
                v[j] = (d < D) ? src[((size_t)bg * SS + t0 + t) * D + d] : 0.f;
            }
        }
#pragma unroll
        for (int j = 0; j < 4; ++j) tile[t][dc + j] = v[j];
        if (gd < DPAD) {
            f16x4 o;
#pragma unroll
            for (int j = 0; j < 4; ++j) o[j] = (_Float16)v[j];
            *(f16x4*)(kv + ((size_t)cbi * SS + t0 + t) * DPAD + gd) = o;
        }
    }
    __syncthreads();
#pragma unroll
    for (int i = 0; i < 4; ++i) {
        int dl = tr + i * 16, gdr = d0 + dl;
        if (gdr < DTPAD) {
            int tc = (tid & 15) * 4;
            f16x4 o;
#pragma unroll
            for (int j = 0; j < 4; ++j) o[j] = (_Float16)tile[tc + j][dl];
            *(f16x4*)(kvT + ((size_t)cbi * DTPAD + gdr) * SS + t0 + tc) = o;
        }
    }
}

// ---------------------------------------------------------------------------
// Unified 1-term GEMM with T3-min prefetch. C[128x128] = A[128xK] * B[128xK]^T.
// BK=32, dbuf 2 x (A 8KB + B 8KB) = 32KB. Per K-step: STAGE next -> 16 MFMA
// on current -> barrier (compiler vmcnt(0) drains the overlapped loads).
// EPI=0: fp32 S out. EPI=1: fp16 out via LDS-staged 16B stores. EPI=2: fused
// normalize+rowmask+maxpool epilogue (atomicMax on ordered keys).
template<int KSTEPS, int TN, int EPI>
__global__ __launch_bounds__(256) void k_mm1(
    const _Float16* __restrict__ A, const _Float16* __restrict__ B, int KA,
    size_t aStride, size_t bStride,
    float* __restrict__ outS,
    _Float16* __restrict__ outH, int SXW,
    const float* __restrict__ rsum, const int* __restrict__ m1,
    u32* __restrict__ keys, int DV,
    int b0, int nwg) {
    __shared__ __align__(16) char lds[32768];  // [2 buf][2 arr][4 slot][128 row][16B]
    __shared__ int m1v[128];
    __shared__ float rsv[128];

    int bid = blockIdx.x;
    int lb = (bid & 7) * (nwg >> 3) + (bid >> 3);  // XCD-contiguous remap
    int cbi = lb / (4 * TN);
    int rest = lb - cbi * (4 * TN);
    int ts = rest / TN, tn = rest - ts * TN;
    int s0 = ts * 128, n0 = tn * 128;
    int tid = threadIdx.x, lane = tid & 63, wid = tid >> 6;
    int wr = wid >> 1, wc = wid & 1;
    int l15 = lane & 15, sl = lane >> 4, gb = sl * 4;

    const _Float16* srcA = A + (size_t)cbi * aStride + (size_t)s0 * KA;
    const _Float16* srcB = B + (size_t)cbi * bStride + (size_t)n0 * KA;

    if constexpr (EPI == 2) {
        if (tid < 128) {
            int bg = b0 + cbi;
            m1v[tid] = m1[bg * SS + s0 + tid];
            rsv[tid] = rsum[cbi * SS + s0 + tid];
        }
    }

    f32x4 zz = {0.f, 0.f, 0.f, 0.f};
    f32x4 acc[4][4];
#pragma unroll
    for (int i = 0; i < 4; ++i)
#pragma unroll
        for (int j = 0; j < 4; ++j) acc[i][j] = zz;

    // stage 16 chunks of 1KB into buf: c = wid+4*i; arr=c>>3, slot=(c&7)>>1,
    // rowhalf=c&1; lane's 16B -> row rh*64+lane, cols ks*32+slot*8..+7.
#define STAGE(buf, ks)                                                        \
    _Pragma("unroll") for (int i = 0; i < 4; ++i) {                           \
        int c = wid + 4 * i;                                                  \
        int arr = c >> 3, sub = c & 7, slot = sub >> 1, rh = sub & 1;         \
        const _Float16* gp = (arr ? srcB : srcA) +                            \
            (size_t)(rh * 64 + lane) * KA + (ks) * 32 + slot * 8;             \
        gl16(gp, lds + (buf) * 16384 + c * 1024);                             \
    }

    STAGE(0, 0);
    __syncthreads();
    int buf = 0;
    for (int ks = 0; ks < KSTEPS; ++ks) {
        if (ks + 1 < KSTEPS) STAGE(buf ^ 1, ks + 1);   // issue early: overlap
        char* base = lds + buf * 16384;
        f16x8 a[4], b[4];
#pragma unroll
        for (int mf = 0; mf < 4; ++mf)
            a[mf] = *(const f16x8*)(base + sl * 2048 + (wr * 64 + mf * 16 + l15) * 16);
#pragma unroll
        for (int nf = 0; nf < 4; ++nf)
            b[nf] = *(const f16x8*)(base + 8192 + sl * 2048 + (wc * 64 + nf * 16 + l15) * 16);
#pragma unroll
        for (int mf = 0; mf < 4; ++mf)
#pragma unroll
            for (int nf = 0; nf < 4; ++nf)
                acc[mf][nf] = mm(a[mf], b[nf], acc[mf][nf]);
        __syncthreads();
        buf ^= 1;
    }
#undef STAGE

    if constexpr (EPI == 0) {
#pragma unroll
        for (int mf = 0; mf < 4; ++mf)
#pragma unroll
            for (int nf = 0; nf < 4; ++nf)
#pragma unroll
                for (int r = 0; r < 4; ++r) {
                    int s = s0 + wr * 64 + mf * 16 + gb + r;
                    int col = n0 + wc * 64 + nf * 16 + l15;
                    outS[((size_t)cbi * SS + s) * SS + col] = acc[mf][nf][r];
                }
    } else if constexpr (EPI == 1) {
        // LDS-staged vectorized write: 32KB = full 128x128 fp16 tile.
        _Float16* ce = (_Float16*)lds;
#pragma unroll
        for (int mf = 0; mf < 4; ++mf)
#pragma unroll
            for (int nf = 0; nf < 4; ++nf)
#pragma unroll
                for (int r = 0; r < 4; ++r) {
                    int row = wr * 64 + mf * 16 + gb + r;
                    int col = wc * 64 + nf * 16 + l15;
                    ce[row * 128 + col] = (_Float16)acc[mf][nf][r];
                }
        __syncthreads();
#pragma unroll
        for (int i = 0; i < 8; ++i) {
            int t = tid + i * 256;              // 2048 chunks of 8 f16
            int row = t >> 4, col = (t & 15) * 8;
            *(f16x8*)(outH + ((size_t)cbi * SS + s0 + row) * SXW + n0 + col) =
                *(const f16x8*)(ce + row * 128 + col);
        }
    } else {
        int bg = b0 + cbi;
#pragma unroll
        for (int nf = 0; nf < 4; ++nf) {
            float mx = -3.0e38f;
#pragma unroll
            for (int mf = 0; mf < 4; ++mf)
#pragma unroll
                for (int r = 0; r < 4; ++r) {
                    int srow = wr * 64 + mf * 16 + gb + r;
                    if (m1v[srow]) mx = fmaxf(mx, acc[mf][nf][r] * rsv[srow]);
                }
            mx = fmaxf(mx, __shfl_xor(mx, 16));
            mx = fmaxf(mx, __shfl_xor(mx, 32));
            if (lane < 16) {
                int d = n0 + wc * 64 + nf * 16 + lane;
                if (d < DV) atomicMax(&keys[(size_t)bg * DV + d], fkey(mx));
            }
        }
    }
}

// ---------------------------------------------------------------------------
// Row softmax: exact max, unnormalized fp16 P, reciprocal sums.
__global__ __launch_bounds__(256) void k_softmax(const float* __restrict__ S,
                                                 const int* __restrict__ m2,
                                                 _Float16* __restrict__ P,
                                                 float* __restrict__ rs, int b0) {
    int bid = blockIdx.x;
    int cbi = bid >> 7, rb = bid & 127;
    int wid = threadIdx.x >> 6, lane = threadIdx.x & 63;
    int row = rb * 4 + wid, bg = b0 + cbi;
    const float* Sr = S + ((size_t)cbi * SS + row) * SS + lane * 8;
    float4 v0 = *(const float4*)(Sr);
    float4 v1 = *(const float4*)(Sr + 4);
    int4 q0 = *(const int4*)(m2 + bg * SS + lane * 8);
    int4 q1 = *(const int4*)(m2 + bg * SS + lane * 8 + 4);
    float c[8] = {q0.x ? v0.x : -1e-5f, q0.y ? v0.y : -1e-5f,
                  q0.z ? v0.z : -1e-5f, q0.w ? v0.w : -1e-5f,
                  q1.x ? v1.x : -1e-5f, q1.y ? v1.y : -1e-5f,
                  q1.z ? v1.z : -1e-5f, q1.w ? v1.w : -1e-5f};
    float mx = c[0];
#pragma unroll
    for (int j = 1; j < 8; ++j) mx = fmaxf(mx, c[j]);
#pragma unroll
    for (int off = 1; off <= 32; off <<= 1) mx = fmaxf(mx, __shfl_xor(mx, off));
    f16x8 o;
    float sm = 0.f;
#pragma unroll
    for (int j = 0; j < 8; ++j) {
        _Float16 h = (_Float16)__expf(c[j] - mx);
        o[j] = h;
        sm += (float)h;
    }
#pragma unroll
    for (int off = 1; off <= 32; off <<= 1) sm += __shfl_xor(sm, off);
    *(f16x8*)(P + ((size_t)cbi * SS + row) * SS + lane * 8) = o;
    if (lane == 0) rs[cbi * SS + row] = 1.0f / sm;
}

// ---------------------------------------------------------------------------
__global__ __launch_bounds__(256) void k_wvproj(const u32* __restrict__ wvkeys,
                                                const float* __restrict__ Wp,
                                                const float* __restrict__ bp,
                                                float* __restrict__ outp) {
    int b = blockIdx.x;
    __shared__ float xv[DWW];
    int tid = threadIdx.x;
    if (tid < DWW) xv[tid] = fdec(wvkeys[b * DWW + tid]);
    __syncthreads();
    for (int h = tid; h < HH; h += 256) {
        float acc = bp[h];
        for (int d = 0; d < DWW; ++d) acc += xv[d] * Wp[d * HH + h];
        outp[b * HH + h] = acc;
    }
}

__global__ __launch_bounds__(256) void k_final(const float* __restrict__ x1h,
                                               const float* __restrict__ x2h,
                                               const u32* __restrict__ keys,
                                               const float* __restrict__ wvp,
                                               const float* __restrict__ lw,
                                               const float* __restrict__ lb,
                                               float* __restrict__ out) {
    int b = blockIdx.x;
    int tid = threadIdx.x;
    float acc = 0.f;
    for (int i = tid; i < HH; i += 256) {
        acc += x1h[b * HH + i] * lw[i];
        acc += x2h[b * HH + i] * lw[HH + i];
        acc += fdec(keys[b * HH + i]) * lw[2 * HH + i];
        acc += wvp[b * HH + i] * lw[3 * HH + i];
    }
    __shared__ float red[4];
    int wid = tid >> 6, lane = tid & 63;
#pragma unroll
    for (int off = 32; off; off >>= 1) acc += __shfl_down(acc, off);
    if (lane == 0) red[wid] = acc;
    __syncthreads();
    if (tid == 0) {
        float z = red[0] + red[1] + red[2] + red[3] + lb[0];
        out[b] = 1.f / (1.f + __expf(-z));
    }
}

// ---------------------------------------------------------------------------
extern "C" void kernel_launch(void* const* d_in, const int* in_sizes, int n_in,
                              void* d_out, int out_size, void* d_ws, size_t ws_size,
                              hipStream_t stream) {
    const float* x1   = (const float*)d_in[0];
    const float* x1h  = (const float*)d_in[1];
    const int*   m1   = (const int*)d_in[2];
    const float* y    = (const float*)d_in[3];
    const float* x2   = (const float*)d_in[4];
    const float* x2h  = (const float*)d_in[5];
    const int*   m2   = (const int*)d_in[6];
    const float* tt   = (const float*)d_in[7];
    const float* tt2  = (const float*)d_in[8];
    const float* Wb   = (const float*)d_in[9];
    const float* Wwv  = (const float*)d_in[10];
    const float* lwvw = (const float*)d_in[11];
    const float* lwvb = (const float*)d_in[12];
    const float* lw   = (const float*)d_in[13];
    const float* lb   = (const float*)d_in[14];
    float* out = (float*)d_out;
    char* ws = (char*)d_ws;

    // fixed region
    u32*      x12key   = (u32*)ws;                    // 196608
    u32*      x12wvkey = (u32*)(ws + 196608);         // 51200
    float*    x12wvp   = (float*)(ws + 247808);       // 196608
    float*    rsumBuf  = (float*)(ws + 444416);       // 131072
    _Float16* wbTH     = (_Float16*)(ws + 575488);    // 768*832*2 = 1277952
    _Float16* wwTH     = (_Float16*)(ws + 1853440);   // 256*256*2 = 131072
    const size_t D0 = 1984512;

    k_init<<<(BB * HH + 255) / 256, 256, 0, stream>>>(x12key, x12wvkey);
    k_masks<<<(BB * SS + 255) / 256, 256, 0, stream>>>(m1, m2, out);
    k_prep_w<<<(768 * 832 + 255) / 256, 256, 0, stream>>>(Wb, wbTH, 769, 768, 832, 768);
    k_prep_w<<<(256 * 256 + 255) / 256, 256, 0, stream>>>(Wwv, wwTH, 201, 200, 256, 256);

    // ---------------- bert phase ----------------
    {
        const size_t perA = 1572864;                 // S (1MB) + P (0.5MB); Xcat aliases S
        const size_t perXW = 786432, perKV = 786432, perKT = 786432;
        const size_t perb = perA + perXW + perKV + perKT;   // 3,932,160
        int nb = 1;
        if (ws_size > D0 + perb) nb = (int)((ws_size - D0) / perb);
        if (nb > BB) nb = BB;
        if (nb < 1) nb = 1;

        _Float16* Xcat = (_Float16*)(ws + D0);       // [nb][512][832] aliases SBuf
        float*    SBuf = (float*)(ws + D0);
        _Float16* PBuf = (_Float16*)(ws + D0 + (size_t)nb * 1048576);
        _Float16* xwH  = (_Float16*)(ws + D0 + (size_t)nb * perA);
        _Float16* kv   = (_Float16*)((char*)xwH + (size_t)nb * perXW);
        _Float16* kvT  = (_Float16*)((char*)kv + (size_t)nb * perKV);

        for (int b0 = 0; b0 < BB; b0 += nb) {
            int cb = (BB - b0 < nb) ? (BB - b0) : nb;
            k_prep_kv<768, 768, 768><<<dim3(cb * 8, 12), 256, 0, stream>>>(x2, kv, kvT, b0);
            k_prep_x<<<dim3(416, cb), 256, 0, stream>>>(x1, y, Xcat, 768, 832, b0);
            // xw = Xcat @ W^T : KA=832, 26 steps, out fp16 [cb][512][768]
            k_mm1<26, 6, 1><<<cb * 24, 256, 0, stream>>>(
                Xcat, wbTH, 832, (size_t)SS * 832, 0,
                nullptr, xwH, 768, nullptr, nullptr, nullptr, 0, b0, cb * 24);
            // S = xwH @ kv^T : KA=768, 24 steps, out fp32 (overwrites Xcat region)
            k_mm1<24, 4, 0><<<cb * 16, 256, 0, stream>>>(
                xwH, kv, 768, (size_t)SS * 768, (size_t)SS * 768,
                SBuf, nullptr, 0, nullptr, nullptr, nullptr, 0, b0, cb * 16);
            k_softmax<<<cb * 128, 256, 0, stream>>>(SBuf, m2, PBuf, rsumBuf, b0);
            // V = P @ kvT^T + fused max : KA=512, 16 steps
            k_mm1<16, 6, 2><<<cb * 24, 256, 0, stream>>>(
                PBuf, kvT, 512, (size_t)SS * 512, (size_t)768 * 512,
                nullptr, nullptr, 0, rsumBuf, m1, x12key, 768, b0, cb * 24);
        }
    }

    // ---------------- wv phase ----------------
    {
        const size_t perA = 1572864;
        const size_t perXW = 262144, perKV = 262144, perKT = 262144;
        const size_t perb = perA + perXW + perKV + perKT;   // 2,359,296
        int nb = 1;
        if (ws_size > D0 + perb) nb = (int)((ws_size - D0) / perb);
        if (nb > BB) nb = BB;
        if (nb < 1) nb = 1;

        _Float16* Xcat = (_Float16*)(ws + D0);       // [nb][512][256]
        float*    SBuf = (float*)(ws + D0);
        _Float16* PBuf = (_Float16*)(ws + D0 + (size_t)nb * 1048576);
        _Float16* xwH  = (_Float16*)(ws + D0 + (size_t)nb * perA);
        _Float16* kv   = (_Float16*)((char*)xwH + (size_t)nb * perXW);
        _Float16* kvT  = (_Float16*)((char*)kv + (size_t)nb * perKV);

        for (int b0 = 0; b0 < BB; b0 += nb) {
            int cb = (BB - b0 < nb) ? (BB - b0) : nb;
            k_prep_kv<200, 256, 256><<<dim3(cb * 8, 4), 256, 0, stream>>>(tt2, kv, kvT, b0);
            k_prep_x<<<dim3(128, cb), 256, 0, stream>>>(tt, y, Xcat, 200, 256, b0);
            // xw : KA=256, 8 steps, out fp16 [cb][512][256]
            k_mm1<8, 2, 1><<<cb * 8, 256, 0, stream>>>(
                Xcat, wwTH, 256, (size_t)SS * 256, 0,
                nullptr, xwH, 256, nullptr, nullptr, nullptr, 0, b0, cb * 8);
            // S = xwH @ kv^T : KA=256, 8 steps
            k_mm1<8, 4, 0><<<cb * 16, 256, 0, stream>>>(
                xwH, kv, 256, (size_t)SS * 256, (size_t)SS * 256,
                SBuf, nullptr, 0, nullptr, nullptr, nullptr, 0, b0, cb * 16);
            k_softmax<<<cb * 128, 256, 0, stream>>>(SBuf, m2, PBuf, rsumBuf, b0);
            // V = P @ kvT^T + fused max : KA=512, 16 steps, DV=200 guard
            k_mm1<16, 2, 2><<<cb * 8, 256, 0, stream>>>(
                PBuf, kvT, 512, (size_t)SS * 512, (size_t)256 * 512,
                nullptr, nullptr, 0, rsumBuf, m1, x12wvkey, 200, b0, cb * 8);
        }
    }

    k_wvproj<<<BB, 256, 0, stream>>>(x12wvkey, lwvw, lwvb, x12wvp);
    k_final<<<BB, 256, 0, stream>>>(x1h, x2h, x12key, x12wvp, lw, lb, out);
}

// Round 7
// 378.156 us; speedup vs baseline: 7.2522x; 1.2376x over previous
//
#include <hip/hip_runtime.h>

// ============================================================================
// Round 7: row compaction. Rows with m1=0 (~50%) are masked to -1e5 before the
// max-pool in the reference -> their xw/S/softmax/PV work is discarded. We
// compact valid rows per batch (stable ballot scan), gather in prep_x (zero-
// padded to 128-multiple rpad), and gate all M-tiles on rpad (uniform block
// early-exit). PV epilogue gates rows by compacted count; -1e5 init covers the
// all-masked case exactly. Arithmetic for surviving rows is bit-identical.
// Also: bert xw KPAD 832->800 (25 K-steps), wv xw KPAD 224 (7 steps).
// GEMM core unchanged from r6 (128x128, BK=32, dbuf, gl16).
// ============================================================================

#define BB 64
#define SS 512
#define HH 768
#define DWW 200

typedef __attribute__((ext_vector_type(8))) _Float16 f16x8;
typedef __attribute__((ext_vector_type(4))) _Float16 f16x4;
typedef __attribute__((ext_vector_type(4))) float f32x4;
typedef unsigned int u32;

__device__ __forceinline__ u32 fkey(float f) {
    u32 u = __float_as_uint(f);
    return (u & 0x80000000u) ? ~u : (u | 0x80000000u);
}
__device__ __forceinline__ float fdec(u32 k) {
    u32 u = (k & 0x80000000u) ? (k & 0x7fffffffu) : ~k;
    return __uint_as_float(u);
}
__device__ __forceinline__ f32x4 mm(f16x8 a, f16x8 b, f32x4 c) {
    return __builtin_amdgcn_mfma_f32_16x16x32_f16(a, b, c, 0, 0, 0);
}
__device__ __forceinline__ void gl16(const void* g, void* l) {
    __builtin_amdgcn_global_load_lds(
        (const __attribute__((address_space(1))) void*)g,
        (__attribute__((address_space(3))) void*)l, 16, 0, 0);
}

// ---------------------------------------------------------------------------
__global__ __launch_bounds__(256) void k_masks(const int* __restrict__ m1,
                                               const int* __restrict__ m2,
                                               float* __restrict__ out) {
    int i = blockIdx.x * 256 + threadIdx.x;
    if (i < BB * SS) {
        out[BB + i]           = (float)(1 - m1[i]);
        out[BB + BB * SS + i] = (float)(1 - m2[i]);
    }
}

__global__ __launch_bounds__(256) void k_init(u32* __restrict__ k1,
                                              u32* __restrict__ k2) {
    int i = blockIdx.x * 256 + threadIdx.x;
    u32 v = fkey(-1e5f);
    if (i < BB * HH) k1[i] = v;
    if (i < BB * DWW) k2[i] = v;
}

// ---------------------------------------------------------------------------
// stable compaction of valid rows: idx[b][j] = j-th s with m1=1; rcnt[b].
__global__ __launch_bounds__(64) void k_scan(const int* __restrict__ m1,
                                             int* __restrict__ idx,
                                             int* __restrict__ rcnt) {
    int b = blockIdx.x, lane = threadIdx.x;
    int base = 0;
#pragma unroll
    for (int c = 0; c < 8; ++c) {
        int s = c * 64 + lane;
        int v = m1[b * SS + s];
        unsigned long long bal = __ballot(v != 0);
        int pre = __popcll(bal & ((1ull << lane) - 1ull));
        if (v) idx[b * SS + base + pre] = s;
        base += __popcll(bal);
    }
    if (lane == 0) rcnt[b] = base;
}

// ---------------------------------------------------------------------------
// W [K][N] fp32 -> transposed padded fp16 [NPAD][KPAD]
__global__ __launch_bounds__(256) void k_prep_w(const float* __restrict__ W,
                                                _Float16* __restrict__ tH,
                                                int K, int N, int KPAD, int NPAD) {
    int idx = blockIdx.x * 256 + threadIdx.x;
    if (idx >= NPAD * KPAD) return;
    int n = idx / KPAD, k = idx - n * KPAD;
    float v = (k < K && n < N) ? W[(size_t)k * N + n] : 0.f;
    tH[idx] = (_Float16)v;
}

// ---------------------------------------------------------------------------
// compacted Xcat: row s<rc gathers original row idx[s]; rows [rc,rpad) zero.
__global__ __launch_bounds__(256) void k_prep_x(const float* __restrict__ X,
                                                const float* __restrict__ y,
                                                const int* __restrict__ idx,
                                                const int* __restrict__ rcnt,
                                                _Float16* __restrict__ out,
                                                int Din, int KPAD, int b0) {
    int cbi = blockIdx.y, bg = b0 + cbi;
    int i4 = (blockIdx.x * 256 + threadIdx.x) * 4;
    int s = i4 / KPAD, k0 = i4 - s * KPAD;
    int rc = rcnt[bg];
    int rpad = (rc + 127) & ~127;
    if (s >= rpad) return;
    f16x4 o = {(_Float16)0.f, (_Float16)0.f, (_Float16)0.f, (_Float16)0.f};
    if (s < rc) {
        int sg = idx[bg * SS + s];
        const float* Xr = X + ((size_t)bg * SS + sg) * Din;
        if (k0 + 3 < Din) {
            float4 p = *(const float4*)(Xr + k0);
            o[0] = (_Float16)p.x; o[1] = (_Float16)p.y;
            o[2] = (_Float16)p.z; o[3] = (_Float16)p.w;
        } else {
#pragma unroll
            for (int j = 0; j < 4; ++j) {
                int k = k0 + j;
                float v = (k < Din) ? Xr[k]
                                    : ((k == Din) ? y[(size_t)bg * SS + sg] : 0.f);
                o[j] = (_Float16)v;
            }
        }
    }
    *(f16x4*)(out + ((size_t)cbi * SS + s) * KPAD + k0) = o;
}

// ---------------------------------------------------------------------------
// KV [B][512][D] fp32 -> fp16 [cb][512][DPAD] + fp16 transposed [cb][DTPAD][512]
template<int D, int DPAD, int DTPAD>
__global__ __launch_bounds__(256) void k_prep_kv(const float* __restrict__ src,
                                                 _Float16* __restrict__ kv,
                                                 _Float16* __restrict__ kvT, int b0) {
    __shared__ float tile[64][65];
    int cbi = blockIdx.x >> 3, t0 = (blockIdx.x & 7) * 64, d0 = blockIdx.y * 64;
    int bg = b0 + cbi, tid = threadIdx.x;
    int tr = tid >> 4, dc = (tid & 15) * 4;
#pragma unroll
    for (int i = 0; i < 4; ++i) {
        int t = tr + i * 16;
        int gd = d0 + dc;
        float v[4];
        if (gd + 3 < D) {
            float4 p = *(const float4*)(src + ((size_t)bg * SS + t0 + t) * D + gd);
            v[0] = p.x; v[1] = p.y; v[2] = p.z; v[3] = p.w;
        } else {
#pragma unroll
            for (int j = 0; j < 4; ++j) {
                int d = gd + j;
                v[j] = (d < D) ? src[((size_t)bg * SS + t0 + t) * D + d] : 0.f;
            }
        }
#pragma unroll
        for (int j = 0; j < 4; ++j) tile[t][dc + j] = v[j];
        if (gd < DPAD) {
            f16x4 o;
#pragma unroll
            for (int j = 0; j < 4; ++j) o[j] = (_Float16)v[j];
            *(f16x4*)(kv + ((size_t)cbi * SS + t0 + t) * DPAD + gd) = o;
        }
    }
    __syncthreads();
#pragma unroll
    for (int i = 0; i < 4; ++i) {
        int dl = tr + i * 16, gdr = d0 + dl;
        if (gdr < DTPAD) {
            int tc = (tid & 15) * 4;
            f16x4 o;
#pragma unroll
            for (int j = 0; j < 4; ++j) o[j] = (_Float16)tile[tc + j][dl];
            *(f16x4*)(kvT + ((size_t)cbi * DTPAD + gdr) * SS + t0 + tc) = o;
        }
    }
}

// ---------------------------------------------------------------------------
// Unified 1-term GEMM (r6 core) + compacted-row gating.
// EPI=0: fp32 S out. EPI=1: fp16 out via LDS-staged 16B stores. EPI=2: fused
// normalize + compacted-row-gate + maxpool (atomicMax on ordered keys).
template<int KSTEPS, int TN, int EPI>
__global__ __launch_bounds__(256) void k_mm1(
    const _Float16* __restrict__ A, const _Float16* __restrict__ B, int KA,
    size_t aStride, size_t bStride,
    float* __restrict__ outS,
    _Float16* __restrict__ outH, int SXW,
    const float* __restrict__ rsum,
    u32* __restrict__ keys, int DV,
    const int* __restrict__ rcnt,
    int b0, int nwg) {
    __shared__ __align__(16) char lds[32768];
    __shared__ float rsv[128];

    int bid = blockIdx.x;
    int lb = (bid & 7) * (nwg >> 3) + (bid >> 3);  // XCD-contiguous remap
    int cbi = lb / (4 * TN);
    int rest = lb - cbi * (4 * TN);
    int ts = rest / TN, tn = rest - ts * TN;
    int s0 = ts * 128, n0 = tn * 128;

    int rc = rcnt[b0 + cbi];
    int rpad = (rc + 127) & ~127;
    if (s0 >= rpad) return;                        // uniform early-exit

    int tid = threadIdx.x, lane = tid & 63, wid = tid >> 6;
    int wr = wid >> 1, wc = wid & 1;
    int l15 = lane & 15, sl = lane >> 4, gb = sl * 4;

    const _Float16* srcA = A + (size_t)cbi * aStride + (size_t)s0 * KA;
    const _Float16* srcB = B + (size_t)cbi * bStride + (size_t)n0 * KA;

    if constexpr (EPI == 2) {
        if (tid < 128) rsv[tid] = rsum[cbi * SS + s0 + tid];
    }

    f32x4 zz = {0.f, 0.f, 0.f, 0.f};
    f32x4 acc[4][4];
#pragma unroll
    for (int i = 0; i < 4; ++i)
#pragma unroll
        for (int j = 0; j < 4; ++j) acc[i][j] = zz;

#define STAGE(buf, ks)                                                        \
    _Pragma("unroll") for (int i = 0; i < 4; ++i) {                           \
        int c = wid + 4 * i;                                                  \
        int arr = c >> 3, sub = c & 7, slot = sub >> 1, rh = sub & 1;         \
        const _Float16* gp = (arr ? srcB : srcA) +                            \
            (size_t)(rh * 64 + lane) * KA + (ks) * 32 + slot * 8;             \
        gl16(gp, lds + (buf) * 16384 + c * 1024);                             \
    }

    STAGE(0, 0);
    __syncthreads();
    int buf = 0;
    for (int ks = 0; ks < KSTEPS; ++ks) {
        if (ks + 1 < KSTEPS) STAGE(buf ^ 1, ks + 1);
        char* base = lds + buf * 16384;
        f16x8 a[4], b[4];
#pragma unroll
        for (int mf = 0; mf < 4; ++mf)
            a[mf] = *(const f16x8*)(base + sl * 2048 + (wr * 64 + mf * 16 + l15) * 16);
#pragma unroll
        for (int nf = 0; nf < 4; ++nf)
            b[nf] = *(const f16x8*)(base + 8192 + sl * 2048 + (wc * 64 + nf * 16 + l15) * 16);
#pragma unroll
        for (int mf = 0; mf < 4; ++mf)
#pragma unroll
            for (int nf = 0; nf < 4; ++nf)
                acc[mf][nf] = mm(a[mf], b[nf], acc[mf][nf]);
        __syncthreads();
        buf ^= 1;
    }
#undef STAGE

    if constexpr (EPI == 0) {
#pragma unroll
        for (int mf = 0; mf < 4; ++mf)
#pragma unroll
            for (int nf = 0; nf < 4; ++nf)
#pragma unroll
                for (int r = 0; r < 4; ++r) {
                    int s = s0 + wr * 64 + mf * 16 + gb + r;
                    int col = n0 + wc * 64 + nf * 16 + l15;
                    outS[((size_t)cbi * SS + s) * SS + col] = acc[mf][nf][r];
                }
    } else if constexpr (EPI == 1) {
        _Float16* ce = (_Float16*)lds;
#pragma unroll
        for (int mf = 0; mf < 4; ++mf)
#pragma unroll
            for (int nf = 0; nf < 4; ++nf)
#pragma unroll
                for (int r = 0; r < 4; ++r) {
                    int row = wr * 64 + mf * 16 + gb + r;
                    int col = wc * 64 + nf * 16 + l15;
                    ce[row * 128 + col] = (_Float16)acc[mf][nf][r];
                }
        __syncthreads();
#pragma unroll
        for (int i = 0; i < 8; ++i) {
            int t = tid + i * 256;
            int row = t >> 4, col = (t & 15) * 8;
            *(f16x8*)(outH + ((size_t)cbi * SS + s0 + row) * SXW + n0 + col) =
                *(const f16x8*)(ce + row * 128 + col);
        }
    } else {
        int bg = b0 + cbi;
#pragma unroll
        for (int nf = 0; nf < 4; ++nf) {
            float mx = -3.0e38f;
#pragma unroll
            for (int mf = 0; mf < 4; ++mf)
#pragma unroll
                for (int r = 0; r < 4; ++r) {
                    int srow = wr * 64 + mf * 16 + gb + r;
                    if (s0 + srow < rc) mx = fmaxf(mx, acc[mf][nf][r] * rsv[srow]);
                }
            mx = fmaxf(mx, __shfl_xor(mx, 16));
            mx = fmaxf(mx, __shfl_xor(mx, 32));
            if (lane < 16) {
                int d = n0 + wc * 64 + nf * 16 + lane;
                if (d < DV) atomicMax(&keys[(size_t)bg * DV + d], fkey(mx));
            }
        }
    }
}

// ---------------------------------------------------------------------------
// Row softmax over compacted rows: exact max, unnormalized fp16 P, 1/sum.
// Rows [rc,rpad): P=0, rs=0 (read by gated PV tiles). Rows >= rpad: skip.
__global__ __launch_bounds__(256) void k_softmax(const float* __restrict__ S,
                                                 const int* __restrict__ m2,
                                                 const int* __restrict__ rcnt,
                                                 _Float16* __restrict__ P,
                                                 float* __restrict__ rs, int b0) {
    int bid = blockIdx.x;
    int cbi = bid >> 7, rb = bid & 127;
    int wid = threadIdx.x >> 6, lane = threadIdx.x & 63;
    int row = rb * 4 + wid, bg = b0 + cbi;
    int rc = rcnt[bg];
    int rpad = (rc + 127) & ~127;
    if (row >= rpad) return;
    if (row >= rc) {
        f16x8 z = {};
        *(f16x8*)(P + ((size_t)cbi * SS + row) * SS + lane * 8) = z;
        if (lane == 0) rs[cbi * SS + row] = 0.f;
        return;
    }
    const float* Sr = S + ((size_t)cbi * SS + row) * SS + lane * 8;
    float4 v0 = *(const float4*)(Sr);
    float4 v1 = *(const float4*)(Sr + 4);
    int4 q0 = *(const int4*)(m2 + bg * SS + lane * 8);
    int4 q1 = *(const int4*)(m2 + bg * SS + lane * 8 + 4);
    float c[8] = {q0.x ? v0.x : -1e-5f, q0.y ? v0.y : -1e-5f,
                  q0.z ? v0.z : -1e-5f, q0.w ? v0.w : -1e-5f,
                  q1.x ? v1.x : -1e-5f, q1.y ? v1.y : -1e-5f,
                  q1.z ? v1.z : -1e-5f, q1.w ? v1.w : -1e-5f};
    float mx = c[0];
#pragma unroll
    for (int j = 1; j < 8; ++j) mx = fmaxf(mx, c[j]);
#pragma unroll
    for (int off = 1; off <= 32; off <<= 1) mx = fmaxf(mx, __shfl_xor(mx, off));
    f16x8 o;
    float sm = 0.f;
#pragma unroll
    for (int j = 0; j < 8; ++j) {
        _Float16 h = (_Float16)__expf(c[j] - mx);
        o[j] = h;
        sm += (float)h;
    }
#pragma unroll
    for (int off = 1; off <= 32; off <<= 1) sm += __shfl_xor(sm, off);
    *(f16x8*)(P + ((size_t)cbi * SS + row) * SS + lane * 8) = o;
    if (lane == 0) rs[cbi * SS + row] = 1.0f / sm;
}

// ---------------------------------------------------------------------------
__global__ __launch_bounds__(256) void k_wvproj(const u32* __restrict__ wvkeys,
                                                const float* __restrict__ Wp,
                                                const float* __restrict__ bp,
                                                float* __restrict__ outp) {
    int b = blockIdx.x;
    __shared__ float xv[DWW];
    int tid = threadIdx.x;
    if (tid < DWW) xv[tid] = fdec(wvkeys[b * DWW + tid]);
    __syncthreads();
    for (int h = tid; h < HH; h += 256) {
        float acc = bp[h];
        for (int d = 0; d < DWW; ++d) acc += xv[d] * Wp[d * HH + h];
        outp[b * HH + h] = acc;
    }
}

__global__ __launch_bounds__(256) void k_final(const float* __restrict__ x1h,
                                               const float* __restrict__ x2h,
                                               const u32* __restrict__ keys,
                                               const float* __restrict__ wvp,
                                               const float* __restrict__ lw,
                                               const float* __restrict__ lb,
                                               float* __restrict__ out) {
    int b = blockIdx.x;
    int tid = threadIdx.x;
    float acc = 0.f;
    for (int i = tid; i < HH; i += 256) {
        acc += x1h[b * HH + i] * lw[i];
        acc += x2h[b * HH + i] * lw[HH + i];
        acc += fdec(keys[b * HH + i]) * lw[2 * HH + i];
        acc += wvp[b * HH + i] * lw[3 * HH + i];
    }
    __shared__ float red[4];
    int wid = tid >> 6, lane = tid & 63;
#pragma unroll
    for (int off = 32; off; off >>= 1) acc += __shfl_down(acc, off);
    if (lane == 0) red[wid] = acc;
    __syncthreads();
    if (tid == 0) {
        float z = red[0] + red[1] + red[2] + red[3] + lb[0];
        out[b] = 1.f / (1.f + __expf(-z));
    }
}

// ---------------------------------------------------------------------------
extern "C" void kernel_launch(void* const* d_in, const int* in_sizes, int n_in,
                              void* d_out, int out_size, void* d_ws, size_t ws_size,
                              hipStream_t stream) {
    const float* x1   = (const float*)d_in[0];
    const float* x1h  = (const float*)d_in[1];
    const int*   m1   = (const int*)d_in[2];
    const float* y    = (const float*)d_in[3];
    const float* x2   = (const float*)d_in[4];
    const float* x2h  = (const float*)d_in[5];
    const int*   m2   = (const int*)d_in[6];
    const float* tt   = (const float*)d_in[7];
    const float* tt2  = (const float*)d_in[8];
    const float* Wb   = (const float*)d_in[9];
    const float* Wwv  = (const float*)d_in[10];
    const float* lwvw = (const float*)d_in[11];
    const float* lwvb = (const float*)d_in[12];
    const float* lw   = (const float*)d_in[13];
    const float* lb   = (const float*)d_in[14];
    float* out = (float*)d_out;
    char* ws = (char*)d_ws;

    // fixed region
    u32*      x12key   = (u32*)ws;                    // 196608
    u32*      x12wvkey = (u32*)(ws + 196608);         // 51200
    float*    x12wvp   = (float*)(ws + 247808);       // 196608
    float*    rsumBuf  = (float*)(ws + 444416);       // 131072
    _Float16* wbTH     = (_Float16*)(ws + 575488);    // 768*800*2 = 1228800
    _Float16* wwTH     = (_Float16*)(ws + 1804288);   // 256*224*2 = 114688
    int*      idxBuf   = (int*)(ws + 1918976);        // 64*512*4  = 131072
    int*      rcntBuf  = (int*)(ws + 2050048);        // 256
    const size_t D0 = 2050304;

    k_init<<<(BB * HH + 255) / 256, 256, 0, stream>>>(x12key, x12wvkey);
    k_masks<<<(BB * SS + 255) / 256, 256, 0, stream>>>(m1, m2, out);
    k_scan<<<BB, 64, 0, stream>>>(m1, idxBuf, rcntBuf);
    k_prep_w<<<(768 * 800 + 255) / 256, 256, 0, stream>>>(Wb, wbTH, 769, 768, 800, 768);
    k_prep_w<<<(256 * 224 + 255) / 256, 256, 0, stream>>>(Wwv, wwTH, 201, 200, 224, 256);

    // ---------------- bert phase ----------------
    {
        const size_t perA = 1572864;                 // S (1MB) + P (0.5MB); Xcat aliases S
        const size_t perXW = 786432, perKV = 786432, perKT = 786432;
        const size_t perb = perA + perXW + perKV + perKT;   // 3,932,160
        int nb = 1;
        if (ws_size > D0 + perb) nb = (int)((ws_size - D0) / perb);
        if (nb > BB) nb = BB;
        if (nb < 1) nb = 1;

        _Float16* Xcat = (_Float16*)(ws + D0);       // [nb][512][800] aliases SBuf
        float*    SBuf = (float*)(ws + D0);
        _Float16* PBuf = (_Float16*)(ws + D0 + (size_t)nb * 1048576);
        _Float16* xwH  = (_Float16*)(ws + D0 + (size_t)nb * perA);
        _Float16* kv   = (_Float16*)((char*)xwH + (size_t)nb * perXW);
        _Float16* kvT  = (_Float16*)((char*)kv + (size_t)nb * perKV);

        for (int b0 = 0; b0 < BB; b0 += nb) {
            int cb = (BB - b0 < nb) ? (BB - b0) : nb;
            k_prep_kv<768, 768, 768><<<dim3(cb * 8, 12), 256, 0, stream>>>(x2, kv, kvT, b0);
            k_prep_x<<<dim3(400, cb), 256, 0, stream>>>(x1, y, idxBuf, rcntBuf,
                                                        Xcat, 768, 800, b0);
            // xw = Xcat @ W^T : KA=800, 25 steps, out fp16 [cb][512][768]
            k_mm1<25, 6, 1><<<cb * 24, 256, 0, stream>>>(
                Xcat, wbTH, 800, (size_t)SS * 800, 0,
                nullptr, xwH, 768, nullptr, nullptr, 0, rcntBuf, b0, cb * 24);
            // S = xwH @ kv^T : KA=768, 24 steps, out fp32
            k_mm1<24, 4, 0><<<cb * 16, 256, 0, stream>>>(
                xwH, kv, 768, (size_t)SS * 768, (size_t)SS * 768,
                SBuf, nullptr, 0, nullptr, nullptr, 0, rcntBuf, b0, cb * 16);
            k_softmax<<<cb * 128, 256, 0, stream>>>(SBuf, m2, rcntBuf, PBuf, rsumBuf, b0);
            // V = P @ kvT^T + fused max : KA=512, 16 steps
            k_mm1<16, 6, 2><<<cb * 24, 256, 0, stream>>>(
                PBuf, kvT, 512, (size_t)SS * 512, (size_t)768 * 512,
                nullptr, nullptr, 0, rsumBuf, x12key, 768, rcntBuf, b0, cb * 24);
        }
    }

    // ---------------- wv phase ----------------
    {
        const size_t perA = 1572864;
        const size_t perXW = 262144, perKV = 262144, perKT = 262144;
        const size_t perb = perA + perXW + perKV + perKT;   // 2,359,296
        int nb = 1;
        if (ws_size > D0 + perb) nb = (int)((ws_size - D0) / perb);
        if (nb > BB) nb = BB;
        if (nb < 1) nb = 1;

        _Float16* Xcat = (_Float16*)(ws + D0);       // [nb][512][224]
        float*    SBuf = (float*)(ws + D0);
        _Float16* PBuf = (_Float16*)(ws + D0 + (size_t)nb * 1048576);
        _Float16* xwH  = (_Float16*)(ws + D0 + (size_t)nb * perA);
        _Float16* kv   = (_Float16*)((char*)xwH + (size_t)nb * perXW);
        _Float16* kvT  = (_Float16*)((char*)kv + (size_t)nb * perKV);

        for (int b0 = 0; b0 < BB; b0 += nb) {
            int cb = (BB - b0 < nb) ? (BB - b0) : nb;
            k_prep_kv<200, 256, 256><<<dim3(cb * 8, 4), 256, 0, stream>>>(tt2, kv, kvT, b0);
            k_prep_x<<<dim3(112, cb), 256, 0, stream>>>(tt, y, idxBuf, rcntBuf,
                                                        Xcat, 200, 224, b0);
            // xw : KA=224, 7 steps, out fp16 [cb][512][256] (cols 200..255 = 0)
            k_mm1<7, 2, 1><<<cb * 8, 256, 0, stream>>>(
                Xcat, wwTH, 224, (size_t)SS * 224, 0,
                nullptr, xwH, 256, nullptr, nullptr, 0, rcntBuf, b0, cb * 8);
            // S = xwH @ kv^T : KA=256, 8 steps (padded K contributes 0)
            k_mm1<8, 4, 0><<<cb * 16, 256, 0, stream>>>(
                xwH, kv, 256, (size_t)SS * 256, (size_t)SS * 256,
                SBuf, nullptr, 0, nullptr, nullptr, 0, rcntBuf, b0, cb * 16);
            k_softmax<<<cb * 128, 256, 0, stream>>>(SBuf, m2, rcntBuf, PBuf, rsumBuf, b0);
            // V = P @ kvT^T + fused max : KA=512, 16 steps, DV=200 guard
            k_mm1<16, 2, 2><<<cb * 8, 256, 0, stream>>>(
                PBuf, kvT, 512, (size_t)SS * 512, (size_t)256 * 512,
                nullptr, nullptr, 0, rsumBuf, x12wvkey, 200, rcntBuf, b0, cb * 8);
        }
    }

    k_wvproj<<<BB, 256, 0, stream>>>(x12wvkey, lwvw, lwvb, x12wvp);
    k_final<<<BB, 256, 0, stream>>>(x1h, x2h, x12key, x12wvp, lw, lb, out);
}

// Round 8
// 376.247 us; speedup vs baseline: 7.2890x; 1.0051x over previous
//
#include <hip/hip_runtime.h>

// ============================================================================
// Round 8: dispatch consolidation + fp16 S.
//   - One k_setup kernel (masks, key init, row-compaction scan, both W preps).
//   - Merged per-stage dispatches: prep_kv, prep_x, xw(k_mmM<1>), scores
//     (k_mmM<1>), softmax, pv(k_mmM<2>) each cover bert AND wv via per-block
//     branch decode (runtime KA/KSTEPS/TN/strides). 19 -> 9 dispatches.
//   - S stored fp16 (scores uses the LDS-staged vector store; softmax reads
//     f16x8): halves S traffic. absmax expected ~0.005-0.008 (thr 0.02).
// Row compaction (r7) and the 128x128 BK=32 dbuf gl16 GEMM core unchanged.
// ============================================================================

#define BB 64
#define SS 512
#define HH 768
#define DWW 200

typedef __attribute__((ext_vector_type(8))) _Float16 f16x8;
typedef __attribute__((ext_vector_type(4))) _Float16 f16x4;
typedef __attribute__((ext_vector_type(4))) float f32x4;
typedef unsigned int u32;

__device__ __forceinline__ u32 fkey(float f) {
    u32 u = __float_as_uint(f);
    return (u & 0x80000000u) ? ~u : (u | 0x80000000u);
}
__device__ __forceinline__ float fdec(u32 k) {
    u32 u = (k & 0x80000000u) ? (k & 0x7fffffffu) : ~k;
    return __uint_as_float(u);
}
__device__ __forceinline__ f32x4 mm(f16x8 a, f16x8 b, f32x4 c) {
    return __builtin_amdgcn_mfma_f32_16x16x32_f16(a, b, c, 0, 0, 0);
}
__device__ __forceinline__ void gl16(const void* g, void* l) {
    __builtin_amdgcn_global_load_lds(
        (const __attribute__((address_space(1))) void*)g,
        (__attribute__((address_space(3))) void*)l, 16, 0, 0);
}

// ---------------------------------------------------------------------------
// k_setup: [0,128) mask outputs; [128,320) key init; [320,384) compaction scan;
// [384,2784) prep_w bert; [2784,3008) prep_w wv.
__global__ __launch_bounds__(256) void k_setup(
    const int* __restrict__ m1, const int* __restrict__ m2,
    const float* __restrict__ Wb, const float* __restrict__ Wwv,
    float* __restrict__ out, u32* __restrict__ k1, u32* __restrict__ k2,
    int* __restrict__ idx, int* __restrict__ rcnt,
    _Float16* __restrict__ wbTH, _Float16* __restrict__ wwTH) {
    int bid = blockIdx.x, tid = threadIdx.x;
    if (bid < 128) {
        int i = bid * 256 + tid;
        out[BB + i]           = (float)(1 - m1[i]);
        out[BB + BB * SS + i] = (float)(1 - m2[i]);
    } else if (bid < 320) {
        int i = (bid - 128) * 256 + tid;
        u32 v = fkey(-1e5f);
        if (i < BB * HH) k1[i] = v;
        if (i < BB * DWW) k2[i] = v;
    } else if (bid < 384) {
        int b = bid - 320;
        if (tid < 64) {
            int base = 0;
#pragma unroll
            for (int c = 0; c < 8; ++c) {
                int s = c * 64 + tid;
                int v = m1[b * SS + s];
                unsigned long long bal = __ballot(v != 0);
                int pre = __popcll(bal & ((1ull << tid) - 1ull));
                if (v) idx[b * SS + base + pre] = s;
                base += __popcll(bal);
            }
            if (tid == 0) rcnt[b] = base;
        }
    } else if (bid < 2784) {
        int i = (bid - 384) * 256 + tid;          // < 768*800
        int n = i / 800, k = i - n * 800;
        wbTH[i] = (_Float16)((k < 769) ? Wb[(size_t)k * 768 + n] : 0.f);
    } else {
        int i = (bid - 2784) * 256 + tid;         // < 256*224
        int n = i / 224, k = i - n * 224;
        wwTH[i] = (_Float16)((k < 201 && n < 200) ? Wwv[(size_t)k * 200 + n] : 0.f);
    }
}

// ---------------------------------------------------------------------------
// merged KV prep: y<12 -> bert (D=768), else wv (D=200, DPAD/DTPAD=256).
__global__ __launch_bounds__(256) void k_prep_kv(
    const float* __restrict__ x2, const float* __restrict__ tt2,
    _Float16* __restrict__ kvB, _Float16* __restrict__ kvTB,
    _Float16* __restrict__ kvW, _Float16* __restrict__ kvTW, int b0) {
    __shared__ float tile[64][65];
    int ybr = blockIdx.y;
    const float* src; _Float16* kv; _Float16* kvT; int D, DPAD, DTPAD, d0;
    if (ybr < 12) { src = x2;  kv = kvB; kvT = kvTB; D = 768; DPAD = 768; DTPAD = 768; d0 = ybr * 64; }
    else          { src = tt2; kv = kvW; kvT = kvTW; D = 200; DPAD = 256; DTPAD = 256; d0 = (ybr - 12) * 64; }
    int cbi = blockIdx.x >> 3, t0 = (blockIdx.x & 7) * 64;
    int bg = b0 + cbi, tid = threadIdx.x;
    int tr = tid >> 4, dc = (tid & 15) * 4;
#pragma unroll
    for (int i = 0; i < 4; ++i) {
        int t = tr + i * 16;
        int gd = d0 + dc;
        float v[4];
        if (gd + 3 < D) {
            float4 p = *(const float4*)(src + ((size_t)bg * SS + t0 + t) * D + gd);
            v[0] = p.x; v[1] = p.y; v[2] = p.z; v[3] = p.w;
        } else {
#pragma unroll
            for (int j = 0; j < 4; ++j) {
                int d = gd + j;
                v[j] = (d < D) ? src[((size_t)bg * SS + t0 + t) * D + d] : 0.f;
            }
        }
#pragma unroll
        for (int j = 0; j < 4; ++j) tile[t][dc + j] = v[j];
        if (gd < DPAD) {
            f16x4 o;
#pragma unroll
            for (int j = 0; j < 4; ++j) o[j] = (_Float16)v[j];
            *(f16x4*)(kv + ((size_t)cbi * SS + t0 + t) * DPAD + gd) = o;
        }
    }
    __syncthreads();
#pragma unroll
    for (int i = 0; i < 4; ++i) {
        int dl = tr + i * 16, gdr = d0 + dl;
        if (gdr < DTPAD) {
            int tc = (tid & 15) * 4;
            f16x4 o;
#pragma unroll
            for (int j = 0; j < 4; ++j) o[j] = (_Float16)tile[tc + j][dl];
            *(f16x4*)(kvT + ((size_t)cbi * DTPAD + gdr) * SS + t0 + tc) = o;
        }
    }
}

// ---------------------------------------------------------------------------
// merged compacted-Xcat prep: x<400 -> bert, else wv.
__global__ __launch_bounds__(256) void k_prep_x(
    const float* __restrict__ x1, const float* __restrict__ tt,
    const float* __restrict__ yv,
    const int* __restrict__ idx, const int* __restrict__ rcnt,
    _Float16* __restrict__ XcB, _Float16* __restrict__ XcW, int b0) {
    int cbi = blockIdx.y, bg = b0 + cbi;
    int xb = blockIdx.x;
    const float* X; _Float16* out; int Din, KPAD; size_t ost;
    if (xb < 400) { X = x1; out = XcB; Din = 768; KPAD = 800; ost = (size_t)cbi * 409600; }
    else { xb -= 400; X = tt; out = XcW; Din = 200; KPAD = 224; ost = (size_t)cbi * 114688; }
    int i4 = (xb * 256 + threadIdx.x) * 4;
    int s = i4 / KPAD, k0 = i4 - s * KPAD;
    int rc = rcnt[bg];
    int rpad = (rc + 127) & ~127;
    if (s >= rpad) return;
    f16x4 o = {(_Float16)0.f, (_Float16)0.f, (_Float16)0.f, (_Float16)0.f};
    if (s < rc) {
        int sg = idx[bg * SS + s];
        const float* Xr = X + ((size_t)bg * SS + sg) * Din;
        if (k0 + 3 < Din) {
            float4 p = *(const float4*)(Xr + k0);
            o[0] = (_Float16)p.x; o[1] = (_Float16)p.y;
            o[2] = (_Float16)p.z; o[3] = (_Float16)p.w;
        } else {
#pragma unroll
            for (int j = 0; j < 4; ++j) {
                int k = k0 + j;
                float v = (k < Din) ? Xr[k]
                                    : ((k == Din) ? yv[(size_t)bg * SS + sg] : 0.f);
                o[j] = (_Float16)v;
            }
        }
    }
    *(f16x4*)(out + ost + (size_t)s * KPAD + k0) = o;
}

// ---------------------------------------------------------------------------
// Merged runtime-parameterized GEMM. Branch 0 = bert, 1 = wv (lb >= nj0).
// EPI=1: fp16 out via LDS-staged 16B stores (used for xw AND scores->S16).
// EPI=2: fused normalize + compacted-row-gate + maxpool.
template<int EPI>
__global__ __launch_bounds__(256) void k_mmM(
    const _Float16* __restrict__ A0, const _Float16* __restrict__ B0,
    _Float16* __restrict__ O0, const float* __restrict__ rs0, u32* __restrict__ key0,
    const _Float16* __restrict__ A1, const _Float16* __restrict__ B1,
    _Float16* __restrict__ O1, const float* __restrict__ rs1, u32* __restrict__ key1,
    int KA0, int KST0, int TN0, int SXW0, int DV0, int aS0, int bS0,
    int KA1, int KST1, int TN1, int SXW1, int DV1, int aS1, int bS1,
    int nj0, const int* __restrict__ rcnt, int b0, int nwg) {
    __shared__ __align__(16) char lds[32768];
    __shared__ float rsv[128];

    int bid = blockIdx.x;
    int lb = (bid & 7) * (nwg >> 3) + (bid >> 3);   // XCD remap (nwg % 8 == 0)
    bool sel = lb >= nj0;
    int jb = sel ? lb - nj0 : lb;
    const _Float16* A = sel ? A1 : A0;
    const _Float16* B = sel ? B1 : B0;
    _Float16* O = sel ? O1 : O0;
    const float* rsum = sel ? rs1 : rs0;
    u32* keys = sel ? key1 : key0;
    int KA  = sel ? KA1 : KA0,  KST = sel ? KST1 : KST0, TN = sel ? TN1 : TN0;
    int SXW = sel ? SXW1 : SXW0, DV = sel ? DV1 : DV0;
    int aS  = sel ? aS1 : aS0,  bS  = sel ? bS1 : bS0;

    int cbi = jb / (4 * TN);
    int rest = jb - cbi * (4 * TN);
    int ts = rest / TN, tn = rest - ts * TN;
    int s0 = ts * 128, n0 = tn * 128;

    int rc = rcnt[b0 + cbi];
    int rpad = (rc + 127) & ~127;
    if (s0 >= rpad) return;

    int tid = threadIdx.x, lane = tid & 63, wid = tid >> 6;
    int wr = wid >> 1, wc = wid & 1;
    int l15 = lane & 15, sl = lane >> 4, gb = sl * 4;

    const _Float16* srcA = A + (size_t)cbi * aS + (size_t)s0 * KA;
    const _Float16* srcB = B + (size_t)cbi * bS + (size_t)n0 * KA;

    if constexpr (EPI == 2) {
        if (tid < 128) rsv[tid] = rsum[cbi * SS + s0 + tid];
    }

    f32x4 zz = {0.f, 0.f, 0.f, 0.f};
    f32x4 acc[4][4];
#pragma unroll
    for (int i = 0; i < 4; ++i)
#pragma unroll
        for (int j = 0; j < 4; ++j) acc[i][j] = zz;

#define STAGE(buf, ks)                                                        \
    _Pragma("unroll") for (int i = 0; i < 4; ++i) {                           \
        int c = wid + 4 * i;                                                  \
        int arr = c >> 3, sub = c & 7, slot = sub >> 1, rh = sub & 1;         \
        const _Float16* gp = (arr ? srcB : srcA) +                            \
            (size_t)(rh * 64 + lane) * KA + (ks) * 32 + slot * 8;             \
        gl16(gp, lds + (buf) * 16384 + c * 1024);                             \
    }

    STAGE(0, 0);
    __syncthreads();
    int buf = 0;
    for (int ks = 0; ks < KST; ++ks) {
        if (ks + 1 < KST) STAGE(buf ^ 1, ks + 1);
        char* base = lds + buf * 16384;
        f16x8 a[4], b[4];
#pragma unroll
        for (int mf = 0; mf < 4; ++mf)
            a[mf] = *(const f16x8*)(base + sl * 2048 + (wr * 64 + mf * 16 + l15) * 16);
#pragma unroll
        for (int nf = 0; nf < 4; ++nf)
            b[nf] = *(const f16x8*)(base + 8192 + sl * 2048 + (wc * 64 + nf * 16 + l15) * 16);
#pragma unroll
        for (int mf = 0; mf < 4; ++mf)
#pragma unroll
            for (int nf = 0; nf < 4; ++nf)
                acc[mf][nf] = mm(a[mf], b[nf], acc[mf][nf]);
        __syncthreads();
        buf ^= 1;
    }
#undef STAGE

    if constexpr (EPI == 1) {
        _Float16* ce = (_Float16*)lds;
#pragma unroll
        for (int mf = 0; mf < 4; ++mf)
#pragma unroll
            for (int nf = 0; nf < 4; ++nf)
#pragma unroll
                for (int r = 0; r < 4; ++r) {
                    int row = wr * 64 + mf * 16 + gb + r;
                    int col = wc * 64 + nf * 16 + l15;
                    ce[row * 128 + col] = (_Float16)acc[mf][nf][r];
                }
        __syncthreads();
#pragma unroll
        for (int i = 0; i < 8; ++i) {
            int t = tid + i * 256;
            int row = t >> 4, col = (t & 15) * 8;
            *(f16x8*)(O + ((size_t)cbi * SS + s0 + row) * SXW + n0 + col) =
                *(const f16x8*)(ce + row * 128 + col);
        }
    } else {
        int bg = b0 + cbi;
#pragma unroll
        for (int nf = 0; nf < 4; ++nf) {
            float mx = -3.0e38f;
#pragma unroll
            for (int mf = 0; mf < 4; ++mf)
#pragma unroll
                for (int r = 0; r < 4; ++r) {
                    int srow = wr * 64 + mf * 16 + gb + r;
                    if (s0 + srow < rc) mx = fmaxf(mx, acc[mf][nf][r] * rsv[srow]);
                }
            mx = fmaxf(mx, __shfl_xor(mx, 16));
            mx = fmaxf(mx, __shfl_xor(mx, 32));
            if (lane < 16) {
                int d = n0 + wc * 64 + nf * 16 + lane;
                if (d < DV) atomicMax(&keys[(size_t)bg * DV + d], fkey(mx));
            }
        }
    }
}

// ---------------------------------------------------------------------------
// merged row softmax over fp16 S: exact max, unnormalized fp16 P, 1/sum.
__global__ __launch_bounds__(256) void k_softmaxM(
    const _Float16* __restrict__ S0, _Float16* __restrict__ P0, float* __restrict__ rs0,
    const _Float16* __restrict__ S1, _Float16* __restrict__ P1, float* __restrict__ rs1,
    const int* __restrict__ m2, const int* __restrict__ rcnt, int nblk0, int b0) {
    int bid = blockIdx.x;
    bool selw = bid >= nblk0;
    int b = selw ? bid - nblk0 : bid;
    const _Float16* S = selw ? S1 : S0;
    _Float16* P = selw ? P1 : P0;
    float* rs = selw ? rs1 : rs0;
    int cbi = b >> 7, rb = b & 127;
    int wid = threadIdx.x >> 6, lane = threadIdx.x & 63;
    int row = rb * 4 + wid, bg = b0 + cbi;
    int rc = rcnt[bg];
    int rpad = (rc + 127) & ~127;
    if (row >= rpad) return;
    if (row >= rc) {
        f16x8 z = {};
        *(f16x8*)(P + ((size_t)cbi * SS + row) * SS + lane * 8) = z;
        if (lane == 0) rs[cbi * SS + row] = 0.f;
        return;
    }
    f16x8 sv = *(const f16x8*)(S + ((size_t)cbi * SS + row) * SS + lane * 8);
    int4 q0 = *(const int4*)(m2 + bg * SS + lane * 8);
    int4 q1 = *(const int4*)(m2 + bg * SS + lane * 8 + 4);
    const int qm[8] = {q0.x, q0.y, q0.z, q0.w, q1.x, q1.y, q1.z, q1.w};
    float c[8];
#pragma unroll
    for (int j = 0; j < 8; ++j) c[j] = qm[j] ? (float)sv[j] : -1e-5f;
    float mx = c[0];
#pragma unroll
    for (int j = 1; j < 8; ++j) mx = fmaxf(mx, c[j]);
#pragma unroll
    for (int off = 1; off <= 32; off <<= 1) mx = fmaxf(mx, __shfl_xor(mx, off));
    f16x8 o;
    float sm = 0.f;
#pragma unroll
    for (int j = 0; j < 8; ++j) {
        _Float16 h = (_Float16)__expf(c[j] - mx);
        o[j] = h;
        sm += (float)h;
    }
#pragma unroll
    for (int off = 1; off <= 32; off <<= 1) sm += __shfl_xor(sm, off);
    *(f16x8*)(P + ((size_t)cbi * SS + row) * SS + lane * 8) = o;
    if (lane == 0) rs[cbi * SS + row] = 1.0f / sm;
}

// ---------------------------------------------------------------------------
__global__ __launch_bounds__(256) void k_wvproj(const u32* __restrict__ wvkeys,
                                                const float* __restrict__ Wp,
                                                const float* __restrict__ bp,
                                                float* __restrict__ outp) {
    int b = blockIdx.x;
    __shared__ float xv[DWW];
    int tid = threadIdx.x;
    if (tid < DWW) xv[tid] = fdec(wvkeys[b * DWW + tid]);
    __syncthreads();
    for (int h = tid; h < HH; h += 256) {
        float acc = bp[h];
        for (int d = 0; d < DWW; ++d) acc += xv[d] * Wp[d * HH + h];
        outp[b * HH + h] = acc;
    }
}

__global__ __launch_bounds__(256) void k_final(const float* __restrict__ x1h,
                                               const float* __restrict__ x2h,
                                               const u32* __restrict__ keys,
                                               const float* __restrict__ wvp,
                                               const float* __restrict__ lw,
                                               const float* __restrict__ lb,
                                               float* __restrict__ out) {
    int b = blockIdx.x;
    int tid = threadIdx.x;
    float acc = 0.f;
    for (int i = tid; i < HH; i += 256) {
        acc += x1h[b * HH + i] * lw[i];
        acc += x2h[b * HH + i] * lw[HH + i];
        acc += fdec(keys[b * HH + i]) * lw[2 * HH + i];
        acc += wvp[b * HH + i] * lw[3 * HH + i];
    }
    __shared__ float red[4];
    int wid = tid >> 6, lane = tid & 63;
#pragma unroll
    for (int off = 32; off; off >>= 1) acc += __shfl_down(acc, off);
    if (lane == 0) red[wid] = acc;
    __syncthreads();
    if (tid == 0) {
        float z = red[0] + red[1] + red[2] + red[3] + lb[0];
        out[b] = 1.f / (1.f + __expf(-z));
    }
}

// ---------------------------------------------------------------------------
extern "C" void kernel_launch(void* const* d_in, const int* in_sizes, int n_in,
                              void* d_out, int out_size, void* d_ws, size_t ws_size,
                              hipStream_t stream) {
    const float* x1   = (const float*)d_in[0];
    const float* x1h  = (const float*)d_in[1];
    const int*   m1   = (const int*)d_in[2];
    const float* y    = (const float*)d_in[3];
    const float* x2   = (const float*)d_in[4];
    const float* x2h  = (const float*)d_in[5];
    const int*   m2   = (const int*)d_in[6];
    const float* tt   = (const float*)d_in[7];
    const float* tt2  = (const float*)d_in[8];
    const float* Wb   = (const float*)d_in[9];
    const float* Wwv  = (const float*)d_in[10];
    const float* lwvw = (const float*)d_in[11];
    const float* lwvb = (const float*)d_in[12];
    const float* lw   = (const float*)d_in[13];
    const float* lb   = (const float*)d_in[14];
    float* out = (float*)d_out;
    char* ws = (char*)d_ws;

    // fixed region
    u32*      x12key   = (u32*)ws;                    // 196608
    u32*      x12wvkey = (u32*)(ws + 196608);         // 51200
    float*    x12wvp   = (float*)(ws + 247808);       // 196608
    float*    rsumB    = (float*)(ws + 444416);       // 131072
    float*    rsumW    = (float*)(ws + 575488);       // 131072
    _Float16* wbTH     = (_Float16*)(ws + 706560);    // 768*800*2 = 1228800
    _Float16* wwTH     = (_Float16*)(ws + 1935360);   // 256*224*2 = 114688
    int*      idxBuf   = (int*)(ws + 2050048);        // 131072
    int*      rcntBuf  = (int*)(ws + 2181120);        // 256
    const size_t D0 = 2181376;

    k_setup<<<3008, 256, 0, stream>>>(m1, m2, Wb, Wwv, out, x12key, x12wvkey,
                                      idxBuf, rcntBuf, wbTH, wwTH);

    const size_t perb = 5242880;
    int nb = 1;
    if (ws_size > D0 + perb) nb = (int)((ws_size - D0) / perb);
    if (nb > BB) nb = BB;
    if (nb < 1) nb = 1;

    char* R = ws + D0;
    _Float16* XcB = (_Float16*)R;                            // stride 409600 elem
    _Float16* XcW = (_Float16*)(R + (size_t)nb * 819200);    // stride 114688
    _Float16* S_b = (_Float16*)R;                            // stride 262144 (alias Xc)
    _Float16* S_w = (_Float16*)(R + (size_t)nb * 524288);    // stride 262144
    char* p = R + (size_t)nb * 1048576;
    _Float16* XW_b = (_Float16*)p; p += (size_t)nb * 786432;  // stride 393216
    _Float16* XW_w = (_Float16*)p; p += (size_t)nb * 262144;  // stride 131072
    _Float16* KV_b = (_Float16*)p; p += (size_t)nb * 786432;  // stride 393216
    _Float16* KV_w = (_Float16*)p; p += (size_t)nb * 262144;  // stride 131072
    _Float16* KT_b = (_Float16*)p; p += (size_t)nb * 786432;  // stride 393216
    _Float16* KT_w = (_Float16*)p; p += (size_t)nb * 262144;  // stride 131072
    _Float16* P_b  = (_Float16*)p; p += (size_t)nb * 524288;  // stride 262144
    _Float16* P_w  = (_Float16*)p;                            // stride 262144

    for (int b0 = 0; b0 < BB; b0 += nb) {
        int cb = (BB - b0 < nb) ? (BB - b0) : nb;
        k_prep_kv<<<dim3(cb * 8, 16), 256, 0, stream>>>(
            x2, tt2, KV_b, KT_b, KV_w, KT_w, b0);
        k_prep_x<<<dim3(512, cb), 256, 0, stream>>>(
            x1, tt, y, idxBuf, rcntBuf, XcB, XcW, b0);
        // xw: bert 25 steps KA=800 TN=6; wv 7 steps KA=224 TN=2
        k_mmM<1><<<cb * 32, 256, 0, stream>>>(
            XcB, wbTH, XW_b, nullptr, nullptr,
            XcW, wwTH, XW_w, nullptr, nullptr,
            800, 25, 6, 768, 0, 409600, 0,
            224, 7, 2, 256, 0, 114688, 0,
            cb * 24, rcntBuf, b0, cb * 32);
        // scores -> fp16 S: bert 24 steps KA=768; wv 8 steps KA=256 (TN=4 both)
        k_mmM<1><<<cb * 32, 256, 0, stream>>>(
            XW_b, KV_b, S_b, nullptr, nullptr,
            XW_w, KV_w, S_w, nullptr, nullptr,
            768, 24, 4, 512, 0, 393216, 393216,
            256, 8, 4, 512, 0, 131072, 131072,
            cb * 16, rcntBuf, b0, cb * 32);
        k_softmaxM<<<cb * 256, 256, 0, stream>>>(
            S_b, P_b, rsumB, S_w, P_w, rsumW, m2, rcntBuf, cb * 128, b0);
        // pv: KA=512, 16 steps; bert TN=6 DV=768; wv TN=2 DV=200
        k_mmM<2><<<cb * 32, 256, 0, stream>>>(
            P_b, KT_b, nullptr, rsumB, x12key,
            P_w, KT_w, nullptr, rsumW, x12wvkey,
            512, 16, 6, 0, 768, 262144, 393216,
            512, 16, 2, 0, 200, 262144, 131072,
            cb * 24, rcntBuf, b0, cb * 32);
    }

    k_wvproj<<<BB, 256, 0, stream>>>(x12wvkey, lwvw, lwvb, x12wvp);
    k_final<<<BB, 256, 0, stream>>>(x1h, x2h, x12key, x12wvp, lw, lb, out);
}

// Round 9
// 364.361 us; speedup vs baseline: 7.5268x; 1.0326x over previous
//
#include <hip/hip_runtime.h>

// ============================================================================
// Round 9: merged dispatches (r8) + compile-time GEMM params (r7 codegen).
//   k_mmM carries TWO full compile-time parameter sets; per-block branch
//   selects the instantiation (bert vs wv) by block id only. K-loops fully
//   unrolled, addressing constant-folded. prep_kv+prep_x merged into k_prep.
// Numerics identical to r7/r8: 1-term fp16, fp16 S, exact softmax max,
// row compaction, fused PV normalize+rowgate+maxpool.
// ============================================================================

#define BB 64
#define SS 512
#define HH 768
#define DWW 200

typedef __attribute__((ext_vector_type(8))) _Float16 f16x8;
typedef __attribute__((ext_vector_type(4))) _Float16 f16x4;
typedef __attribute__((ext_vector_type(4))) float f32x4;
typedef unsigned int u32;

__device__ __forceinline__ u32 fkey(float f) {
    u32 u = __float_as_uint(f);
    return (u & 0x80000000u) ? ~u : (u | 0x80000000u);
}
__device__ __forceinline__ float fdec(u32 k) {
    u32 u = (k & 0x80000000u) ? (k & 0x7fffffffu) : ~k;
    return __uint_as_float(u);
}
__device__ __forceinline__ f32x4 mm(f16x8 a, f16x8 b, f32x4 c) {
    return __builtin_amdgcn_mfma_f32_16x16x32_f16(a, b, c, 0, 0, 0);
}
__device__ __forceinline__ void gl16(const void* g, void* l) {
    __builtin_amdgcn_global_load_lds(
        (const __attribute__((address_space(1))) void*)g,
        (__attribute__((address_space(3))) void*)l, 16, 0, 0);
}

// ---------------------------------------------------------------------------
// k_setup: [0,128) mask outputs; [128,320) key init; [320,384) compaction scan;
// [384,2784) prep_w bert; [2784,3008) prep_w wv.
__global__ __launch_bounds__(256) void k_setup(
    const int* __restrict__ m1, const int* __restrict__ m2,
    const float* __restrict__ Wb, const float* __restrict__ Wwv,
    float* __restrict__ out, u32* __restrict__ k1, u32* __restrict__ k2,
    int* __restrict__ idx, int* __restrict__ rcnt,
    _Float16* __restrict__ wbTH, _Float16* __restrict__ wwTH) {
    int bid = blockIdx.x, tid = threadIdx.x;
    if (bid < 128) {
        int i = bid * 256 + tid;
        out[BB + i]           = (float)(1 - m1[i]);
        out[BB + BB * SS + i] = (float)(1 - m2[i]);
    } else if (bid < 320) {
        int i = (bid - 128) * 256 + tid;
        u32 v = fkey(-1e5f);
        if (i < BB * HH) k1[i] = v;
        if (i < BB * DWW) k2[i] = v;
    } else if (bid < 384) {
        int b = bid - 320;
        if (tid < 64) {
            int base = 0;
#pragma unroll
            for (int c = 0; c < 8; ++c) {
                int s = c * 64 + tid;
                int v = m1[b * SS + s];
                unsigned long long bal = __ballot(v != 0);
                int pre = __popcll(bal & ((1ull << tid) - 1ull));
                if (v) idx[b * SS + base + pre] = s;
                base += __popcll(bal);
            }
            if (tid == 0) rcnt[b] = base;
        }
    } else if (bid < 2784) {
        int i = (bid - 384) * 256 + tid;          // < 768*800
        int n = i / 800, k = i - n * 800;
        wbTH[i] = (_Float16)((k < 769) ? Wb[(size_t)k * 768 + n] : 0.f);
    } else {
        int i = (bid - 2784) * 256 + tid;         // < 256*224
        int n = i / 224, k = i - n * 224;
        wwTH[i] = (_Float16)((k < 201 && n < 200) ? Wwv[(size_t)k * 200 + n] : 0.f);
    }
}

// ---------------------------------------------------------------------------
// merged input prep: [0, cb*128) KV tiles (bert 12 d-slabs + wv 4);
// [cb*128, cb*640) compacted Xcat (bert 400 + wv 112 col-blocks).
__global__ __launch_bounds__(256) void k_prep(
    const float* __restrict__ x2, const float* __restrict__ tt2,
    const float* __restrict__ x1, const float* __restrict__ tt,
    const float* __restrict__ yv,
    const int* __restrict__ idx, const int* __restrict__ rcnt,
    _Float16* __restrict__ kvB, _Float16* __restrict__ kvTB,
    _Float16* __restrict__ kvW, _Float16* __restrict__ kvTW,
    _Float16* __restrict__ XcB, _Float16* __restrict__ XcW,
    int cb, int b0) {
    __shared__ float tile[64][65];
    int bx = blockIdx.x, tid = threadIdx.x;
    if (bx < cb * 128) {
        int cbi = bx >> 7, sub = bx & 127;
        int t0 = (sub & 7) * 64, ybr = sub >> 3;
        const float* src; _Float16* kv; _Float16* kvT; int D, DPAD, DTPAD, d0;
        if (ybr < 12) { src = x2;  kv = kvB; kvT = kvTB; D = 768; DPAD = 768; DTPAD = 768; d0 = ybr * 64; }
        else          { src = tt2; kv = kvW; kvT = kvTW; D = 200; DPAD = 256; DTPAD = 256; d0 = (ybr - 12) * 64; }
        int bg = b0 + cbi;
        int tr = tid >> 4, dc = (tid & 15) * 4;
#pragma unroll
        for (int i = 0; i < 4; ++i) {
            int t = tr + i * 16;
            int gd = d0 + dc;
            float v[4];
            if (gd + 3 < D) {
                float4 p = *(const float4*)(src + ((size_t)bg * SS + t0 + t) * D + gd);
                v[0] = p.x; v[1] = p.y; v[2] = p.z; v[3] = p.w;
            } else {
#pragma unroll
                for (int j = 0; j < 4; ++j) {
                    int d = gd + j;
                    v[j] = (d < D) ? src[((size_t)bg * SS + t0 + t) * D + d] : 0.f;
                }
            }
#pragma unroll
            for (int j = 0; j < 4; ++j) tile[t][dc + j] = v[j];
            if (gd < DPAD) {
                f16x4 o;
#pragma unroll
                for (int j = 0; j < 4; ++j) o[j] = (_Float16)v[j];
                *(f16x4*)(kv + ((size_t)cbi * SS + t0 + t) * DPAD + gd) = o;
            }
        }
        __syncthreads();
#pragma unroll
        for (int i = 0; i < 4; ++i) {
            int dl = tr + i * 16, gdr = d0 + dl;
            if (gdr < DTPAD) {
                int tc = (tid & 15) * 4;
                f16x4 o;
#pragma unroll
                for (int j = 0; j < 4; ++j) o[j] = (_Float16)tile[tc + j][dl];
                *(f16x4*)(kvT + ((size_t)cbi * DTPAD + gdr) * SS + t0 + tc) = o;
            }
        }
    } else {
        bx -= cb * 128;
        int cbi = bx >> 9, xb = bx & 511;
        int bg = b0 + cbi;
        const float* X; _Float16* outp; int Din, KPAD; size_t ost;
        if (xb < 400) { X = x1; outp = XcB; Din = 768; KPAD = 800; ost = (size_t)cbi * 409600; }
        else { xb -= 400; X = tt; outp = XcW; Din = 200; KPAD = 224; ost = (size_t)cbi * 114688; }
        int i4 = (xb * 256 + tid) * 4;
        int s = i4 / KPAD, k0 = i4 - s * KPAD;
        int rc = rcnt[bg];
        int rpad = (rc + 127) & ~127;
        if (s >= rpad) return;
        f16x4 o = {(_Float16)0.f, (_Float16)0.f, (_Float16)0.f, (_Float16)0.f};
        if (s < rc) {
            int sg = idx[bg * SS + s];
            const float* Xr = X + ((size_t)bg * SS + sg) * Din;
            if (k0 + 3 < Din) {
                float4 p = *(const float4*)(Xr + k0);
                o[0] = (_Float16)p.x; o[1] = (_Float16)p.y;
                o[2] = (_Float16)p.z; o[3] = (_Float16)p.w;
            } else {
#pragma unroll
                for (int j = 0; j < 4; ++j) {
                    int k = k0 + j;
                    float v = (k < Din) ? Xr[k]
                                        : ((k == Din) ? yv[(size_t)bg * SS + sg] : 0.f);
                    o[j] = (_Float16)v;
                }
            }
        }
        *(f16x4*)(outp + ost + (size_t)s * KPAD + k0) = o;
    }
}

// ---------------------------------------------------------------------------
// Compile-time GEMM core (r7 codegen). C[128x128] = A[128xKA] * B[128xKA]^T.
// BK=32 dbuf, gl16 staging, 16 MFMA per step. EPI=1: fp16 out (LDS-staged
// 16B stores, row stride SXW, batch stride SS*SXW). EPI=2: fused normalize +
// compacted-row-gate + maxpool via atomicMax.
template<int KA, int KST, int TN, int SXW, int DV, int AS, int BS, int EPI>
__device__ __forceinline__ void mm_core(
    const _Float16* __restrict__ A, const _Float16* __restrict__ B,
    _Float16* __restrict__ O, const float* __restrict__ rsum,
    u32* __restrict__ keys, int jb, const int* __restrict__ rcnt,
    int b0, char* lds, float* rsv) {
    int cbi = jb / (4 * TN);
    int rest = jb - cbi * (4 * TN);
    int ts = rest / TN, tn = rest - ts * TN;
    int s0 = ts * 128, n0 = tn * 128;

    int rc = rcnt[b0 + cbi];
    int rpad = (rc + 127) & ~127;
    if (s0 >= rpad) return;

    int tid = threadIdx.x, lane = tid & 63, wid = tid >> 6;
    int wr = wid >> 1, wc = wid & 1;
    int l15 = lane & 15, sl = lane >> 4, gb = sl * 4;

    const _Float16* srcA = A + (size_t)cbi * AS + (size_t)s0 * KA;
    const _Float16* srcB = B + (size_t)cbi * BS + (size_t)n0 * KA;

    if constexpr (EPI == 2) {
        if (tid < 128) rsv[tid] = rsum[cbi * SS + s0 + tid];
    }

    f32x4 zz = {0.f, 0.f, 0.f, 0.f};
    f32x4 acc[4][4];
#pragma unroll
    for (int i = 0; i < 4; ++i)
#pragma unroll
        for (int j = 0; j < 4; ++j) acc[i][j] = zz;

#define STAGE(buf, ks)                                                        \
    _Pragma("unroll") for (int i = 0; i < 4; ++i) {                           \
        int c = wid + 4 * i;                                                  \
        int arr = c >> 3, sub = c & 7, slot = sub >> 1, rh = sub & 1;         \
        const _Float16* gp = (arr ? srcB : srcA) +                            \
            (size_t)(rh * 64 + lane) * KA + (ks) * 32 + slot * 8;             \
        gl16(gp, lds + (buf) * 16384 + c * 1024);                             \
    }

    STAGE(0, 0);
    __syncthreads();
    int buf = 0;
#pragma unroll
    for (int ks = 0; ks < KST; ++ks) {
        if (ks + 1 < KST) STAGE(buf ^ 1, ks + 1);
        char* base = lds + buf * 16384;
        f16x8 a[4], b[4];
#pragma unroll
        for (int mf = 0; mf < 4; ++mf)
            a[mf] = *(const f16x8*)(base + sl * 2048 + (wr * 64 + mf * 16 + l15) * 16);
#pragma unroll
        for (int nf = 0; nf < 4; ++nf)
            b[nf] = *(const f16x8*)(base + 8192 + sl * 2048 + (wc * 64 + nf * 16 + l15) * 16);
#pragma unroll
        for (int mf = 0; mf < 4; ++mf)
#pragma unroll
            for (int nf = 0; nf < 4; ++nf)
                acc[mf][nf] = mm(a[mf], b[nf], acc[mf][nf]);
        __syncthreads();
        buf ^= 1;
    }
#undef STAGE

    if constexpr (EPI == 1) {
        _Float16* ce = (_Float16*)lds;
#pragma unroll
        for (int mf = 0; mf < 4; ++mf)
#pragma unroll
            for (int nf = 0; nf < 4; ++nf)
#pragma unroll
                for (int r = 0; r < 4; ++r) {
                    int row = wr * 64 + mf * 16 + gb + r;
                    int col = wc * 64 + nf * 16 + l15;
                    ce[row * 128 + col] = (_Float16)acc[mf][nf][r];
                }
        __syncthreads();
#pragma unroll
        for (int i = 0; i < 8; ++i) {
            int t = tid + i * 256;
            int row = t >> 4, col = (t & 15) * 8;
            *(f16x8*)(O + ((size_t)cbi * SS + s0 + row) * SXW + n0 + col) =
                *(const f16x8*)(ce + row * 128 + col);
        }
    } else {
        int bg = b0 + cbi;
#pragma unroll
        for (int nf = 0; nf < 4; ++nf) {
            float mx = -3.0e38f;
#pragma unroll
            for (int mf = 0; mf < 4; ++mf)
#pragma unroll
                for (int r = 0; r < 4; ++r) {
                    int srow = wr * 64 + mf * 16 + gb + r;
                    if (s0 + srow < rc) mx = fmaxf(mx, acc[mf][nf][r] * rsv[srow]);
                }
            mx = fmaxf(mx, __shfl_xor(mx, 16));
            mx = fmaxf(mx, __shfl_xor(mx, 32));
            if (lane < 16) {
                int d = n0 + wc * 64 + nf * 16 + lane;
                if (d < DV) atomicMax(&keys[(size_t)bg * DV + d], fkey(mx));
            }
        }
    }
}

// Merged dual-instantiation GEMM: lb < nj0 -> set 0 (bert), else set 1 (wv).
template<int EPI,
         int KA0, int KST0, int TN0, int SXW0, int DV0, int AS0, int BS0,
         int KA1, int KST1, int TN1, int SXW1, int DV1, int AS1, int BS1>
__global__ __launch_bounds__(256) void k_mmM(
    const _Float16* __restrict__ A0, const _Float16* __restrict__ B0,
    _Float16* __restrict__ O0, const float* __restrict__ rs0, u32* __restrict__ key0,
    const _Float16* __restrict__ A1, const _Float16* __restrict__ B1,
    _Float16* __restrict__ O1, const float* __restrict__ rs1, u32* __restrict__ key1,
    int nj0, const int* __restrict__ rcnt, int b0, int nwg) {
    __shared__ __align__(16) char lds[32768];
    __shared__ float rsv[128];
    int bid = blockIdx.x;
    int lb = (bid & 7) * (nwg >> 3) + (bid >> 3);   // XCD remap (nwg % 8 == 0)
    if (lb < nj0)
        mm_core<KA0, KST0, TN0, SXW0, DV0, AS0, BS0, EPI>(
            A0, B0, O0, rs0, key0, lb, rcnt, b0, lds, rsv);
    else
        mm_core<KA1, KST1, TN1, SXW1, DV1, AS1, BS1, EPI>(
            A1, B1, O1, rs1, key1, lb - nj0, rcnt, b0, lds, rsv);
}

// ---------------------------------------------------------------------------
// merged row softmax over fp16 S: exact max, unnormalized fp16 P, 1/sum.
__global__ __launch_bounds__(256) void k_softmaxM(
    const _Float16* __restrict__ S0, _Float16* __restrict__ P0, float* __restrict__ rs0,
    const _Float16* __restrict__ S1, _Float16* __restrict__ P1, float* __restrict__ rs1,
    const int* __restrict__ m2, const int* __restrict__ rcnt, int nblk0, int b0) {
    int bid = blockIdx.x;
    bool selw = bid >= nblk0;
    int b = selw ? bid - nblk0 : bid;
    const _Float16* S = selw ? S1 : S0;
    _Float16* P = selw ? P1 : P0;
    float* rs = selw ? rs1 : rs0;
    int cbi = b >> 7, rb = b & 127;
    int wid = threadIdx.x >> 6, lane = threadIdx.x & 63;
    int row = rb * 4 + wid, bg = b0 + cbi;
    int rc = rcnt[bg];
    int rpad = (rc + 127) & ~127;
    if (row >= rpad) return;
    if (row >= rc) {
        f16x8 z = {};
        *(f16x8*)(P + ((size_t)cbi * SS + row) * SS + lane * 8) = z;
        if (lane == 0) rs[cbi * SS + row] = 0.f;
        return;
    }
    f16x8 sv = *(const f16x8*)(S + ((size_t)cbi * SS + row) * SS + lane * 8);
    int4 q0 = *(const int4*)(m2 + bg * SS + lane * 8);
    int4 q1 = *(const int4*)(m2 + bg * SS + lane * 8 + 4);
    const int qm[8] = {q0.x, q0.y, q0.z, q0.w, q1.x, q1.y, q1.z, q1.w};
    float c[8];
#pragma unroll
    for (int j = 0; j < 8; ++j) c[j] = qm[j] ? (float)sv[j] : -1e-5f;
    float mx = c[0];
#pragma unroll
    for (int j = 1; j < 8; ++j) mx = fmaxf(mx, c[j]);
#pragma unroll
    for (int off = 1; off <= 32; off <<= 1) mx = fmaxf(mx, __shfl_xor(mx, off));
    f16x8 o;
    float sm = 0.f;
#pragma unroll
    for (int j = 0; j < 8; ++j) {
        _Float16 h = (_Float16)__expf(c[j] - mx);
        o[j] = h;
        sm += (float)h;
    }
#pragma unroll
    for (int off = 1; off <= 32; off <<= 1) sm += __shfl_xor(sm, off);
    *(f16x8*)(P + ((size_t)cbi * SS + row) * SS + lane * 8) = o;
    if (lane == 0) rs[cbi * SS + row] = 1.0f / sm;
}

// ---------------------------------------------------------------------------
__global__ __launch_bounds__(256) void k_wvproj(const u32* __restrict__ wvkeys,
                                                const float* __restrict__ Wp,
                                                const float* __restrict__ bp,
                                                float* __restrict__ outp) {
    int b = blockIdx.x;
    __shared__ float xv[DWW];
    int tid = threadIdx.x;
    if (tid < DWW) xv[tid] = fdec(wvkeys[b * DWW + tid]);
    __syncthreads();
    for (int h = tid; h < HH; h += 256) {
        float acc = bp[h];
        for (int d = 0; d < DWW; ++d) acc += xv[d] * Wp[d * HH + h];
        outp[b * HH + h] = acc;
    }
}

__global__ __launch_bounds__(256) void k_final(const float* __restrict__ x1h,
                                               const float* __restrict__ x2h,
                                               const u32* __restrict__ keys,
                                               const float* __restrict__ wvp,
                                               const float* __restrict__ lw,
                                               const float* __restrict__ lb,
                                               float* __restrict__ out) {
    int b = blockIdx.x;
    int tid = threadIdx.x;
    float acc = 0.f;
    for (int i = tid; i < HH; i += 256) {
        acc += x1h[b * HH + i] * lw[i];
        acc += x2h[b * HH + i] * lw[HH + i];
        acc += fdec(keys[b * HH + i]) * lw[2 * HH + i];
        acc += wvp[b * HH + i] * lw[3 * HH + i];
    }
    __shared__ float red[4];
    int wid = tid >> 6, lane = tid & 63;
#pragma unroll
    for (int off = 32; off; off >>= 1) acc += __shfl_down(acc, off);
    if (lane == 0) red[wid] = acc;
    __syncthreads();
    if (tid == 0) {
        float z = red[0] + red[1] + red[2] + red[3] + lb[0];
        out[b] = 1.f / (1.f + __expf(-z));
    }
}

// ---------------------------------------------------------------------------
extern "C" void kernel_launch(void* const* d_in, const int* in_sizes, int n_in,
                              void* d_out, int out_size, void* d_ws, size_t ws_size,
                              hipStream_t stream) {
    const float* x1   = (const float*)d_in[0];
    const float* x1h  = (const float*)d_in[1];
    const int*   m1   = (const int*)d_in[2];
    const float* y    = (const float*)d_in[3];
    const float* x2   = (const float*)d_in[4];
    const float* x2h  = (const float*)d_in[5];
    const int*   m2   = (const int*)d_in[6];
    const float* tt   = (const float*)d_in[7];
    const float* tt2  = (const float*)d_in[8];
    const float* Wb   = (const float*)d_in[9];
    const float* Wwv  = (const float*)d_in[10];
    const float* lwvw = (const float*)d_in[11];
    const float* lwvb = (const float*)d_in[12];
    const float* lw   = (const float*)d_in[13];
    const float* lb   = (const float*)d_in[14];
    float* out = (float*)d_out;
    char* ws = (char*)d_ws;

    // fixed region
    u32*      x12key   = (u32*)ws;                    // 196608
    u32*      x12wvkey = (u32*)(ws + 196608);         // 51200
    float*    x12wvp   = (float*)(ws + 247808);       // 196608
    float*    rsumB    = (float*)(ws + 444416);       // 131072
    float*    rsumW    = (float*)(ws + 575488);       // 131072
    _Float16* wbTH     = (_Float16*)(ws + 706560);    // 768*800*2 = 1228800
    _Float16* wwTH     = (_Float16*)(ws + 1935360);   // 256*224*2 = 114688
    int*      idxBuf   = (int*)(ws + 2050048);        // 131072
    int*      rcntBuf  = (int*)(ws + 2181120);        // 256
    const size_t D0 = 2181376;

    k_setup<<<3008, 256, 0, stream>>>(m1, m2, Wb, Wwv, out, x12key, x12wvkey,
                                      idxBuf, rcntBuf, wbTH, wwTH);

    const size_t perb = 5242880;
    int nb = 1;
    if (ws_size > D0 + perb) nb = (int)((ws_size - D0) / perb);
    if (nb > BB) nb = BB;
    if (nb < 1) nb = 1;

    char* R = ws + D0;
    _Float16* XcB = (_Float16*)R;                            // stride 409600 elem
    _Float16* XcW = (_Float16*)(R + (size_t)nb * 819200);    // stride 114688
    _Float16* S_b = (_Float16*)R;                            // stride 262144 (alias Xc)
    _Float16* S_w = (_Float16*)(R + (size_t)nb * 524288);    // stride 262144
    char* p = R + (size_t)nb * 1048576;
    _Float16* XW_b = (_Float16*)p; p += (size_t)nb * 786432;  // stride 393216
    _Float16* XW_w = (_Float16*)p; p += (size_t)nb * 262144;  // stride 131072
    _Float16* KV_b = (_Float16*)p; p += (size_t)nb * 786432;  // stride 393216
    _Float16* KV_w = (_Float16*)p; p += (size_t)nb * 262144;  // stride 131072
    _Float16* KT_b = (_Float16*)p; p += (size_t)nb * 786432;  // stride 393216
    _Float16* KT_w = (_Float16*)p; p += (size_t)nb * 262144;  // stride 131072
    _Float16* P_b  = (_Float16*)p; p += (size_t)nb * 524288;  // stride 262144
    _Float16* P_w  = (_Float16*)p;                            // stride 262144

    for (int b0 = 0; b0 < BB; b0 += nb) {
        int cb = (BB - b0 < nb) ? (BB - b0) : nb;
        k_prep<<<cb * 640, 256, 0, stream>>>(
            x2, tt2, x1, tt, y, idxBuf, rcntBuf,
            KV_b, KT_b, KV_w, KT_w, XcB, XcW, cb, b0);
        // xw: bert KA=800,25 steps,TN=6,SXW=768; wv KA=224,7,TN=2,SXW=256
        k_mmM<1, 800, 25, 6, 768, 0, 409600, 0,
                 224,  7, 2, 256, 0, 114688, 0><<<cb * 32, 256, 0, stream>>>(
            XcB, wbTH, XW_b, nullptr, nullptr,
            XcW, wwTH, XW_w, nullptr, nullptr,
            cb * 24, rcntBuf, b0, cb * 32);
        // scores -> fp16 S: bert KA=768,24,TN=4,SXW=512; wv KA=256,8,TN=4,SXW=512
        k_mmM<1, 768, 24, 4, 512, 0, 393216, 393216,
                 256,  8, 4, 512, 0, 131072, 131072><<<cb * 32, 256, 0, stream>>>(
            XW_b, KV_b, S_b, nullptr, nullptr,
            XW_w, KV_w, S_w, nullptr, nullptr,
            cb * 16, rcntBuf, b0, cb * 32);
        k_softmaxM<<<cb * 256, 256, 0, stream>>>(
            S_b, P_b, rsumB, S_w, P_w, rsumW, m2, rcntBuf, cb * 128, b0);
        // pv: KA=512,16 steps; bert TN=6 DV=768; wv TN=2 DV=200
        k_mmM<2, 512, 16, 6, 0, 768, 262144, 393216,
                 512, 16, 2, 0, 200, 262144, 131072><<<cb * 32, 256, 0, stream>>>(
            P_b, KT_b, nullptr, rsumB, x12key,
            P_w, KT_w, nullptr, rsumW, x12wvkey,
            cb * 24, rcntBuf, b0, cb * 32);
    }

    k_wvproj<<<BB, 256, 0, stream>>>(x12wvkey, lwvw, lwvb, x12wvp);
    k_final<<<BB, 256, 0, stream>>>(x1h, x2h, x12key, x12wvp, lw, lb, out);
}

// Round 10
// 324.604 us; speedup vs baseline: 8.4487x; 1.1225x over previous
//
#include <hip/hip_runtime.h>

// ============================================================================
// Round 10: fix XCD work imbalance in merged GEMMs.
//   r9's remap gave each XCD a contiguous work-id chunk, but merged work-ids
//   are [bert | wv] -> bert and wv landed on DISJOINT XCD sets with 3-3.5x
//   different per-tile cost (scores: 24 vs 8 K-steps). New mapping: XCD
//   x=bid&7 gets proportional shares of BOTH branches, batch-contiguous
//   within the XCD: t=bid>>3; t<nj0/8 -> bert jb=x*(nj0/8)+t, else wv.
// Everything else identical to r9 (compile-time dual-instantiation GEMM,
// fp16 S, row compaction, fused PV maxpool). absmax bit-identical.
// ============================================================================

#define BB 64
#define SS 512
#define HH 768
#define DWW 200

typedef __attribute__((ext_vector_type(8))) _Float16 f16x8;
typedef __attribute__((ext_vector_type(4))) _Float16 f16x4;
typedef __attribute__((ext_vector_type(4))) float f32x4;
typedef unsigned int u32;

__device__ __forceinline__ u32 fkey(float f) {
    u32 u = __float_as_uint(f);
    return (u & 0x80000000u) ? ~u : (u | 0x80000000u);
}
__device__ __forceinline__ float fdec(u32 k) {
    u32 u = (k & 0x80000000u) ? (k & 0x7fffffffu) : ~k;
    return __uint_as_float(u);
}
__device__ __forceinline__ f32x4 mm(f16x8 a, f16x8 b, f32x4 c) {
    return __builtin_amdgcn_mfma_f32_16x16x32_f16(a, b, c, 0, 0, 0);
}
__device__ __forceinline__ void gl16(const void* g, void* l) {
    __builtin_amdgcn_global_load_lds(
        (const __attribute__((address_space(1))) void*)g,
        (__attribute__((address_space(3))) void*)l, 16, 0, 0);
}

// ---------------------------------------------------------------------------
// k_setup: [0,128) mask outputs; [128,320) key init; [320,384) compaction scan;
// [384,2784) prep_w bert; [2784,3008) prep_w wv.
__global__ __launch_bounds__(256) void k_setup(
    const int* __restrict__ m1, const int* __restrict__ m2,
    const float* __restrict__ Wb, const float* __restrict__ Wwv,
    float* __restrict__ out, u32* __restrict__ k1, u32* __restrict__ k2,
    int* __restrict__ idx, int* __restrict__ rcnt,
    _Float16* __restrict__ wbTH, _Float16* __restrict__ wwTH) {
    int bid = blockIdx.x, tid = threadIdx.x;
    if (bid < 128) {
        int i = bid * 256 + tid;
        out[BB + i]           = (float)(1 - m1[i]);
        out[BB + BB * SS + i] = (float)(1 - m2[i]);
    } else if (bid < 320) {
        int i = (bid - 128) * 256 + tid;
        u32 v = fkey(-1e5f);
        if (i < BB * HH) k1[i] = v;
        if (i < BB * DWW) k2[i] = v;
    } else if (bid < 384) {
        int b = bid - 320;
        if (tid < 64) {
            int base = 0;
#pragma unroll
            for (int c = 0; c < 8; ++c) {
                int s = c * 64 + tid;
                int v = m1[b * SS + s];
                unsigned long long bal = __ballot(v != 0);
                int pre = __popcll(bal & ((1ull << tid) - 1ull));
                if (v) idx[b * SS + base + pre] = s;
                base += __popcll(bal);
            }
            if (tid == 0) rcnt[b] = base;
        }
    } else if (bid < 2784) {
        int i = (bid - 384) * 256 + tid;          // < 768*800
        int n = i / 800, k = i - n * 800;
        wbTH[i] = (_Float16)((k < 769) ? Wb[(size_t)k * 768 + n] : 0.f);
    } else {
        int i = (bid - 2784) * 256 + tid;         // < 256*224
        int n = i / 224, k = i - n * 224;
        wwTH[i] = (_Float16)((k < 201 && n < 200) ? Wwv[(size_t)k * 200 + n] : 0.f);
    }
}

// ---------------------------------------------------------------------------
// merged input prep: [0, cb*128) KV tiles (bert 12 d-slabs + wv 4);
// [cb*128, cb*640) compacted Xcat (bert 400 + wv 112 col-blocks).
__global__ __launch_bounds__(256) void k_prep(
    const float* __restrict__ x2, const float* __restrict__ tt2,
    const float* __restrict__ x1, const float* __restrict__ tt,
    const float* __restrict__ yv,
    const int* __restrict__ idx, const int* __restrict__ rcnt,
    _Float16* __restrict__ kvB, _Float16* __restrict__ kvTB,
    _Float16* __restrict__ kvW, _Float16* __restrict__ kvTW,
    _Float16* __restrict__ XcB, _Float16* __restrict__ XcW,
    int cb, int b0) {
    __shared__ float tile[64][65];
    int bx = blockIdx.x, tid = threadIdx.x;
    if (bx < cb * 128) {
        int cbi = bx >> 7, sub = bx & 127;
        int t0 = (sub & 7) * 64, ybr = sub >> 3;
        const float* src; _Float16* kv; _Float16* kvT; int D, DPAD, DTPAD, d0;
        if (ybr < 12) { src = x2;  kv = kvB; kvT = kvTB; D = 768; DPAD = 768; DTPAD = 768; d0 = ybr * 64; }
        else          { src = tt2; kv = kvW; kvT = kvTW; D = 200; DPAD = 256; DTPAD = 256; d0 = (ybr - 12) * 64; }
        int bg = b0 + cbi;
        int tr = tid >> 4, dc = (tid & 15) * 4;
#pragma unroll
        for (int i = 0; i < 4; ++i) {
            int t = tr + i * 16;
            int gd = d0 + dc;
            float v[4];
            if (gd + 3 < D) {
                float4 p = *(const float4*)(src + ((size_t)bg * SS + t0 + t) * D + gd);
                v[0] = p.x; v[1] = p.y; v[2] = p.z; v[3] = p.w;
            } else {
#pragma unroll
                for (int j = 0; j < 4; ++j) {
                    int d = gd + j;
                    v[j] = (d < D) ? src[((size_t)bg * SS + t0 + t) * D + d] : 0.f;
                }
            }
#pragma unroll
            for (int j = 0; j < 4; ++j) tile[t][dc + j] = v[j];
            if (gd < DPAD) {
                f16x4 o;
#pragma unroll
                for (int j = 0; j < 4; ++j) o[j] = (_Float16)v[j];
                *(f16x4*)(kv + ((size_t)cbi * SS + t0 + t) * DPAD + gd) = o;
            }
        }
        __syncthreads();
#pragma unroll
        for (int i = 0; i < 4; ++i) {
            int dl = tr + i * 16, gdr = d0 + dl;
            if (gdr < DTPAD) {
                int tc = (tid & 15) * 4;
                f16x4 o;
#pragma unroll
                for (int j = 0; j < 4; ++j) o[j] = (_Float16)tile[tc + j][dl];
                *(f16x4*)(kvT + ((size_t)cbi * DTPAD + gdr) * SS + t0 + tc) = o;
            }
        }
    } else {
        bx -= cb * 128;
        int cbi = bx >> 9, xb = bx & 511;
        int bg = b0 + cbi;
        const float* X; _Float16* outp; int Din, KPAD; size_t ost;
        if (xb < 400) { X = x1; outp = XcB; Din = 768; KPAD = 800; ost = (size_t)cbi * 409600; }
        else { xb -= 400; X = tt; outp = XcW; Din = 200; KPAD = 224; ost = (size_t)cbi * 114688; }
        int i4 = (xb * 256 + tid) * 4;
        int s = i4 / KPAD, k0 = i4 - s * KPAD;
        int rc = rcnt[bg];
        int rpad = (rc + 127) & ~127;
        if (s >= rpad) return;
        f16x4 o = {(_Float16)0.f, (_Float16)0.f, (_Float16)0.f, (_Float16)0.f};
        if (s < rc) {
            int sg = idx[bg * SS + s];
            const float* Xr = X + ((size_t)bg * SS + sg) * Din;
            if (k0 + 3 < Din) {
                float4 p = *(const float4*)(Xr + k0);
                o[0] = (_Float16)p.x; o[1] = (_Float16)p.y;
                o[2] = (_Float16)p.z; o[3] = (_Float16)p.w;
            } else {
#pragma unroll
                for (int j = 0; j < 4; ++j) {
                    int k = k0 + j;
                    float v = (k < Din) ? Xr[k]
                                        : ((k == Din) ? yv[(size_t)bg * SS + sg] : 0.f);
                    o[j] = (_Float16)v;
                }
            }
        }
        *(f16x4*)(outp + ost + (size_t)s * KPAD + k0) = o;
    }
}

// ---------------------------------------------------------------------------
// Compile-time GEMM core. C[128x128] = A[128xKA] * B[128xKA]^T.
// BK=32 dbuf, gl16 staging, 16 MFMA per step. EPI=1: fp16 out (LDS-staged
// 16B stores). EPI=2: fused normalize + compacted-row-gate + maxpool.
template<int KA, int KST, int TN, int SXW, int DV, int AS, int BS, int EPI>
__device__ __forceinline__ void mm_core(
    const _Float16* __restrict__ A, const _Float16* __restrict__ B,
    _Float16* __restrict__ O, const float* __restrict__ rsum,
    u32* __restrict__ keys, int jb, const int* __restrict__ rcnt,
    int b0, char* lds, float* rsv) {
    int cbi = jb / (4 * TN);
    int rest = jb - cbi * (4 * TN);
    int ts = rest / TN, tn = rest - ts * TN;
    int s0 = ts * 128, n0 = tn * 128;

    int rc = rcnt[b0 + cbi];
    int rpad = (rc + 127) & ~127;
    if (s0 >= rpad) return;

    int tid = threadIdx.x, lane = tid & 63, wid = tid >> 6;
    int wr = wid >> 1, wc = wid & 1;
    int l15 = lane & 15, sl = lane >> 4, gb = sl * 4;

    const _Float16* srcA = A + (size_t)cbi * AS + (size_t)s0 * KA;
    const _Float16* srcB = B + (size_t)cbi * BS + (size_t)n0 * KA;

    if constexpr (EPI == 2) {
        if (tid < 128) rsv[tid] = rsum[cbi * SS + s0 + tid];
    }

    f32x4 zz = {0.f, 0.f, 0.f, 0.f};
    f32x4 acc[4][4];
#pragma unroll
    for (int i = 0; i < 4; ++i)
#pragma unroll
        for (int j = 0; j < 4; ++j) acc[i][j] = zz;

#define STAGE(buf, ks)                                                        \
    _Pragma("unroll") for (int i = 0; i < 4; ++i) {                           \
        int c = wid + 4 * i;                                                  \
        int arr = c >> 3, sub = c & 7, slot = sub >> 1, rh = sub & 1;         \
        const _Float16* gp = (arr ? srcB : srcA) +                            \
            (size_t)(rh * 64 + lane) * KA + (ks) * 32 + slot * 8;             \
        gl16(gp, lds + (buf) * 16384 + c * 1024);                             \
    }

    STAGE(0, 0);
    __syncthreads();
    int buf = 0;
#pragma unroll
    for (int ks = 0; ks < KST; ++ks) {
        if (ks + 1 < KST) STAGE(buf ^ 1, ks + 1);
        char* base = lds + buf * 16384;
        f16x8 a[4], b[4];
#pragma unroll
        for (int mf = 0; mf < 4; ++mf)
            a[mf] = *(const f16x8*)(base + sl * 2048 + (wr * 64 + mf * 16 + l15) * 16);
#pragma unroll
        for (int nf = 0; nf < 4; ++nf)
            b[nf] = *(const f16x8*)(base + 8192 + sl * 2048 + (wc * 64 + nf * 16 + l15) * 16);
#pragma unroll
        for (int mf = 0; mf < 4; ++mf)
#pragma unroll
            for (int nf = 0; nf < 4; ++nf)
                acc[mf][nf] = mm(a[mf], b[nf], acc[mf][nf]);
        __syncthreads();
        buf ^= 1;
    }
#undef STAGE

    if constexpr (EPI == 1) {
        _Float16* ce = (_Float16*)lds;
#pragma unroll
        for (int mf = 0; mf < 4; ++mf)
#pragma unroll
            for (int nf = 0; nf < 4; ++nf)
#pragma unroll
                for (int r = 0; r < 4; ++r) {
                    int row = wr * 64 + mf * 16 + gb + r;
                    int col = wc * 64 + nf * 16 + l15;
                    ce[row * 128 + col] = (_Float16)acc[mf][nf][r];
                }
        __syncthreads();
#pragma unroll
        for (int i = 0; i < 8; ++i) {
            int t = tid + i * 256;
            int row = t >> 4, col = (t & 15) * 8;
            *(f16x8*)(O + ((size_t)cbi * SS + s0 + row) * SXW + n0 + col) =
                *(const f16x8*)(ce + row * 128 + col);
        }
    } else {
        int bg = b0 + cbi;
#pragma unroll
        for (int nf = 0; nf < 4; ++nf) {
            float mx = -3.0e38f;
#pragma unroll
            for (int mf = 0; mf < 4; ++mf)
#pragma unroll
                for (int r = 0; r < 4; ++r) {
                    int srow = wr * 64 + mf * 16 + gb + r;
                    if (s0 + srow < rc) mx = fmaxf(mx, acc[mf][nf][r] * rsv[srow]);
                }
            mx = fmaxf(mx, __shfl_xor(mx, 16));
            mx = fmaxf(mx, __shfl_xor(mx, 32));
            if (lane < 16) {
                int d = n0 + wc * 64 + nf * 16 + lane;
                if (d < DV) atomicMax(&keys[(size_t)bg * DV + d], fkey(mx));
            }
        }
    }
}

// Merged dual-instantiation GEMM with XCD-proportional branch split:
// XCD x = bid&7, slot t = bid>>3. Each XCD gets nj0/8 bert tiles (batch-
// contiguous) then (nwg-nj0)/8 wv tiles. Requires nj0 % 8 == 0 (all callers).
template<int EPI,
         int KA0, int KST0, int TN0, int SXW0, int DV0, int AS0, int BS0,
         int KA1, int KST1, int TN1, int SXW1, int DV1, int AS1, int BS1>
__global__ __launch_bounds__(256) void k_mmM(
    const _Float16* __restrict__ A0, const _Float16* __restrict__ B0,
    _Float16* __restrict__ O0, const float* __restrict__ rs0, u32* __restrict__ key0,
    const _Float16* __restrict__ A1, const _Float16* __restrict__ B1,
    _Float16* __restrict__ O1, const float* __restrict__ rs1, u32* __restrict__ key1,
    int nj0, const int* __restrict__ rcnt, int b0, int nwg) {
    __shared__ __align__(16) char lds[32768];
    __shared__ float rsv[128];
    int bid = blockIdx.x;
    int x = bid & 7, t = bid >> 3;
    int tb = nj0 >> 3;                 // bert tiles per XCD
    int tw = (nwg - nj0) >> 3;         // wv tiles per XCD
    if (t < tb)
        mm_core<KA0, KST0, TN0, SXW0, DV0, AS0, BS0, EPI>(
            A0, B0, O0, rs0, key0, x * tb + t, rcnt, b0, lds, rsv);
    else
        mm_core<KA1, KST1, TN1, SXW1, DV1, AS1, BS1, EPI>(
            A1, B1, O1, rs1, key1, x * tw + (t - tb), rcnt, b0, lds, rsv);
}

// ---------------------------------------------------------------------------
// merged row softmax over fp16 S: exact max, unnormalized fp16 P, 1/sum.
__global__ __launch_bounds__(256) void k_softmaxM(
    const _Float16* __restrict__ S0, _Float16* __restrict__ P0, float* __restrict__ rs0,
    const _Float16* __restrict__ S1, _Float16* __restrict__ P1, float* __restrict__ rs1,
    const int* __restrict__ m2, const int* __restrict__ rcnt, int nblk0, int b0) {
    int bid = blockIdx.x;
    bool selw = bid >= nblk0;
    int b = selw ? bid - nblk0 : bid;
    const _Float16* S = selw ? S1 : S0;
    _Float16* P = selw ? P1 : P0;
    float* rs = selw ? rs1 : rs0;
    int cbi = b >> 7, rb = b & 127;
    int wid = threadIdx.x >> 6, lane = threadIdx.x & 63;
    int row = rb * 4 + wid, bg = b0 + cbi;
    int rc = rcnt[bg];
    int rpad = (rc + 127) & ~127;
    if (row >= rpad) return;
    if (row >= rc) {
        f16x8 z = {};
        *(f16x8*)(P + ((size_t)cbi * SS + row) * SS + lane * 8) = z;
        if (lane == 0) rs[cbi * SS + row] = 0.f;
        return;
    }
    f16x8 sv = *(const f16x8*)(S + ((size_t)cbi * SS + row) * SS + lane * 8);
    int4 q0 = *(const int4*)(m2 + bg * SS + lane * 8);
    int4 q1 = *(const int4*)(m2 + bg * SS + lane * 8 + 4);
    const int qm[8] = {q0.x, q0.y, q0.z, q0.w, q1.x, q1.y, q1.z, q1.w};
    float c[8];
#pragma unroll
    for (int j = 0; j < 8; ++j) c[j] = qm[j] ? (float)sv[j] : -1e-5f;
    float mx = c[0];
#pragma unroll
    for (int j = 1; j < 8; ++j) mx = fmaxf(mx, c[j]);
#pragma unroll
    for (int off = 1; off <= 32; off <<= 1) mx = fmaxf(mx, __shfl_xor(mx, off));
    f16x8 o;
    float sm = 0.f;
#pragma unroll
    for (int j = 0; j < 8; ++j) {
        _Float16 h = (_Float16)__expf(c[j] - mx);
        o[j] = h;
        sm += (float)h;
    }
#pragma unroll
    for (int off = 1; off <= 32; off <<= 1) sm += __shfl_xor(sm, off);
    *(f16x8*)(P + ((size_t)cbi * SS + row) * SS + lane * 8) = o;
    if (lane == 0) rs[cbi * SS + row] = 1.0f / sm;
}

// ---------------------------------------------------------------------------
__global__ __launch_bounds__(256) void k_wvproj(const u32* __restrict__ wvkeys,
                                                const float* __restrict__ Wp,
                                                const float* __restrict__ bp,
                                                float* __restrict__ outp) {
    int b = blockIdx.x;
    __shared__ float xv[DWW];
    int tid = threadIdx.x;
    if (tid < DWW) xv[tid] = fdec(wvkeys[b * DWW + tid]);
    __syncthreads();
    for (int h = tid; h < HH; h += 256) {
        float acc = bp[h];
        for (int d = 0; d < DWW; ++d) acc += xv[d] * Wp[d * HH + h];
        outp[b * HH + h] = acc;
    }
}

__global__ __launch_bounds__(256) void k_final(const float* __restrict__ x1h,
                                               const float* __restrict__ x2h,
                                               const u32* __restrict__ keys,
                                               const float* __restrict__ wvp,
                                               const float* __restrict__ lw,
                                               const float* __restrict__ lb,
                                               float* __restrict__ out) {
    int b = blockIdx.x;
    int tid = threadIdx.x;
    float acc = 0.f;
    for (int i = tid; i < HH; i += 256) {
        acc += x1h[b * HH + i] * lw[i];
        acc += x2h[b * HH + i] * lw[HH + i];
        acc += fdec(keys[b * HH + i]) * lw[2 * HH + i];
        acc += wvp[b * HH + i] * lw[3 * HH + i];
    }
    __shared__ float red[4];
    int wid = tid >> 6, lane = tid & 63;
#pragma unroll
    for (int off = 32; off; off >>= 1) acc += __shfl_down(acc, off);
    if (lane == 0) red[wid] = acc;
    __syncthreads();
    if (tid == 0) {
        float z = red[0] + red[1] + red[2] + red[3] + lb[0];
        out[b] = 1.f / (1.f + __expf(-z));
    }
}

// ---------------------------------------------------------------------------
extern "C" void kernel_launch(void* const* d_in, const int* in_sizes, int n_in,
                              void* d_out, int out_size, void* d_ws, size_t ws_size,
                              hipStream_t stream) {
    const float* x1   = (const float*)d_in[0];
    const float* x1h  = (const float*)d_in[1];
    const int*   m1   = (const int*)d_in[2];
    const float* y    = (const float*)d_in[3];
    const float* x2   = (const float*)d_in[4];
    const float* x2h  = (const float*)d_in[5];
    const int*   m2   = (const int*)d_in[6];
    const float* tt   = (const float*)d_in[7];
    const float* tt2  = (const float*)d_in[8];
    const float* Wb   = (const float*)d_in[9];
    const float* Wwv  = (const float*)d_in[10];
    const float* lwvw = (const float*)d_in[11];
    const float* lwvb = (const float*)d_in[12];
    const float* lw   = (const float*)d_in[13];
    const float* lb   = (const float*)d_in[14];
    float* out = (float*)d_out;
    char* ws = (char*)d_ws;

    // fixed region
    u32*      x12key   = (u32*)ws;                    // 196608
    u32*      x12wvkey = (u32*)(ws + 196608);         // 51200
    float*    x12wvp   = (float*)(ws + 247808);       // 196608
    float*    rsumB    = (float*)(ws + 444416);       // 131072
    float*    rsumW    = (float*)(ws + 575488);       // 131072
    _Float16* wbTH     = (_Float16*)(ws + 706560);    // 768*800*2 = 1228800
    _Float16* wwTH     = (_Float16*)(ws + 1935360);   // 256*224*2 = 114688
    int*      idxBuf   = (int*)(ws + 2050048);        // 131072
    int*      rcntBuf  = (int*)(ws + 2181120);        // 256
    const size_t D0 = 2181376;

    k_setup<<<3008, 256, 0, stream>>>(m1, m2, Wb, Wwv, out, x12key, x12wvkey,
                                      idxBuf, rcntBuf, wbTH, wwTH);

    const size_t perb = 5242880;
    int nb = 1;
    if (ws_size > D0 + perb) nb = (int)((ws_size - D0) / perb);
    if (nb > BB) nb = BB;
    if (nb < 1) nb = 1;

    char* R = ws + D0;
    _Float16* XcB = (_Float16*)R;                            // stride 409600 elem
    _Float16* XcW = (_Float16*)(R + (size_t)nb * 819200);    // stride 114688
    _Float16* S_b = (_Float16*)R;                            // stride 262144 (alias Xc)
    _Float16* S_w = (_Float16*)(R + (size_t)nb * 524288);    // stride 262144
    char* p = R + (size_t)nb * 1048576;
    _Float16* XW_b = (_Float16*)p; p += (size_t)nb * 786432;  // stride 393216
    _Float16* XW_w = (_Float16*)p; p += (size_t)nb * 262144;  // stride 131072
    _Float16* KV_b = (_Float16*)p; p += (size_t)nb * 786432;  // stride 393216
    _Float16* KV_w = (_Float16*)p; p += (size_t)nb * 262144;  // stride 131072
    _Float16* KT_b = (_Float16*)p; p += (size_t)nb * 786432;  // stride 393216
    _Float16* KT_w = (_Float16*)p; p += (size_t)nb * 262144;  // stride 131072
    _Float16* P_b  = (_Float16*)p; p += (size_t)nb * 524288;  // stride 262144
    _Float16* P_w  = (_Float16*)p;                            // stride 262144

    for (int b0 = 0; b0 < BB; b0 += nb) {
        int cb = (BB - b0 < nb) ? (BB - b0) : nb;
        k_prep<<<cb * 640, 256, 0, stream>>>(
            x2, tt2, x1, tt, y, idxBuf, rcntBuf,
            KV_b, KT_b, KV_w, KT_w, XcB, XcW, cb, b0);
        // xw: bert KA=800,25 steps,TN=6,SXW=768; wv KA=224,7,TN=2,SXW=256
        k_mmM<1, 800, 25, 6, 768, 0, 409600, 0,
                 224,  7, 2, 256, 0, 114688, 0><<<cb * 32, 256, 0, stream>>>(
            XcB, wbTH, XW_b, nullptr, nullptr,
            XcW, wwTH, XW_w, nullptr, nullptr,
            cb * 24, rcntBuf, b0, cb * 32);
        // scores -> fp16 S: bert KA=768,24,TN=4; wv KA=256,8,TN=4
        k_mmM<1, 768, 24, 4, 512, 0, 393216, 393216,
                 256,  8, 4, 512, 0, 131072, 131072><<<cb * 32, 256, 0, stream>>>(
            XW_b, KV_b, S_b, nullptr, nullptr,
            XW_w, KV_w, S_w, nullptr, nullptr,
            cb * 16, rcntBuf, b0, cb * 32);
        k_softmaxM<<<cb * 256, 256, 0, stream>>>(
            S_b, P_b, rsumB, S_w, P_w, rsumW, m2, rcntBuf, cb * 128, b0);
        // pv: KA=512,16 steps; bert TN=6 DV=768; wv TN=2 DV=200
        k_mmM<2, 512, 16, 6, 0, 768, 262144, 393216,
                 512, 16, 2, 0, 200, 262144, 131072><<<cb * 32, 256, 0, stream>>>(
            P_b, KT_b, nullptr, rsumB, x12key,
            P_w, KT_w, nullptr, rsumW, x12wvkey,
            cb * 24, rcntBuf, b0, cb * 32);
    }

    k_wvproj<<<BB, 256, 0, stream>>>(x12wvkey, lwvw, lwvb, x12wvp);
    k_final<<<BB, 256, 0, stream>>>(x1h, x2h, x12key, x12wvp, lw, lb, out);
}

// Round 11
// 313.718 us; speedup vs baseline: 8.7419x; 1.0347x over previous
//
#include <hip/hip_runtime.h>

// ============================================================================
// Round 11: widen k_prep (f16x8 per thread everywhere) + in-place P (P=S).
//   - k_prep: KV 64x64 tiles with 8-elem threads (2 iters of 32 rows), LDS
//     [64][65] transpose, f16x8 stores for kv/kvT; Xcat gather 8-wide.
//   - P written in-place over S (element-wise, same-thread same-address);
//     softmax early-returns rows >= rc (PV gated epilogue discards them).
//     perb 5.24 -> 4.19 MB/batch -> nb=64 guaranteed within ~271 MB ws.
// GEMMs, XCD-proportional mapping, numerics identical to r10.
// ============================================================================

#define BB 64
#define SS 512
#define HH 768
#define DWW 200

typedef __attribute__((ext_vector_type(8))) _Float16 f16x8;
typedef __attribute__((ext_vector_type(4))) _Float16 f16x4;
typedef __attribute__((ext_vector_type(4))) float f32x4;
typedef unsigned int u32;

__device__ __forceinline__ u32 fkey(float f) {
    u32 u = __float_as_uint(f);
    return (u & 0x80000000u) ? ~u : (u | 0x80000000u);
}
__device__ __forceinline__ float fdec(u32 k) {
    u32 u = (k & 0x80000000u) ? (k & 0x7fffffffu) : ~k;
    return __uint_as_float(u);
}
__device__ __forceinline__ f32x4 mm(f16x8 a, f16x8 b, f32x4 c) {
    return __builtin_amdgcn_mfma_f32_16x16x32_f16(a, b, c, 0, 0, 0);
}
__device__ __forceinline__ void gl16(const void* g, void* l) {
    __builtin_amdgcn_global_load_lds(
        (const __attribute__((address_space(1))) void*)g,
        (__attribute__((address_space(3))) void*)l, 16, 0, 0);
}

// ---------------------------------------------------------------------------
// k_setup: [0,128) mask outputs; [128,320) key init; [320,384) compaction scan;
// [384,2784) prep_w bert; [2784,3008) prep_w wv.
__global__ __launch_bounds__(256) void k_setup(
    const int* __restrict__ m1, const int* __restrict__ m2,
    const float* __restrict__ Wb, const float* __restrict__ Wwv,
    float* __restrict__ out, u32* __restrict__ k1, u32* __restrict__ k2,
    int* __restrict__ idx, int* __restrict__ rcnt,
    _Float16* __restrict__ wbTH, _Float16* __restrict__ wwTH) {
    int bid = blockIdx.x, tid = threadIdx.x;
    if (bid < 128) {
        int i = bid * 256 + tid;
        out[BB + i]           = (float)(1 - m1[i]);
        out[BB + BB * SS + i] = (float)(1 - m2[i]);
    } else if (bid < 320) {
        int i = (bid - 128) * 256 + tid;
        u32 v = fkey(-1e5f);
        if (i < BB * HH) k1[i] = v;
        if (i < BB * DWW) k2[i] = v;
    } else if (bid < 384) {
        int b = bid - 320;
        if (tid < 64) {
            int base = 0;
#pragma unroll
            for (int c = 0; c < 8; ++c) {
                int s = c * 64 + tid;
                int v = m1[b * SS + s];
                unsigned long long bal = __ballot(v != 0);
                int pre = __popcll(bal & ((1ull << tid) - 1ull));
                if (v) idx[b * SS + base + pre] = s;
                base += __popcll(bal);
            }
            if (tid == 0) rcnt[b] = base;
        }
    } else if (bid < 2784) {
        int i = (bid - 384) * 256 + tid;          // < 768*800
        int n = i / 800, k = i - n * 800;
        wbTH[i] = (_Float16)((k < 769) ? Wb[(size_t)k * 768 + n] : 0.f);
    } else {
        int i = (bid - 2784) * 256 + tid;         // < 256*224
        int n = i / 224, k = i - n * 224;
        wwTH[i] = (_Float16)((k < 201 && n < 200) ? Wwv[(size_t)k * 200 + n] : 0.f);
    }
}

// ---------------------------------------------------------------------------
// merged input prep, 8 elems/thread:
//   [0, cb*128): KV 64x64 tiles (bert 12 d-slabs + wv 4) -> kv + kvT.
//   [cb*128, cb*384): compacted Xcat (bert 200 + wv 56 chunks of 2048 elems).
__global__ __launch_bounds__(256) void k_prep(
    const float* __restrict__ x2, const float* __restrict__ tt2,
    const float* __restrict__ x1, const float* __restrict__ tt,
    const float* __restrict__ yv,
    const int* __restrict__ idx, const int* __restrict__ rcnt,
    _Float16* __restrict__ kvB, _Float16* __restrict__ kvTB,
    _Float16* __restrict__ kvW, _Float16* __restrict__ kvTW,
    _Float16* __restrict__ XcB, _Float16* __restrict__ XcW,
    int cb, int b0) {
    __shared__ float tile[64][65];
    int bx = blockIdx.x, tid = threadIdx.x;
    if (bx < cb * 128) {
        int cbi = bx >> 7, sub = bx & 127;
        int t0 = (sub & 7) * 64, ybr = sub >> 3;
        const float* src; _Float16* kv; _Float16* kvT; int D, DPAD, DTPAD, d0;
        if (ybr < 12) { src = x2;  kv = kvB; kvT = kvTB; D = 768; DPAD = 768; DTPAD = 768; d0 = ybr * 64; }
        else          { src = tt2; kv = kvW; kvT = kvTW; D = 200; DPAD = 256; DTPAD = 256; d0 = (ybr - 12) * 64; }
        int bg = b0 + cbi;
        int tq = tid >> 3, c8 = (tid & 7) * 8;
#pragma unroll
        for (int i = 0; i < 2; ++i) {
            int t = tq + i * 32;
            int gd = d0 + c8;
            float v[8];
            if (gd + 7 < D) {
                const float* rp = src + ((size_t)bg * SS + t0 + t) * D + gd;
                float4 p0 = *(const float4*)(rp);
                float4 p1 = *(const float4*)(rp + 4);
                v[0] = p0.x; v[1] = p0.y; v[2] = p0.z; v[3] = p0.w;
                v[4] = p1.x; v[5] = p1.y; v[6] = p1.z; v[7] = p1.w;
            } else {
#pragma unroll
                for (int j = 0; j < 8; ++j) {
                    int d = gd + j;
                    v[j] = (d < D) ? src[((size_t)bg * SS + t0 + t) * D + d] : 0.f;
                }
            }
            f16x8 o;
#pragma unroll
            for (int j = 0; j < 8; ++j) {
                tile[t][c8 + j] = v[j];
                o[j] = (_Float16)v[j];
            }
            *(f16x8*)(kv + ((size_t)cbi * SS + t0 + t) * DPAD + gd) = o;
        }
        __syncthreads();
#pragma unroll
        for (int i = 0; i < 2; ++i) {
            int dl = tq + i * 32, gdr = d0 + dl;
            f16x8 o;
#pragma unroll
            for (int j = 0; j < 8; ++j) o[j] = (_Float16)tile[c8 + j][dl];
            *(f16x8*)(kvT + ((size_t)cbi * DTPAD + gdr) * SS + t0 + c8) = o;
        }
    } else {
        bx -= cb * 128;
        int cbi = bx >> 8, xb = bx & 255;
        int bg = b0 + cbi;
        const float* X; _Float16* outp; int Din, KPAD; size_t ost;
        if (xb < 200) { X = x1; outp = XcB; Din = 768; KPAD = 800; ost = (size_t)cbi * 409600; }
        else { xb -= 200; X = tt; outp = XcW; Din = 200; KPAD = 224; ost = (size_t)cbi * 114688; }
        int i8 = (xb * 256 + tid) * 8;
        int s = i8 / KPAD, k0 = i8 - s * KPAD;
        int rc = rcnt[bg];
        int rpad = (rc + 127) & ~127;
        if (s >= rpad) return;
        f16x8 o = {};
        if (s < rc) {
            int sg = idx[bg * SS + s];
            const float* Xr = X + ((size_t)bg * SS + sg) * Din;
            if (k0 + 7 < Din) {
                float4 p0 = *(const float4*)(Xr + k0);
                float4 p1 = *(const float4*)(Xr + k0 + 4);
                o[0] = (_Float16)p0.x; o[1] = (_Float16)p0.y;
                o[2] = (_Float16)p0.z; o[3] = (_Float16)p0.w;
                o[4] = (_Float16)p1.x; o[5] = (_Float16)p1.y;
                o[6] = (_Float16)p1.z; o[7] = (_Float16)p1.w;
            } else {
#pragma unroll
                for (int j = 0; j < 8; ++j) {
                    int k = k0 + j;
                    float v = (k < Din) ? Xr[k]
                                        : ((k == Din) ? yv[(size_t)bg * SS + sg] : 0.f);
                    o[j] = (_Float16)v;
                }
            }
        }
        *(f16x8*)(outp + ost + (size_t)s * KPAD + k0) = o;
    }
}

// ---------------------------------------------------------------------------
// Compile-time GEMM core. C[128x128] = A[128xKA] * B[128xKA]^T.
// BK=32 dbuf, gl16 staging, 16 MFMA per step. EPI=1: fp16 out (LDS-staged
// 16B stores). EPI=2: fused normalize + compacted-row-gate + maxpool.
template<int KA, int KST, int TN, int SXW, int DV, int AS, int BS, int EPI>
__device__ __forceinline__ void mm_core(
    const _Float16* __restrict__ A, const _Float16* __restrict__ B,
    _Float16* __restrict__ O, const float* __restrict__ rsum,
    u32* __restrict__ keys, int jb, const int* __restrict__ rcnt,
    int b0, char* lds, float* rsv) {
    int cbi = jb / (4 * TN);
    int rest = jb - cbi * (4 * TN);
    int ts = rest / TN, tn = rest - ts * TN;
    int s0 = ts * 128, n0 = tn * 128;

    int rc = rcnt[b0 + cbi];
    int rpad = (rc + 127) & ~127;
    if (s0 >= rpad) return;

    int tid = threadIdx.x, lane = tid & 63, wid = tid >> 6;
    int wr = wid >> 1, wc = wid & 1;
    int l15 = lane & 15, sl = lane >> 4, gb = sl * 4;

    const _Float16* srcA = A + (size_t)cbi * AS + (size_t)s0 * KA;
    const _Float16* srcB = B + (size_t)cbi * BS + (size_t)n0 * KA;

    if constexpr (EPI == 2) {
        if (tid < 128) rsv[tid] = rsum[cbi * SS + s0 + tid];
    }

    f32x4 zz = {0.f, 0.f, 0.f, 0.f};
    f32x4 acc[4][4];
#pragma unroll
    for (int i = 0; i < 4; ++i)
#pragma unroll
        for (int j = 0; j < 4; ++j) acc[i][j] = zz;

#define STAGE(buf, ks)                                                        \
    _Pragma("unroll") for (int i = 0; i < 4; ++i) {                           \
        int c = wid + 4 * i;                                                  \
        int arr = c >> 3, sub = c & 7, slot = sub >> 1, rh = sub & 1;         \
        const _Float16* gp = (arr ? srcB : srcA) +                            \
            (size_t)(rh * 64 + lane) * KA + (ks) * 32 + slot * 8;             \
        gl16(gp, lds + (buf) * 16384 + c * 1024);                             \
    }

    STAGE(0, 0);
    __syncthreads();
    int buf = 0;
#pragma unroll
    for (int ks = 0; ks < KST; ++ks) {
        if (ks + 1 < KST) STAGE(buf ^ 1, ks + 1);
        char* base = lds + buf * 16384;
        f16x8 a[4], b[4];
#pragma unroll
        for (int mf = 0; mf < 4; ++mf)
            a[mf] = *(const f16x8*)(base + sl * 2048 + (wr * 64 + mf * 16 + l15) * 16);
#pragma unroll
        for (int nf = 0; nf < 4; ++nf)
            b[nf] = *(const f16x8*)(base + 8192 + sl * 2048 + (wc * 64 + nf * 16 + l15) * 16);
#pragma unroll
        for (int mf = 0; mf < 4; ++mf)
#pragma unroll
            for (int nf = 0; nf < 4; ++nf)
                acc[mf][nf] = mm(a[mf], b[nf], acc[mf][nf]);
        __syncthreads();
        buf ^= 1;
    }
#undef STAGE

    if constexpr (EPI == 1) {
        _Float16* ce = (_Float16*)lds;
#pragma unroll
        for (int mf = 0; mf < 4; ++mf)
#pragma unroll
            for (int nf = 0; nf < 4; ++nf)
#pragma unroll
                for (int r = 0; r < 4; ++r) {
                    int row = wr * 64 + mf * 16 + gb + r;
                    int col = wc * 64 + nf * 16 + l15;
                    ce[row * 128 + col] = (_Float16)acc[mf][nf][r];
                }
        __syncthreads();
#pragma unroll
        for (int i = 0; i < 8; ++i) {
            int t = tid + i * 256;
            int row = t >> 4, col = (t & 15) * 8;
            *(f16x8*)(O + ((size_t)cbi * SS + s0 + row) * SXW + n0 + col) =
                *(const f16x8*)(ce + row * 128 + col);
        }
    } else {
        int bg = b0 + cbi;
#pragma unroll
        for (int nf = 0; nf < 4; ++nf) {
            float mx = -3.0e38f;
#pragma unroll
            for (int mf = 0; mf < 4; ++mf)
#pragma unroll
                for (int r = 0; r < 4; ++r) {
                    int srow = wr * 64 + mf * 16 + gb + r;
                    if (s0 + srow < rc) mx = fmaxf(mx, acc[mf][nf][r] * rsv[srow]);
                }
            mx = fmaxf(mx, __shfl_xor(mx, 16));
            mx = fmaxf(mx, __shfl_xor(mx, 32));
            if (lane < 16) {
                int d = n0 + wc * 64 + nf * 16 + lane;
                if (d < DV) atomicMax(&keys[(size_t)bg * DV + d], fkey(mx));
            }
        }
    }
}

// Merged dual-instantiation GEMM with XCD-proportional branch split:
// XCD x = bid&7, slot t = bid>>3. Each XCD gets nj0/8 bert tiles (batch-
// contiguous) then (nwg-nj0)/8 wv tiles. Requires nj0 % 8 == 0 (all callers).
template<int EPI,
         int KA0, int KST0, int TN0, int SXW0, int DV0, int AS0, int BS0,
         int KA1, int KST1, int TN1, int SXW1, int DV1, int AS1, int BS1>
__global__ __launch_bounds__(256) void k_mmM(
    const _Float16* __restrict__ A0, const _Float16* __restrict__ B0,
    _Float16* __restrict__ O0, const float* __restrict__ rs0, u32* __restrict__ key0,
    const _Float16* __restrict__ A1, const _Float16* __restrict__ B1,
    _Float16* __restrict__ O1, const float* __restrict__ rs1, u32* __restrict__ key1,
    int nj0, const int* __restrict__ rcnt, int b0, int nwg) {
    __shared__ __align__(16) char lds[32768];
    __shared__ float rsv[128];
    int bid = blockIdx.x;
    int x = bid & 7, t = bid >> 3;
    int tb = nj0 >> 3;                 // bert tiles per XCD
    int tw = (nwg - nj0) >> 3;         // wv tiles per XCD
    if (t < tb)
        mm_core<KA0, KST0, TN0, SXW0, DV0, AS0, BS0, EPI>(
            A0, B0, O0, rs0, key0, x * tb + t, rcnt, b0, lds, rsv);
    else
        mm_core<KA1, KST1, TN1, SXW1, DV1, AS1, BS1, EPI>(
            A1, B1, O1, rs1, key1, x * tw + (t - tb), rcnt, b0, lds, rsv);
}

// ---------------------------------------------------------------------------
// merged row softmax over fp16 S, IN-PLACE (P overwrites S): exact max,
// unnormalized fp16 P, 1/sum. Rows >= rc: skip (PV epilogue gates them).
__global__ __launch_bounds__(256) void k_softmaxM(
    _Float16* __restrict__ SP0, float* __restrict__ rs0,
    _Float16* __restrict__ SP1, float* __restrict__ rs1,
    const int* __restrict__ m2, const int* __restrict__ rcnt, int nblk0, int b0) {
    int bid = blockIdx.x;
    bool selw = bid >= nblk0;
    int b = selw ? bid - nblk0 : bid;
    _Float16* SP = selw ? SP1 : SP0;
    float* rs = selw ? rs1 : rs0;
    int cbi = b >> 7, rb = b & 127;
    int wid = threadIdx.x >> 6, lane = threadIdx.x & 63;
    int row = rb * 4 + wid, bg = b0 + cbi;
    int rc = rcnt[bg];
    if (row >= rc) return;
    f16x8 sv = *(const f16x8*)(SP + ((size_t)cbi * SS + row) * SS + lane * 8);
    int4 q0 = *(const int4*)(m2 + bg * SS + lane * 8);
    int4 q1 = *(const int4*)(m2 + bg * SS + lane * 8 + 4);
    const int qm[8] = {q0.x, q0.y, q0.z, q0.w, q1.x, q1.y, q1.z, q1.w};
    float c[8];
#pragma unroll
    for (int j = 0; j < 8; ++j) c[j] = qm[j] ? (float)sv[j] : -1e-5f;
    float mx = c[0];
#pragma unroll
    for (int j = 1; j < 8; ++j) mx = fmaxf(mx, c[j]);
#pragma unroll
    for (int off = 1; off <= 32; off <<= 1) mx = fmaxf(mx, __shfl_xor(mx, off));
    f16x8 o;
    float sm = 0.f;
#pragma unroll
    for (int j = 0; j < 8; ++j) {
        _Float16 h = (_Float16)__expf(c[j] - mx);
        o[j] = h;
        sm += (float)h;
    }
#pragma unroll
    for (int off = 1; off <= 32; off <<= 1) sm += __shfl_xor(sm, off);
    *(f16x8*)(SP + ((size_t)cbi * SS + row) * SS + lane * 8) = o;
    if (lane == 0) rs[cbi * SS + row] = 1.0f / sm;
}

// ---------------------------------------------------------------------------
__global__ __launch_bounds__(256) void k_wvproj(const u32* __restrict__ wvkeys,
                                                const float* __restrict__ Wp,
                                                const float* __restrict__ bp,
                                                float* __restrict__ outp) {
    int b = blockIdx.x;
    __shared__ float xv[DWW];
    int tid = threadIdx.x;
    if (tid < DWW) xv[tid] = fdec(wvkeys[b * DWW + tid]);
    __syncthreads();
    for (int h = tid; h < HH; h += 256) {
        float acc = bp[h];
        for (int d = 0; d < DWW; ++d) acc += xv[d] * Wp[d * HH + h];
        outp[b * HH + h] = acc;
    }
}

__global__ __launch_bounds__(256) void k_final(const float* __restrict__ x1h,
                                               const float* __restrict__ x2h,
                                               const u32* __restrict__ keys,
                                               const float* __restrict__ wvp,
                                               const float* __restrict__ lw,
                                               const float* __restrict__ lb,
                                               float* __restrict__ out) {
    int b = blockIdx.x;
    int tid = threadIdx.x;
    float acc = 0.f;
    for (int i = tid; i < HH; i += 256) {
        acc += x1h[b * HH + i] * lw[i];
        acc += x2h[b * HH + i] * lw[HH + i];
        acc += fdec(keys[b * HH + i]) * lw[2 * HH + i];
        acc += wvp[b * HH + i] * lw[3 * HH + i];
    }
    __shared__ float red[4];
    int wid = tid >> 6, lane = tid & 63;
#pragma unroll
    for (int off = 32; off; off >>= 1) acc += __shfl_down(acc, off);
    if (lane == 0) red[wid] = acc;
    __syncthreads();
    if (tid == 0) {
        float z = red[0] + red[1] + red[2] + red[3] + lb[0];
        out[b] = 1.f / (1.f + __expf(-z));
    }
}

// ---------------------------------------------------------------------------
extern "C" void kernel_launch(void* const* d_in, const int* in_sizes, int n_in,
                              void* d_out, int out_size, void* d_ws, size_t ws_size,
                              hipStream_t stream) {
    const float* x1   = (const float*)d_in[0];
    const float* x1h  = (const float*)d_in[1];
    const int*   m1   = (const int*)d_in[2];
    const float* y    = (const float*)d_in[3];
    const float* x2   = (const float*)d_in[4];
    const float* x2h  = (const float*)d_in[5];
    const int*   m2   = (const int*)d_in[6];
    const float* tt   = (const float*)d_in[7];
    const float* tt2  = (const float*)d_in[8];
    const float* Wb   = (const float*)d_in[9];
    const float* Wwv  = (const float*)d_in[10];
    const float* lwvw = (const float*)d_in[11];
    const float* lwvb = (const float*)d_in[12];
    const float* lw   = (const float*)d_in[13];
    const float* lb   = (const float*)d_in[14];
    float* out = (float*)d_out;
    char* ws = (char*)d_ws;

    // fixed region
    u32*      x12key   = (u32*)ws;                    // 196608
    u32*      x12wvkey = (u32*)(ws + 196608);         // 51200
    float*    x12wvp   = (float*)(ws + 247808);       // 196608
    float*    rsumB    = (float*)(ws + 444416);       // 131072
    float*    rsumW    = (float*)(ws + 575488);       // 131072
    _Float16* wbTH     = (_Float16*)(ws + 706560);    // 768*800*2 = 1228800
    _Float16* wwTH     = (_Float16*)(ws + 1935360);   // 256*224*2 = 114688
    int*      idxBuf   = (int*)(ws + 2050048);        // 131072
    int*      rcntBuf  = (int*)(ws + 2181120);        // 256
    const size_t D0 = 2181376;

    k_setup<<<3008, 256, 0, stream>>>(m1, m2, Wb, Wwv, out, x12key, x12wvkey,
                                      idxBuf, rcntBuf, wbTH, wwTH);

    const size_t perb = 4194304;
    int nb = 1;
    if (ws_size > D0 + perb) nb = (int)((ws_size - D0) / perb);
    if (nb > BB) nb = BB;
    if (nb < 1) nb = 1;

    char* R = ws + D0;
    _Float16* XcB = (_Float16*)R;                            // stride 409600 elem
    _Float16* XcW = (_Float16*)(R + (size_t)nb * 819200);    // stride 114688 elem
    _Float16* S_b = (_Float16*)R;                            // stride 262144 elem (alias Xc; P in-place)
    _Float16* S_w = (_Float16*)(R + (size_t)nb * 524288);    // stride 262144 elem
    char* p = R + (size_t)nb * 1048576;
    _Float16* XW_b = (_Float16*)p; p += (size_t)nb * 786432;  // stride 393216 elem
    _Float16* XW_w = (_Float16*)p; p += (size_t)nb * 262144;  // stride 131072 elem
    _Float16* KV_b = (_Float16*)p; p += (size_t)nb * 786432;  // stride 393216 elem
    _Float16* KV_w = (_Float16*)p; p += (size_t)nb * 262144;  // stride 131072 elem
    _Float16* KT_b = (_Float16*)p; p += (size_t)nb * 786432;  // stride 393216 elem
    _Float16* KT_w = (_Float16*)p;                            // stride 131072 elem

    for (int b0 = 0; b0 < BB; b0 += nb) {
        int cb = (BB - b0 < nb) ? (BB - b0) : nb;
        k_prep<<<cb * 384, 256, 0, stream>>>(
            x2, tt2, x1, tt, y, idxBuf, rcntBuf,
            KV_b, KT_b, KV_w, KT_w, XcB, XcW, cb, b0);
        // xw: bert KA=800,25 steps,TN=6,SXW=768; wv KA=224,7,TN=2,SXW=256
        k_mmM<1, 800, 25, 6, 768, 0, 409600, 0,
                 224,  7, 2, 256, 0, 114688, 0><<<cb * 32, 256, 0, stream>>>(
            XcB, wbTH, XW_b, nullptr, nullptr,
            XcW, wwTH, XW_w, nullptr, nullptr,
            cb * 24, rcntBuf, b0, cb * 32);
        // scores -> fp16 S: bert KA=768,24,TN=4; wv KA=256,8,TN=4
        k_mmM<1, 768, 24, 4, 512, 0, 393216, 393216,
                 256,  8, 4, 512, 0, 131072, 131072><<<cb * 32, 256, 0, stream>>>(
            XW_b, KV_b, S_b, nullptr, nullptr,
            XW_w, KV_w, S_w, nullptr, nullptr,
            cb * 16, rcntBuf, b0, cb * 32);
        k_softmaxM<<<cb * 256, 256, 0, stream>>>(
            S_b, rsumB, S_w, rsumW, m2, rcntBuf, cb * 128, b0);
        // pv: KA=512,16 steps; bert TN=6 DV=768; wv TN=2 DV=200 (A = in-place P)
        k_mmM<2, 512, 16, 6, 0, 768, 262144, 393216,
                 512, 16, 2, 0, 200, 262144, 131072><<<cb * 32, 256, 0, stream>>>(
            S_b, KT_b, nullptr, rsumB, x12key,
            S_w, KT_w, nullptr, rsumW, x12wvkey,
            cb * 24, rcntBuf, b0, cb * 32);
    }

    k_wvproj<<<BB, 256, 0, stream>>>(x12wvkey, lwvw, lwvb, x12wvp);
    k_final<<<BB, 256, 0, stream>>>(x1h, x2h, x12key, x12wvp, lw, lb, out);
}